// Round 1
// baseline (276.798 us; speedup 1.0000x reference)
//
#include <hip/hip_runtime.h>
#include <climits>

#define B_ 2
#define N_ 512
#define C_ 128
#define H_ 128
#define W_ 128
#define HW_ (H_ * W_)
#define NUM_NEG_ 16
#define SOS_NEG_ 8

// ---------------------------------------------------------------------------
// 4 nearest grid-cell centers of point (y,x). Grid: cell (yi,xi) center at
// (8*yi+4, 8*xi+4), id = yi*128+xi. The 4-nearest set always lies in a
// clamped 4x4 window around floor((p-4)/8); tie-break (dist, then lower id)
// matches lax.top_k.
// ---------------------------------------------------------------------------
__device__ inline void nearest4(float y, float x, int out[4]) {
    // safety clamp (pathological homography): avoids int-conversion UB
    y = fminf(fmaxf(y, -1e6f), 1e6f);
    x = fminf(fmaxf(x, -1e6f), 1e6f);
    int fy = (int)floorf(y * 0.125f - 0.5f);
    int fx = (int)floorf(x * 0.125f - 0.5f);
    int ylo = fy - 1; if (ylo < 0) ylo = 0; if (ylo > H_ - 4) ylo = H_ - 4;
    int xlo = fx - 1; if (xlo < 0) xlo = 0; if (xlo > W_ - 4) xlo = W_ - 4;
    float bd[4] = {1e30f, 1e30f, 1e30f, 1e30f};
    int   bi[4] = {INT_MAX, INT_MAX, INT_MAX, INT_MAX};
#pragma unroll
    for (int dyi = 0; dyi < 4; ++dyi) {
        int yi = ylo + dyi;
        float dy = y - (8.0f * yi + 4.0f);
        float dy2 = dy * dy;
#pragma unroll
        for (int dxi = 0; dxi < 4; ++dxi) {
            int xi = xlo + dxi;
            float dx = x - (8.0f * xi + 4.0f);
            float d = dy2 + dx * dx;
            int id = yi * W_ + xi;
#pragma unroll
            for (int k = 0; k < 4; ++k) {
                bool sm = (d < bd[k]) || (d == bd[k] && id < bi[k]);
                float od = bd[k]; int oi = bi[k];
                bd[k] = sm ? d : od;  bi[k] = sm ? id : oi;
                d = sm ? od : d;      id = sm ? oi : id;
            }
        }
    }
    out[0] = bi[0]; out[1] = bi[1]; out[2] = bi[2]; out[3] = bi[3];
}

// ---------------------------------------------------------------------------
// K1: per keypoint -> 4 nearest cell ids (cid4), warp those 4 cells and take
// each warped point's 4 nearest cells (wcc16), and w_kp1's 4 nearest (wid4).
// ---------------------------------------------------------------------------
__global__ void hqt_k1_cells(const float* __restrict__ kp1,
                             const float* __restrict__ w_kp1,
                             const float* __restrict__ homo,
                             int* __restrict__ cid4,
                             int* __restrict__ wcc16,
                             int* __restrict__ wid4) {
    int t = blockIdx.x * blockDim.x + threadIdx.x;
    if (t >= B_ * N_) return;
    int b = t / N_;
    float ky = kp1[2 * t], kx = kp1[2 * t + 1];
    int ids[4];
    nearest4(ky, kx, ids);
    const float* Hb = homo + 9 * b;
    float h00 = Hb[0], h01 = Hb[1], h02 = Hb[2];
    float h10 = Hb[3], h11 = Hb[4], h12 = Hb[5];
    float h20 = Hb[6], h21 = Hb[7], h22 = Hb[8];
#pragma unroll
    for (int i = 0; i < 4; ++i) {
        int id = ids[i];
        cid4[4 * t + i] = id;
        float cy = 8.0f * (id >> 7) + 4.0f;
        float cx = 8.0f * (id & 127) + 4.0f;
        // warp_points: ph=(x,y,1); wp=H*ph; out (y,x) = (wp1,wp0)/(wp2+1e-8)
        float X = cx, Y = cy;
        float wz = h20 * X + h21 * Y + h22;
        float inv = 1.0f / (wz + 1e-8f);
        float wy = (h10 * X + h11 * Y + h12) * inv;
        float wx = (h00 * X + h01 * Y + h02) * inv;
        int wids[4];
        nearest4(wy, wx, wids);
#pragma unroll
        for (int j = 0; j < 4; ++j) wcc16[16 * t + 4 * i + j] = wids[j];
    }
    float zy = w_kp1[2 * t], zx = w_kp1[2 * t + 1];
    int wi4[4];
    nearest4(zy, zx, wi4);
#pragma unroll
    for (int j = 0; j < 4; ++j) wid4[4 * t + j] = wi4[j];
}

// ---------------------------------------------------------------------------
// K2: bilinear-sample desc2 at w_kp1, L2-normalize -> w_desc; pos = 2-2*dot.
// One block (128 threads = channels) per keypoint.
// ---------------------------------------------------------------------------
__global__ __launch_bounds__(128) void hqt_k2_sample(
    const float* __restrict__ w_kp1, const float* __restrict__ desc2,
    const float* __restrict__ kp1_desc, float* __restrict__ w_desc,
    float* __restrict__ pos) {
    int bn = blockIdx.x;
    int b = bn / N_;
    int c = threadIdx.x;
    float ky = w_kp1[2 * bn], kx = w_kp1[2 * bn + 1];
    float y = fminf(fmaxf(ky * 0.125f - 0.5f, 0.0f), (float)(H_ - 1));
    float x = fminf(fmaxf(kx * 0.125f - 0.5f, 0.0f), (float)(W_ - 1));
    int y0 = (int)floorf(y); if (y0 > H_ - 2) y0 = H_ - 2;
    int x0 = (int)floorf(x); if (x0 > W_ - 2) x0 = W_ - 2;
    float wy = y - (float)y0, wx = x - (float)x0;
    const float* dB = desc2 + ((size_t)b * C_ + c) * HW_;
    int i00 = y0 * W_ + x0;
    float v = dB[i00]          * (1.0f - wy) * (1.0f - wx)
            + dB[i00 + 1]      * (1.0f - wy) * wx
            + dB[i00 + W_]     * wy * (1.0f - wx)
            + dB[i00 + W_ + 1] * wy * wx;
    __shared__ float red[128];
    red[c] = v * v;
    __syncthreads();
    for (int s = 64; s > 0; s >>= 1) {
        if (c < s) red[c] += red[c + s];
        __syncthreads();
    }
    float nrm = sqrtf(red[0]);
    __syncthreads();
    float vn = v / (nrm + 1e-8f);
    w_desc[(size_t)bn * C_ + c] = vn;
    float qd = kp1_desc[(size_t)bn * C_ + c];
    red[c] = qd * vn;
    __syncthreads();
    for (int s = 64; s > 0; s >>= 1) {
        if (c < s) red[c] += red[c + s];
        __syncthreads();
    }
    if (c == 0) pos[bn] = 2.0f - 2.0f * red[0];
}

// ---------------------------------------------------------------------------
// Bitonic helpers (all-static register index networks)
// ---------------------------------------------------------------------------
__device__ inline void bitonic16_asc(float (&a)[16]) {
#pragma unroll
    for (int dd = 0; dd < 4; ++dd) {
        const int d = 8 >> dd;
#pragma unroll
        for (int i = 0; i < 16; ++i) {
            if ((i & d) == 0) {
                float lo = fminf(a[i], a[i + d]);
                float hi = fmaxf(a[i], a[i + d]);
                a[i] = lo; a[i + d] = hi;
            }
        }
    }
}

// ---------------------------------------------------------------------------
// K3: dsim = 2 - 2*(kp1_desc @ desc2f^T) + 5*neigh; per row smallest-16
// values; fos partial sum -> atomicAdd(acc[0]).
// R3=4 rows per block, T3=512 threads, each thread 8 groups of 4 cols.
// ---------------------------------------------------------------------------
#define T3 512
#define R3 4
__global__ __launch_bounds__(T3) void hqt_k3_dsim(
    const float* __restrict__ desc2, const float* __restrict__ kp1_desc,
    const int* __restrict__ wcc16, const float* __restrict__ pos,
    float* __restrict__ acc) {
    const int nb = N_ / R3;
    int b = blockIdx.x / nb;
    int n0 = (blockIdx.x % nb) * R3;
    int tid = threadIdx.x;
    __shared__ float qT[C_][R3];     // transposed row descriptors
    __shared__ int ids_s[R3][16];
    {
        int r = tid & 3, c = tid >> 2;   // T3 == R3*C_
        qT[c][r] = kp1_desc[(size_t)(b * N_ + n0 + r) * C_ + c];
    }
    if (tid < R3 * 16)
        ids_s[tid >> 4][tid & 15] = wcc16[(b * N_ + n0) * 16 + tid];
    __syncthreads();

    float top[R3][16];
#pragma unroll
    for (int r = 0; r < R3; ++r)
#pragma unroll
        for (int k = 0; k < 16; ++k) top[r][k] = 1e30f;

    const float* d2b = desc2 + (size_t)b * C_ * HW_;
#pragma unroll 1
    for (int g = 0; g < HW_ / (T3 * 4); ++g) {
        int j0 = (g * T3 + tid) * 4;
        float4 A0 = {0, 0, 0, 0}, A1 = {0, 0, 0, 0}, A2 = {0, 0, 0, 0}, A3 = {0, 0, 0, 0};
        for (int c = 0; c < C_; ++c) {
            float4 d = *reinterpret_cast<const float4*>(d2b + (size_t)c * HW_ + j0);
            float4 qv = *reinterpret_cast<const float4*>(&qT[c][0]);
            A0.x = fmaf(qv.x, d.x, A0.x); A0.y = fmaf(qv.x, d.y, A0.y);
            A0.z = fmaf(qv.x, d.z, A0.z); A0.w = fmaf(qv.x, d.w, A0.w);
            A1.x = fmaf(qv.y, d.x, A1.x); A1.y = fmaf(qv.y, d.y, A1.y);
            A1.z = fmaf(qv.y, d.z, A1.z); A1.w = fmaf(qv.y, d.w, A1.w);
            A2.x = fmaf(qv.z, d.x, A2.x); A2.y = fmaf(qv.z, d.y, A2.y);
            A2.z = fmaf(qv.z, d.z, A2.z); A2.w = fmaf(qv.z, d.w, A2.w);
            A3.x = fmaf(qv.w, d.x, A3.x); A3.y = fmaf(qv.w, d.y, A3.y);
            A3.z = fmaf(qv.w, d.z, A3.z); A3.w = fmaf(qv.w, d.w, A3.w);
        }
#pragma unroll
        for (int r = 0; r < R3; ++r) {
            float dots[4];
            dots[0] = (r == 0) ? A0.x : (r == 1) ? A1.x : (r == 2) ? A2.x : A3.x;
            dots[1] = (r == 0) ? A0.y : (r == 1) ? A1.y : (r == 2) ? A2.y : A3.y;
            dots[2] = (r == 0) ? A0.z : (r == 1) ? A1.z : (r == 2) ? A2.z : A3.z;
            dots[3] = (r == 0) ? A0.w : (r == 1) ? A1.w : (r == 2) ? A2.w : A3.w;
#pragma unroll
            for (int cc = 0; cc < 4; ++cc) {
                int j = j0 + cc;
                int cnt = 0;
#pragma unroll
                for (int i = 0; i < 16; ++i) cnt += (ids_s[r][i] == j) ? 1 : 0;
                float v = 2.0f - 2.0f * dots[cc] + 5.0f * (float)cnt;
                if (v < top[r][15]) {
#pragma unroll
                    for (int k = 0; k < 16; ++k) {
                        float o = top[r][k];
                        bool sm = v < o;
                        top[r][k] = sm ? v : o;
                        v = sm ? o : v;
                    }
                }
            }
        }
    }

    // tree merge of per-thread sorted-16 lists, one row at a time
    __shared__ float mv[T3][16];
#pragma unroll
    for (int r = 0; r < R3; ++r) {
        float a[16];
#pragma unroll
        for (int k = 0; k < 16; ++k) { a[k] = top[r][k]; mv[tid][k] = a[k]; }
        __syncthreads();
        for (int step = T3 / 2; step >= 1; step >>= 1) {
            if (tid < step) {
                // half-cleaner: own asc vs partner reversed, then re-sort
#pragma unroll
                for (int i = 0; i < 16; ++i)
                    a[i] = fminf(a[i], mv[tid + step][15 - i]);
                bitonic16_asc(a);
#pragma unroll
                for (int i = 0; i < 16; ++i) mv[tid][i] = a[i];
            }
            __syncthreads();
        }
        if (tid == 0) {
            float p = pos[b * N_ + n0 + r];
            float s = 0.0f;
#pragma unroll
            for (int k = 0; k < 16; ++k) {
                float xv = p - a[k] + 1.0f;
                xv = fmaxf(xv, 0.0f);
                s += xv * xv;
            }
            atomicAdd(acc + 0, s);
        }
        __syncthreads();
    }
}

// ---------------------------------------------------------------------------
// K4: k_sim/w_sim smallest-8 indices per row (512 cols), then sos term.
// One wave (64 lanes) per (b,n); lane handles 8 contiguous columns.
// ---------------------------------------------------------------------------
__device__ inline void insert8_vi(float (&av)[8], int (&ai)[8], float v, int id) {
    bool le = (v < av[7]) || (v == av[7] && id < ai[7]);
    if (!le) return;
#pragma unroll
    for (int k = 0; k < 8; ++k) {
        float ov = av[k]; int oi = ai[k];
        bool sm = (v < ov) || (v == ov && id < oi);
        av[k] = sm ? v : ov;  ai[k] = sm ? id : oi;
        v = sm ? ov : v;      id = sm ? oi : id;
    }
}

__device__ inline void bitonic8_pairs(float (&av)[8], int (&ai)[8]) {
#pragma unroll
    for (int dd = 0; dd < 3; ++dd) {
        const int d = 4 >> dd;
#pragma unroll
        for (int i = 0; i < 8; ++i) {
            if ((i & d) == 0) {
                bool sw = (av[i + d] < av[i]) ||
                          (av[i + d] == av[i] && ai[i + d] < ai[i]);
                float tv = av[i]; int ti = ai[i];
                av[i]     = sw ? av[i + d] : av[i];
                ai[i]     = sw ? ai[i + d] : ai[i];
                av[i + d] = sw ? tv : av[i + d];
                ai[i + d] = sw ? ti : ai[i + d];
            }
        }
    }
}

__global__ __launch_bounds__(64) void hqt_k4_sos(
    const float* __restrict__ kp1_desc, const float* __restrict__ w_desc,
    const int* __restrict__ cid4, const int* __restrict__ wcc16,
    const int* __restrict__ wid4, float* __restrict__ acc) {
    int bn = blockIdx.x;
    int b = bn / N_;
    int lane = threadIdx.x;
    __shared__ float qk[C_], qw[C_];
    for (int c = lane; c < C_; c += 64) {
        qk[c] = kp1_desc[(size_t)bn * C_ + c];
        qw[c] = w_desc[(size_t)bn * C_ + c];
    }
    __syncthreads();
    int nk[4];
#pragma unroll
    for (int i = 0; i < 4; ++i) nk[i] = cid4[4 * bn + i];
    int nw[16];
#pragma unroll
    for (int i = 0; i < 16; ++i) nw[i] = wcc16[16 * bn + i];

    float kv[8], wv[8]; int ki[8], wi[8];
#pragma unroll
    for (int k = 0; k < 8; ++k) {
        kv[k] = 1e30f; wv[k] = 1e30f; ki[k] = INT_MAX; wi[k] = INT_MAX;
    }
    const float* kb = kp1_desc + (size_t)b * N_ * C_;
    const float* wb = w_desc + (size_t)b * N_ * C_;
    for (int tt = 0; tt < 8; ++tt) {
        int m = lane * 8 + tt;
        const float* rk = kb + (size_t)m * C_;
        const float* rw = wb + (size_t)m * C_;
        float dk = 0.0f, dw = 0.0f;
        for (int c = 0; c < C_; c += 4) {
            float4 xk = *(const float4*)(rk + c);
            float4 xw = *(const float4*)(rw + c);
            dk += qk[c] * xk.x + qk[c + 1] * xk.y + qk[c + 2] * xk.z + qk[c + 3] * xk.w;
            dw += qw[c] * xw.x + qw[c + 1] * xw.y + qw[c + 2] * xw.z + qw[c + 3] * xw.w;
        }
        int4 mc = *(const int4*)(cid4 + 4 * (b * N_ + m));
        int ck = 0;
#pragma unroll
        for (int i = 0; i < 4; ++i) {
            int u = nk[i];
            ck += (u == mc.x) + (u == mc.y) + (u == mc.z) + (u == mc.w);
        }
        int4 mw = *(const int4*)(wid4 + 4 * (b * N_ + m));
        int cw = 0;
#pragma unroll
        for (int i = 0; i < 16; ++i) {
            int u = nw[i];
            cw += (u == mw.x) + (u == mw.y) + (u == mw.z) + (u == mw.w);
        }
        float vk = 2.0f - 2.0f * dk + 5.0f * (float)ck;
        float vw2 = 2.0f - 2.0f * dw + 5.0f * (float)cw;
        insert8_vi(kv, ki, vk, m);
        insert8_vi(wv, wi, vw2, m);
    }

    __shared__ float mvs[64][8];
    __shared__ int mis[64][8];
    __shared__ int fk[8], fw[8];

    // merge K lists
#pragma unroll
    for (int i = 0; i < 8; ++i) { mvs[lane][i] = kv[i]; mis[lane][i] = ki[i]; }
    __syncthreads();
    for (int step = 32; step >= 1; step >>= 1) {
        if (lane < step) {
            float bv[8]; int bix[8];
#pragma unroll
            for (int i = 0; i < 8; ++i) {
                bv[i] = mvs[lane + step][7 - i];
                bix[i] = mis[lane + step][7 - i];
            }
#pragma unroll
            for (int i = 0; i < 8; ++i) {
                bool ta = (kv[i] < bv[i]) || (kv[i] == bv[i] && ki[i] < bix[i]);
                kv[i] = ta ? kv[i] : bv[i];
                ki[i] = ta ? ki[i] : bix[i];
            }
            bitonic8_pairs(kv, ki);
#pragma unroll
            for (int i = 0; i < 8; ++i) { mvs[lane][i] = kv[i]; mis[lane][i] = ki[i]; }
        }
        __syncthreads();
    }
    if (lane < 8) fk[lane] = mis[0][lane];
    __syncthreads();

    // merge W lists (reuse buffers)
#pragma unroll
    for (int i = 0; i < 8; ++i) { mvs[lane][i] = wv[i]; mis[lane][i] = wi[i]; }
    __syncthreads();
    for (int step = 32; step >= 1; step >>= 1) {
        if (lane < step) {
            float bv[8]; int bix[8];
#pragma unroll
            for (int i = 0; i < 8; ++i) {
                bv[i] = mvs[lane + step][7 - i];
                bix[i] = mis[lane + step][7 - i];
            }
#pragma unroll
            for (int i = 0; i < 8; ++i) {
                bool ta = (wv[i] < bv[i]) || (wv[i] == bv[i] && wi[i] < bix[i]);
                wv[i] = ta ? wv[i] : bv[i];
                wi[i] = ta ? wi[i] : bix[i];
            }
            bitonic8_pairs(wv, wi);
#pragma unroll
            for (int i = 0; i < 8; ++i) { mvs[lane][i] = wv[i]; mis[lane][i] = wi[i]; }
        }
        __syncthreads();
    }
    if (lane < 8) fw[lane] = mis[0][lane];
    __syncthreads();

    // clean dots for the 8 selected neighbors (no mask term): sos term
    int s = lane >> 3, p = lane & 7;
    const float* rk = kb + (size_t)fk[s] * C_;
    const float* rw = wb + (size_t)fw[s] * C_;
    float dk = 0.0f, dw = 0.0f;
    for (int c = p; c < C_; c += 8) {
        dk += qk[c] * rk[c];
        dw += qw[c] * rw[c];
    }
    dk += __shfl_xor(dk, 1); dk += __shfl_xor(dk, 2); dk += __shfl_xor(dk, 4);
    dw += __shfl_xor(dw, 1); dw += __shfl_xor(dw, 2); dw += __shfl_xor(dw, 4);
    __shared__ float tsq[8];
    if (p == 0) {
        float t2 = 2.0f * (dw - dk);   // sos_v = (2-2dk) - (2-2dw)
        tsq[s] = t2 * t2;
    }
    __syncthreads();
    if (lane == 0) {
        float s8 = 0.0f;
#pragma unroll
        for (int i = 0; i < 8; ++i) s8 += tsq[i];
        atomicAdd(acc + 1, sqrtf(s8));
    }
}

// ---------------------------------------------------------------------------
// K5: finalize scalar
// ---------------------------------------------------------------------------
__global__ void hqt_k5_final(const float* __restrict__ acc, float* __restrict__ out) {
    if (threadIdx.x == 0 && blockIdx.x == 0) {
        out[0] = acc[0] * (1.0f / (float)(B_ * N_ * NUM_NEG_))
               + acc[1] * (1.0f / (float)(B_ * N_));
    }
}

extern "C" void kernel_launch(void* const* d_in, const int* in_sizes, int n_in,
                              void* d_out, int out_size, void* d_ws, size_t ws_size,
                              hipStream_t stream) {
    const float* kp1      = (const float*)d_in[0];
    const float* w_kp1    = (const float*)d_in[1];
    const float* kp1_desc = (const float*)d_in[2];
    const float* desc2    = (const float*)d_in[3];
    const float* homo     = (const float*)d_in[4];
    float* out = (float*)d_out;

    // workspace layout (all 16B-aligned slices)
    float* w_desc = (float*)d_ws;                       // B*N*C
    float* pos    = w_desc + (size_t)B_ * N_ * C_;      // B*N
    int*   cid4   = (int*)(pos + B_ * N_);              // B*N*4
    int*   wid4   = cid4 + B_ * N_ * 4;                 // B*N*4
    int*   wcc16  = wid4 + B_ * N_ * 4;                 // B*N*16
    float* acc    = (float*)(wcc16 + B_ * N_ * 16);     // 2 accumulators

    hipMemsetAsync(acc, 0, 2 * sizeof(float), stream);

    hqt_k1_cells<<<(B_ * N_ + 255) / 256, 256, 0, stream>>>(
        kp1, w_kp1, homo, cid4, wcc16, wid4);
    hqt_k2_sample<<<B_ * N_, 128, 0, stream>>>(
        w_kp1, desc2, kp1_desc, w_desc, pos);
    hqt_k3_dsim<<<B_ * (N_ / R3), T3, 0, stream>>>(
        desc2, kp1_desc, wcc16, pos, acc);
    hqt_k4_sos<<<B_ * N_, 64, 0, stream>>>(
        kp1_desc, w_desc, cid4, wcc16, wid4, acc);
    hqt_k5_final<<<1, 1, 0, stream>>>(acc, out);
}

// Round 2
// 206.409 us; speedup vs baseline: 1.3410x; 1.3410x over previous
//
#include <hip/hip_runtime.h>
#include <climits>

#define B_ 2
#define N_ 512
#define C_ 128
#define H_ 128
#define W_ 128
#define HW_ (H_ * W_)
#define NUM_NEG_ 16
#define SOS_NEG_ 8
#define SCAP_ 128   // survivor cap per row

typedef __attribute__((ext_vector_type(8))) short short8;
typedef __attribute__((ext_vector_type(4))) float f32x4;

__device__ inline unsigned int f2bf(float x) {
    unsigned int u = __float_as_uint(x);
    return (u + 0x7FFFu + ((u >> 16) & 1u)) >> 16;
}
__device__ inline float bf2f(unsigned int h) {
    return __uint_as_float(h << 16);
}

// ---------------------------------------------------------------------------
// 4 nearest grid-cell centers of point (y,x). Cell (yi,xi) center at
// (8*yi+4, 8*xi+4), id = yi*128+xi. 4-nearest always in clamped 4x4 window;
// tie-break (dist, then lower id) matches lax.top_k.
// ---------------------------------------------------------------------------
__device__ inline void nearest4(float y, float x, int out[4]) {
    y = fminf(fmaxf(y, -1e6f), 1e6f);
    x = fminf(fmaxf(x, -1e6f), 1e6f);
    int fy = (int)floorf(y * 0.125f - 0.5f);
    int fx = (int)floorf(x * 0.125f - 0.5f);
    int ylo = fy - 1; if (ylo < 0) ylo = 0; if (ylo > H_ - 4) ylo = H_ - 4;
    int xlo = fx - 1; if (xlo < 0) xlo = 0; if (xlo > W_ - 4) xlo = W_ - 4;
    float bd[4] = {1e30f, 1e30f, 1e30f, 1e30f};
    int   bi[4] = {INT_MAX, INT_MAX, INT_MAX, INT_MAX};
#pragma unroll
    for (int dyi = 0; dyi < 4; ++dyi) {
        int yi = ylo + dyi;
        float dy = y - (8.0f * yi + 4.0f);
        float dy2 = dy * dy;
#pragma unroll
        for (int dxi = 0; dxi < 4; ++dxi) {
            int xi = xlo + dxi;
            float dx = x - (8.0f * xi + 4.0f);
            float d = dy2 + dx * dx;
            int id = yi * W_ + xi;
#pragma unroll
            for (int k = 0; k < 4; ++k) {
                bool sm = (d < bd[k]) || (d == bd[k] && id < bi[k]);
                float od = bd[k]; int oi = bi[k];
                bd[k] = sm ? d : od;  bi[k] = sm ? id : oi;
                d = sm ? od : d;      id = sm ? oi : id;
            }
        }
    }
    out[0] = bi[0]; out[1] = bi[1]; out[2] = bi[2]; out[3] = bi[3];
}

__device__ inline void k1_body(int t, const float* kp1, const float* w_kp1,
                               const float* homo, int* cid4, int* wcc16,
                               int* wid4, unsigned int* marked) {
    int b = t / N_;
    float ky = kp1[2 * t], kx = kp1[2 * t + 1];
    int ids[4];
    nearest4(ky, kx, ids);
    const float* Hb = homo + 9 * b;
    float h00 = Hb[0], h01 = Hb[1], h02 = Hb[2];
    float h10 = Hb[3], h11 = Hb[4], h12 = Hb[5];
    float h20 = Hb[6], h21 = Hb[7], h22 = Hb[8];
    int w16[16];
#pragma unroll
    for (int i = 0; i < 4; ++i) {
        int id = ids[i];
        cid4[4 * t + i] = id;
        float cy = 8.0f * (id >> 7) + 4.0f;
        float cx = 8.0f * (id & 127) + 4.0f;
        float X = cx, Y = cy;
        float wz = h20 * X + h21 * Y + h22;
        float inv = 1.0f / (wz + 1e-8f);
        float wy = (h10 * X + h11 * Y + h12) * inv;
        float wx = (h00 * X + h01 * Y + h02) * inv;
        int wids[4];
        nearest4(wy, wx, wids);
#pragma unroll
        for (int j = 0; j < 4; ++j) {
            w16[4 * i + j] = wids[j];
            wcc16[16 * t + 4 * i + j] = wids[j];
        }
    }
    // dedup with multiplicity: slot i canonical iff first occurrence
#pragma unroll
    for (int i = 0; i < 16; ++i) {
        int cnt = 0; bool first = true;
#pragma unroll
        for (int j = 0; j < 16; ++j) {
            bool eq = (w16[j] == w16[i]);
            cnt += eq ? 1 : 0;
            if (j < i && eq) first = false;
        }
        marked[16 * t + i] = first ? ((unsigned int)w16[i] | ((unsigned int)cnt << 16))
                                   : 0xFFFFFFFFu;
    }
    float zy = w_kp1[2 * t], zx = w_kp1[2 * t + 1];
    int wi4[4];
    nearest4(zy, zx, wi4);
#pragma unroll
    for (int j = 0; j < 4; ++j) wid4[4 * t + j] = wi4[j];
}

// ---------------------------------------------------------------------------
// K0 fused: [0,1024) transpose+convert desc2 -> d2t_bf[b][j][c];
// [1024,1152) convert kp1_desc -> q_bf; 1152 zero scnt/acc; [1153,1157) k1.
// ---------------------------------------------------------------------------
__global__ __launch_bounds__(256) void hqt_k0(
    const float* __restrict__ desc2, const float* __restrict__ kp1_desc,
    const float* __restrict__ kp1, const float* __restrict__ w_kp1,
    const float* __restrict__ homo,
    unsigned short* __restrict__ d2t, unsigned short* __restrict__ q_bf,
    int* __restrict__ cid4, int* __restrict__ wcc16, int* __restrict__ wid4,
    unsigned int* __restrict__ marked, int* __restrict__ scnt,
    float* __restrict__ acc) {
    int blk = blockIdx.x;
    int tid = threadIdx.x;
    if (blk < 1024) {
        __shared__ float tile[32][129];
        int b = blk >> 9;
        int j0 = (blk & 511) * 32;
        int jj = tid & 31, cg = tid >> 5;
        const float* src = desc2 + (size_t)b * C_ * HW_;
#pragma unroll
        for (int cc = 0; cc < 16; ++cc) {
            int c = cg * 16 + cc;
            tile[jj][c] = src[(size_t)c * HW_ + j0 + jj];
        }
        __syncthreads();
        int row = tid >> 3, c8 = (tid & 7) * 16;
        unsigned int tmp[16];
#pragma unroll
        for (int k = 0; k < 16; ++k) tmp[k] = f2bf(tile[row][c8 + k]);
        uint4 o0, o1;
        o0.x = tmp[0] | (tmp[1] << 16);  o0.y = tmp[2] | (tmp[3] << 16);
        o0.z = tmp[4] | (tmp[5] << 16);  o0.w = tmp[6] | (tmp[7] << 16);
        o1.x = tmp[8] | (tmp[9] << 16);  o1.y = tmp[10] | (tmp[11] << 16);
        o1.z = tmp[12] | (tmp[13] << 16); o1.w = tmp[14] | (tmp[15] << 16);
        unsigned short* dst = d2t + ((size_t)(b << 14) + j0 + row) * C_ + c8;
        ((uint4*)dst)[0] = o0;
        ((uint4*)dst)[1] = o1;
    } else if (blk < 1152) {
        int idx = (blk - 1024) * 256 + tid;   // 4 elems each, 131072 total
        float4 v = *(const float4*)(kp1_desc + (size_t)idx * 4);
        uint2 u;
        u.x = f2bf(v.x) | (f2bf(v.y) << 16);
        u.y = f2bf(v.z) | (f2bf(v.w) << 16);
        *(uint2*)(q_bf + (size_t)idx * 4) = u;
    } else if (blk == 1152) {
        ((int4*)scnt)[tid] = make_int4(0, 0, 0, 0);
        if (tid == 0) { acc[0] = 0.0f; acc[1] = 0.0f; }
    } else {
        int t = (blk - 1153) * 256 + tid;
        if (t < B_ * N_)
            k1_body(t, kp1, w_kp1, homo, cid4, wcc16, wid4, marked);
    }
}

// ---------------------------------------------------------------------------
// K2: bilinear-sample desc2 at w_kp1, normalize -> w_desc; pos = 2-2*dot.
// ---------------------------------------------------------------------------
__global__ __launch_bounds__(128) void hqt_k2_sample(
    const float* __restrict__ w_kp1, const float* __restrict__ desc2,
    const float* __restrict__ kp1_desc, float* __restrict__ w_desc,
    float* __restrict__ pos) {
    int bn = blockIdx.x;
    int b = bn / N_;
    int c = threadIdx.x;
    float ky = w_kp1[2 * bn], kx = w_kp1[2 * bn + 1];
    float y = fminf(fmaxf(ky * 0.125f - 0.5f, 0.0f), (float)(H_ - 1));
    float x = fminf(fmaxf(kx * 0.125f - 0.5f, 0.0f), (float)(W_ - 1));
    int y0 = (int)floorf(y); if (y0 > H_ - 2) y0 = H_ - 2;
    int x0 = (int)floorf(x); if (x0 > W_ - 2) x0 = W_ - 2;
    float wy = y - (float)y0, wx = x - (float)x0;
    const float* dB = desc2 + ((size_t)b * C_ + c) * HW_;
    int i00 = y0 * W_ + x0;
    float v = dB[i00]          * (1.0f - wy) * (1.0f - wx)
            + dB[i00 + 1]      * (1.0f - wy) * wx
            + dB[i00 + W_]     * wy * (1.0f - wx)
            + dB[i00 + W_ + 1] * wy * wx;
    __shared__ float red[128];
    red[c] = v * v;
    __syncthreads();
    for (int s = 64; s > 0; s >>= 1) {
        if (c < s) red[c] += red[c + s];
        __syncthreads();
    }
    float nrm = sqrtf(red[0]);
    __syncthreads();
    float vn = v / (nrm + 1e-8f);
    w_desc[(size_t)bn * C_ + c] = vn;
    float qd = kp1_desc[(size_t)bn * C_ + c];
    red[c] = qd * vn;
    __syncthreads();
    for (int s = 64; s > 0; s >>= 1) {
        if (c < s) red[c] += red[c + s];
        __syncthreads();
    }
    if (c == 0) pos[bn] = 2.0f - 2.0f * red[0];
}

// ---------------------------------------------------------------------------
// K3a: MFMA pass 1. Block: 64 rows x 1024 cols, 8 waves (128 cols each).
// Per (row, 128-col window) write max dot to rowmax[row][chunk] (128 chunks).
// ---------------------------------------------------------------------------
__global__ __launch_bounds__(512) void hqt_k3a(
    const unsigned short* __restrict__ q_bf,
    const unsigned short* __restrict__ d2t,
    float* __restrict__ rowmax) {
    int blk = blockIdx.x;           // 256 = 2b x 8rg x 16cb
    int b = blk >> 7;
    int rg = (blk >> 4) & 7;
    int cb = blk & 15;
    int tid = threadIdx.x, w = tid >> 6, l = tid & 63;
    int l15 = l & 15, lg = l >> 4;
    int rowbase = rg * 64;
    int colbase = cb * 1024 + w * 128;
    const unsigned short* qb = q_bf + (size_t)b * N_ * C_;
    const unsigned short* db = d2t + (size_t)b * HW_ * C_;
    short8 a[4][4];
#pragma unroll
    for (int rt = 0; rt < 4; ++rt)
#pragma unroll
        for (int ks = 0; ks < 4; ++ks)
            a[rt][ks] = *(const short8*)(qb + (size_t)(rowbase + rt * 16 + l15) * C_ + ks * 32 + lg * 8);
    f32x4 mx[4];
#pragma unroll
    for (int rt = 0; rt < 4; ++rt) mx[rt] = f32x4{-1e30f, -1e30f, -1e30f, -1e30f};
#pragma unroll
    for (int t = 0; t < 8; ++t) {
        const unsigned short* dp = db + (size_t)(colbase + t * 16 + l15) * C_ + lg * 8;
        short8 b0 = *(const short8*)(dp);
        short8 b1 = *(const short8*)(dp + 32);
        short8 b2 = *(const short8*)(dp + 64);
        short8 b3 = *(const short8*)(dp + 96);
#pragma unroll
        for (int rt = 0; rt < 4; ++rt) {
            f32x4 acc4 = {0.0f, 0.0f, 0.0f, 0.0f};
            acc4 = __builtin_amdgcn_mfma_f32_16x16x32_bf16(a[rt][0], b0, acc4, 0, 0, 0);
            acc4 = __builtin_amdgcn_mfma_f32_16x16x32_bf16(a[rt][1], b1, acc4, 0, 0, 0);
            acc4 = __builtin_amdgcn_mfma_f32_16x16x32_bf16(a[rt][2], b2, acc4, 0, 0, 0);
            acc4 = __builtin_amdgcn_mfma_f32_16x16x32_bf16(a[rt][3], b3, acc4, 0, 0, 0);
#pragma unroll
            for (int r = 0; r < 4; ++r) mx[rt][r] = fmaxf(mx[rt][r], acc4[r]);
        }
    }
#pragma unroll
    for (int rt = 0; rt < 4; ++rt)
#pragma unroll
        for (int r = 0; r < 4; ++r) {
            float v = mx[rt][r];
            v = fmaxf(v, __shfl_xor(v, 1));
            v = fmaxf(v, __shfl_xor(v, 2));
            v = fmaxf(v, __shfl_xor(v, 4));
            v = fmaxf(v, __shfl_xor(v, 8));
            mx[rt][r] = v;
        }
    if (l15 == 0) {
        int chunk = cb * 8 + w;
#pragma unroll
        for (int rt = 0; rt < 4; ++rt)
#pragma unroll
            for (int r = 0; r < 4; ++r) {
                int rowg = b * N_ + rowbase + rt * 16 + lg * 4 + r;
                rowmax[(size_t)rowg * 128 + chunk] = mx[rt][r];
            }
    }
}

// ---------------------------------------------------------------------------
// K3b: per row, t = 32nd-largest of 128 window maxes (via 64 pair-maxes).
// Guarantees >=32 dots >= t  =>  >=16 unmarked survivors.
// ---------------------------------------------------------------------------
__global__ __launch_bounds__(256) void hqt_k3b(
    const float* __restrict__ rowmax, float* __restrict__ t32) {
    int w = threadIdx.x >> 6, l = threadIdx.x & 63;
    int row = blockIdx.x * 4 + w;
    const float* rm = rowmax + (size_t)row * 128;
    float v = fmaxf(rm[l], rm[64 + l]);
    float t = -1e30f;
#pragma unroll 1
    for (int it = 0; it < 32; ++it) {
        float m = v;
        m = fmaxf(m, __shfl_xor(m, 1));
        m = fmaxf(m, __shfl_xor(m, 2));
        m = fmaxf(m, __shfl_xor(m, 4));
        m = fmaxf(m, __shfl_xor(m, 8));
        m = fmaxf(m, __shfl_xor(m, 16));
        m = fmaxf(m, __shfl_xor(m, 32));
        v = (v == m) ? -1e30f : v;
        t = m;
    }
    if (l == 0) t32[row] = t;
}

// ---------------------------------------------------------------------------
// K3c: MFMA pass 2: push (dot, col) with dot >= t[row] into survivor buffer.
// ---------------------------------------------------------------------------
__global__ __launch_bounds__(512) void hqt_k3c(
    const unsigned short* __restrict__ q_bf,
    const unsigned short* __restrict__ d2t,
    const float* __restrict__ t32,
    int* __restrict__ scnt, float2* __restrict__ sbuf) {
    int blk = blockIdx.x;
    int b = blk >> 7;
    int rg = (blk >> 4) & 7;
    int cb = blk & 15;
    int tid = threadIdx.x, w = tid >> 6, l = tid & 63;
    int l15 = l & 15, lg = l >> 4;
    int rowbase = rg * 64;
    int colbase = cb * 1024 + w * 128;
    const unsigned short* qb = q_bf + (size_t)b * N_ * C_;
    const unsigned short* db = d2t + (size_t)b * HW_ * C_;
    short8 a[4][4];
#pragma unroll
    for (int rt = 0; rt < 4; ++rt)
#pragma unroll
        for (int ks = 0; ks < 4; ++ks)
            a[rt][ks] = *(const short8*)(qb + (size_t)(rowbase + rt * 16 + l15) * C_ + ks * 32 + lg * 8);
    float tl[4][4];
#pragma unroll
    for (int rt = 0; rt < 4; ++rt)
#pragma unroll
        for (int r = 0; r < 4; ++r)
            tl[rt][r] = t32[b * N_ + rowbase + rt * 16 + lg * 4 + r];
#pragma unroll
    for (int t = 0; t < 8; ++t) {
        const unsigned short* dp = db + (size_t)(colbase + t * 16 + l15) * C_ + lg * 8;
        short8 b0 = *(const short8*)(dp);
        short8 b1 = *(const short8*)(dp + 32);
        short8 b2 = *(const short8*)(dp + 64);
        short8 b3 = *(const short8*)(dp + 96);
#pragma unroll
        for (int rt = 0; rt < 4; ++rt) {
            f32x4 acc4 = {0.0f, 0.0f, 0.0f, 0.0f};
            acc4 = __builtin_amdgcn_mfma_f32_16x16x32_bf16(a[rt][0], b0, acc4, 0, 0, 0);
            acc4 = __builtin_amdgcn_mfma_f32_16x16x32_bf16(a[rt][1], b1, acc4, 0, 0, 0);
            acc4 = __builtin_amdgcn_mfma_f32_16x16x32_bf16(a[rt][2], b2, acc4, 0, 0, 0);
            acc4 = __builtin_amdgcn_mfma_f32_16x16x32_bf16(a[rt][3], b3, acc4, 0, 0, 0);
#pragma unroll
            for (int r = 0; r < 4; ++r) {
                float d = acc4[r];
                if (d >= tl[rt][r]) {
                    int rowg = b * N_ + rowbase + rt * 16 + lg * 4 + r;
                    int idx = atomicAdd(scnt + rowg, 1);
                    if (idx < SCAP_) {
                        float2 e;
                        e.x = d;
                        e.y = __int_as_float(colbase + t * 16 + l15);
                        sbuf[(size_t)rowg * SCAP_ + idx] = e;
                    }
                }
            }
        }
    }
}

// ---------------------------------------------------------------------------
// K3d: one wave per row. Exclude marked cols from survivors, add marked cols
// with exact keys (dot - 2.5*cnt), extract top-16 keys, accumulate fos.
// ---------------------------------------------------------------------------
__global__ __launch_bounds__(256) void hqt_k3d(
    const unsigned short* __restrict__ q_bf,
    const unsigned short* __restrict__ d2t,
    const unsigned int* __restrict__ marked,
    const int* __restrict__ scnt, const float2* __restrict__ sbuf,
    const float* __restrict__ pos, float* __restrict__ acc) {
    int w = threadIdx.x >> 6, l = threadIdx.x & 63;
    int row = blockIdx.x * 4 + w;
    int b = row >> 9;
    int sc = scnt[row]; if (sc > SCAP_) sc = SCAP_;
    float k0 = -1e30f, k1 = -1e30f, k2c = -1e30f;
    int c0 = -1, c1 = -1;
    if (l < sc) {
        float2 e = sbuf[(size_t)row * SCAP_ + l];
        k0 = e.x; c0 = __float_as_int(e.y);
    }
    if (64 + l < sc) {
        float2 e = sbuf[(size_t)row * SCAP_ + 64 + l];
        k1 = e.x; c1 = __float_as_int(e.y);
    }
    // exclude marked columns from survivors (sentinel id 0xFFFF never matches)
#pragma unroll
    for (int i = 0; i < 16; ++i) {
        unsigned int mv = marked[row * 16 + i];
        int id = (int)(mv & 0xFFFFu);
        if (c0 == id) k0 = -1e30f;
        if (c1 == id) k1 = -1e30f;
    }
    // marked candidates: lane groups of 4 per marked slot
    {
        int mi = l >> 2, cq = l & 3;
        unsigned int mv = marked[row * 16 + mi];
        bool valid = (mv != 0xFFFFFFFFu);
        int col = valid ? (int)(mv & 0xFFFFu) : 0;
        int cnt = (int)(mv >> 16);
        const unsigned short* qp = q_bf + (size_t)row * C_ + cq * 32;
        const unsigned short* dp = d2t + ((size_t)b * HW_ + col) * C_ + cq * 32;
        float dot = 0.0f;
#pragma unroll
        for (int u = 0; u < 4; ++u) {
            short8 qv = *(const short8*)(qp + u * 8);
            short8 dv = *(const short8*)(dp + u * 8);
#pragma unroll
            for (int e = 0; e < 8; ++e)
                dot = fmaf(bf2f((unsigned short)qv[e]), bf2f((unsigned short)dv[e]), dot);
        }
        dot += __shfl_xor(dot, 1);
        dot += __shfl_xor(dot, 2);
        k2c = (valid && cq == 0) ? (dot - 2.5f * (float)cnt) : -1e30f;
    }
    float pos_r = pos[row];
    float sum = 0.0f;
#pragma unroll 1
    for (int it = 0; it < 16; ++it) {
        float v = fmaxf(k0, fmaxf(k1, k2c));
        float m = v;
        m = fmaxf(m, __shfl_xor(m, 1));
        m = fmaxf(m, __shfl_xor(m, 2));
        m = fmaxf(m, __shfl_xor(m, 4));
        m = fmaxf(m, __shfl_xor(m, 8));
        m = fmaxf(m, __shfl_xor(m, 16));
        m = fmaxf(m, __shfl_xor(m, 32));
        unsigned long long b0 = __ballot(k0 == m);
        if (b0) {
            if (l == __ffsll(b0) - 1) k0 = -1e30f;
        } else {
            unsigned long long b1 = __ballot(k1 == m);
            if (b1) {
                if (l == __ffsll(b1) - 1) k1 = -1e30f;
            } else {
                unsigned long long b2 = __ballot(k2c == m);
                if (l == __ffsll(b2) - 1) k2c = -1e30f;
            }
        }
        float h = pos_r + 2.0f * m - 1.0f;   // pos - (2-2m) + 1
        h = fmaxf(h, 0.0f);
        sum += h * h;
    }
    if (l == 0) atomicAdd(acc + 0, sum);
}

// ---------------------------------------------------------------------------
// K4: k_sim/w_sim smallest-8 ids per row, then sos term. (unchanged + pad)
// ---------------------------------------------------------------------------
__device__ inline void insert8_vi(float (&av)[8], int (&ai)[8], float v, int id) {
    bool le = (v < av[7]) || (v == av[7] && id < ai[7]);
    if (!le) return;
#pragma unroll
    for (int k = 0; k < 8; ++k) {
        float ov = av[k]; int oi = ai[k];
        bool sm = (v < ov) || (v == ov && id < oi);
        av[k] = sm ? v : ov;  ai[k] = sm ? id : oi;
        v = sm ? ov : v;      id = sm ? oi : id;
    }
}

__device__ inline void bitonic8_pairs(float (&av)[8], int (&ai)[8]) {
#pragma unroll
    for (int dd = 0; dd < 3; ++dd) {
        const int d = 4 >> dd;
#pragma unroll
        for (int i = 0; i < 8; ++i) {
            if ((i & d) == 0) {
                bool sw = (av[i + d] < av[i]) ||
                          (av[i + d] == av[i] && ai[i + d] < ai[i]);
                float tv = av[i]; int ti = ai[i];
                av[i]     = sw ? av[i + d] : av[i];
                ai[i]     = sw ? ai[i + d] : ai[i];
                av[i + d] = sw ? tv : av[i + d];
                ai[i + d] = sw ? ti : ai[i + d];
            }
        }
    }
}

__global__ __launch_bounds__(64) void hqt_k4_sos(
    const float* __restrict__ kp1_desc, const float* __restrict__ w_desc,
    const int* __restrict__ cid4, const int* __restrict__ wcc16,
    const int* __restrict__ wid4, float* __restrict__ acc) {
    int bn = blockIdx.x;
    int b = bn / N_;
    int lane = threadIdx.x;
    __shared__ float qk[C_], qw[C_];
    for (int c = lane; c < C_; c += 64) {
        qk[c] = kp1_desc[(size_t)bn * C_ + c];
        qw[c] = w_desc[(size_t)bn * C_ + c];
    }
    __syncthreads();
    int nk[4];
#pragma unroll
    for (int i = 0; i < 4; ++i) nk[i] = cid4[4 * bn + i];
    int nw[16];
#pragma unroll
    for (int i = 0; i < 16; ++i) nw[i] = wcc16[16 * bn + i];

    float kv[8], wv[8]; int ki[8], wi[8];
#pragma unroll
    for (int k = 0; k < 8; ++k) {
        kv[k] = 1e30f; wv[k] = 1e30f; ki[k] = INT_MAX; wi[k] = INT_MAX;
    }
    const float* kb = kp1_desc + (size_t)b * N_ * C_;
    const float* wb = w_desc + (size_t)b * N_ * C_;
    for (int tt = 0; tt < 8; ++tt) {
        int m = lane * 8 + tt;
        const float* rk = kb + (size_t)m * C_;
        const float* rw = wb + (size_t)m * C_;
        float dk = 0.0f, dw = 0.0f;
        for (int c = 0; c < C_; c += 4) {
            float4 xk = *(const float4*)(rk + c);
            float4 xw = *(const float4*)(rw + c);
            dk += qk[c] * xk.x + qk[c + 1] * xk.y + qk[c + 2] * xk.z + qk[c + 3] * xk.w;
            dw += qw[c] * xw.x + qw[c + 1] * xw.y + qw[c + 2] * xw.z + qw[c + 3] * xw.w;
        }
        int4 mc = *(const int4*)(cid4 + 4 * (b * N_ + m));
        int ck = 0;
#pragma unroll
        for (int i = 0; i < 4; ++i) {
            int u = nk[i];
            ck += (u == mc.x) + (u == mc.y) + (u == mc.z) + (u == mc.w);
        }
        int4 mw = *(const int4*)(wid4 + 4 * (b * N_ + m));
        int cw = 0;
#pragma unroll
        for (int i = 0; i < 16; ++i) {
            int u = nw[i];
            cw += (u == mw.x) + (u == mw.y) + (u == mw.z) + (u == mw.w);
        }
        float vk = 2.0f - 2.0f * dk + 5.0f * (float)ck;
        float vw2 = 2.0f - 2.0f * dw + 5.0f * (float)cw;
        insert8_vi(kv, ki, vk, m);
        insert8_vi(wv, wi, vw2, m);
    }

    __shared__ float mvs[64][9];
    __shared__ int mis[64][9];
    __shared__ int fk[8], fw[8];

#pragma unroll
    for (int i = 0; i < 8; ++i) { mvs[lane][i] = kv[i]; mis[lane][i] = ki[i]; }
    __syncthreads();
    for (int step = 32; step >= 1; step >>= 1) {
        if (lane < step) {
            float bv[8]; int bix[8];
#pragma unroll
            for (int i = 0; i < 8; ++i) {
                bv[i] = mvs[lane + step][7 - i];
                bix[i] = mis[lane + step][7 - i];
            }
#pragma unroll
            for (int i = 0; i < 8; ++i) {
                bool ta = (kv[i] < bv[i]) || (kv[i] == bv[i] && ki[i] < bix[i]);
                kv[i] = ta ? kv[i] : bv[i];
                ki[i] = ta ? ki[i] : bix[i];
            }
            bitonic8_pairs(kv, ki);
#pragma unroll
            for (int i = 0; i < 8; ++i) { mvs[lane][i] = kv[i]; mis[lane][i] = ki[i]; }
        }
        __syncthreads();
    }
    if (lane < 8) fk[lane] = mis[0][lane];
    __syncthreads();

#pragma unroll
    for (int i = 0; i < 8; ++i) { mvs[lane][i] = wv[i]; mis[lane][i] = wi[i]; }
    __syncthreads();
    for (int step = 32; step >= 1; step >>= 1) {
        if (lane < step) {
            float bv[8]; int bix[8];
#pragma unroll
            for (int i = 0; i < 8; ++i) {
                bv[i] = mvs[lane + step][7 - i];
                bix[i] = mis[lane + step][7 - i];
            }
#pragma unroll
            for (int i = 0; i < 8; ++i) {
                bool ta = (wv[i] < bv[i]) || (wv[i] == bv[i] && wi[i] < bix[i]);
                wv[i] = ta ? wv[i] : bv[i];
                wi[i] = ta ? wi[i] : bix[i];
            }
            bitonic8_pairs(wv, wi);
#pragma unroll
            for (int i = 0; i < 8; ++i) { mvs[lane][i] = wv[i]; mis[lane][i] = wi[i]; }
        }
        __syncthreads();
    }
    if (lane < 8) fw[lane] = mis[0][lane];
    __syncthreads();

    int s = lane >> 3, p = lane & 7;
    const float* rk = kb + (size_t)fk[s] * C_;
    const float* rw = wb + (size_t)fw[s] * C_;
    float dk = 0.0f, dw = 0.0f;
    for (int c = p; c < C_; c += 8) {
        dk += qk[c] * rk[c];
        dw += qw[c] * rw[c];
    }
    dk += __shfl_xor(dk, 1); dk += __shfl_xor(dk, 2); dk += __shfl_xor(dk, 4);
    dw += __shfl_xor(dw, 1); dw += __shfl_xor(dw, 2); dw += __shfl_xor(dw, 4);
    __shared__ float tsq[8];
    if (p == 0) {
        float t2 = 2.0f * (dw - dk);
        tsq[s] = t2 * t2;
    }
    __syncthreads();
    if (lane == 0) {
        float s8 = 0.0f;
#pragma unroll
        for (int i = 0; i < 8; ++i) s8 += tsq[i];
        atomicAdd(acc + 1, sqrtf(s8));
    }
}

__global__ void hqt_k5_final(const float* __restrict__ acc, float* __restrict__ out) {
    if (threadIdx.x == 0 && blockIdx.x == 0) {
        out[0] = acc[0] * (1.0f / (float)(B_ * N_ * NUM_NEG_))
               + acc[1] * (1.0f / (float)(B_ * N_));
    }
}

// ======================= fallback (round-1) k1/k3 ==========================
__global__ void hqt_k1_cells(const float* __restrict__ kp1,
                             const float* __restrict__ w_kp1,
                             const float* __restrict__ homo,
                             int* __restrict__ cid4,
                             int* __restrict__ wcc16,
                             int* __restrict__ wid4) {
    int t = blockIdx.x * blockDim.x + threadIdx.x;
    if (t >= B_ * N_) return;
    int b = t / N_;
    float ky = kp1[2 * t], kx = kp1[2 * t + 1];
    int ids[4];
    nearest4(ky, kx, ids);
    const float* Hb = homo + 9 * b;
    float h00 = Hb[0], h01 = Hb[1], h02 = Hb[2];
    float h10 = Hb[3], h11 = Hb[4], h12 = Hb[5];
    float h20 = Hb[6], h21 = Hb[7], h22 = Hb[8];
#pragma unroll
    for (int i = 0; i < 4; ++i) {
        int id = ids[i];
        cid4[4 * t + i] = id;
        float cy = 8.0f * (id >> 7) + 4.0f;
        float cx = 8.0f * (id & 127) + 4.0f;
        float X = cx, Y = cy;
        float wz = h20 * X + h21 * Y + h22;
        float inv = 1.0f / (wz + 1e-8f);
        float wy = (h10 * X + h11 * Y + h12) * inv;
        float wx = (h00 * X + h01 * Y + h02) * inv;
        int wids[4];
        nearest4(wy, wx, wids);
#pragma unroll
        for (int j = 0; j < 4; ++j) wcc16[16 * t + 4 * i + j] = wids[j];
    }
    float zy = w_kp1[2 * t], zx = w_kp1[2 * t + 1];
    int wi4[4];
    nearest4(zy, zx, wi4);
#pragma unroll
    for (int j = 0; j < 4; ++j) wid4[4 * t + j] = wi4[j];
}

__device__ inline void bitonic16_asc(float (&a)[16]) {
#pragma unroll
    for (int dd = 0; dd < 4; ++dd) {
        const int d = 8 >> dd;
#pragma unroll
        for (int i = 0; i < 16; ++i) {
            if ((i & d) == 0) {
                float lo = fminf(a[i], a[i + d]);
                float hi = fmaxf(a[i], a[i + d]);
                a[i] = lo; a[i + d] = hi;
            }
        }
    }
}

#define T3 512
#define R3 4
__global__ __launch_bounds__(T3) void hqt_k3_dsim(
    const float* __restrict__ desc2, const float* __restrict__ kp1_desc,
    const int* __restrict__ wcc16, const float* __restrict__ pos,
    float* __restrict__ acc) {
    const int nb = N_ / R3;
    int b = blockIdx.x / nb;
    int n0 = (blockIdx.x % nb) * R3;
    int tid = threadIdx.x;
    __shared__ float qT[C_][R3];
    __shared__ int ids_s[R3][16];
    {
        int r = tid & 3, c = tid >> 2;
        qT[c][r] = kp1_desc[(size_t)(b * N_ + n0 + r) * C_ + c];
    }
    if (tid < R3 * 16)
        ids_s[tid >> 4][tid & 15] = wcc16[(b * N_ + n0) * 16 + tid];
    __syncthreads();

    float top[R3][16];
#pragma unroll
    for (int r = 0; r < R3; ++r)
#pragma unroll
        for (int k = 0; k < 16; ++k) top[r][k] = 1e30f;

    const float* d2b = desc2 + (size_t)b * C_ * HW_;
#pragma unroll 1
    for (int g = 0; g < HW_ / (T3 * 4); ++g) {
        int j0 = (g * T3 + tid) * 4;
        float4 A0 = {0, 0, 0, 0}, A1 = {0, 0, 0, 0}, A2 = {0, 0, 0, 0}, A3 = {0, 0, 0, 0};
        for (int c = 0; c < C_; ++c) {
            float4 d = *reinterpret_cast<const float4*>(d2b + (size_t)c * HW_ + j0);
            float4 qv = *reinterpret_cast<const float4*>(&qT[c][0]);
            A0.x = fmaf(qv.x, d.x, A0.x); A0.y = fmaf(qv.x, d.y, A0.y);
            A0.z = fmaf(qv.x, d.z, A0.z); A0.w = fmaf(qv.x, d.w, A0.w);
            A1.x = fmaf(qv.y, d.x, A1.x); A1.y = fmaf(qv.y, d.y, A1.y);
            A1.z = fmaf(qv.y, d.z, A1.z); A1.w = fmaf(qv.y, d.w, A1.w);
            A2.x = fmaf(qv.z, d.x, A2.x); A2.y = fmaf(qv.z, d.y, A2.y);
            A2.z = fmaf(qv.z, d.z, A2.z); A2.w = fmaf(qv.z, d.w, A2.w);
            A3.x = fmaf(qv.w, d.x, A3.x); A3.y = fmaf(qv.w, d.y, A3.y);
            A3.z = fmaf(qv.w, d.z, A3.z); A3.w = fmaf(qv.w, d.w, A3.w);
        }
#pragma unroll
        for (int r = 0; r < R3; ++r) {
            float dots[4];
            dots[0] = (r == 0) ? A0.x : (r == 1) ? A1.x : (r == 2) ? A2.x : A3.x;
            dots[1] = (r == 0) ? A0.y : (r == 1) ? A1.y : (r == 2) ? A2.y : A3.y;
            dots[2] = (r == 0) ? A0.z : (r == 1) ? A1.z : (r == 2) ? A2.z : A3.z;
            dots[3] = (r == 0) ? A0.w : (r == 1) ? A1.w : (r == 2) ? A2.w : A3.w;
#pragma unroll
            for (int cc = 0; cc < 4; ++cc) {
                int j = j0 + cc;
                int cnt = 0;
#pragma unroll
                for (int i = 0; i < 16; ++i) cnt += (ids_s[r][i] == j) ? 1 : 0;
                float v = 2.0f - 2.0f * dots[cc] + 5.0f * (float)cnt;
                if (v < top[r][15]) {
#pragma unroll
                    for (int k = 0; k < 16; ++k) {
                        float o = top[r][k];
                        bool sm = v < o;
                        top[r][k] = sm ? v : o;
                        v = sm ? o : v;
                    }
                }
            }
        }
    }

    __shared__ float mv[T3][17];
#pragma unroll
    for (int r = 0; r < R3; ++r) {
        float a[16];
#pragma unroll
        for (int k = 0; k < 16; ++k) { a[k] = top[r][k]; mv[tid][k] = a[k]; }
        __syncthreads();
        for (int step = T3 / 2; step >= 1; step >>= 1) {
            if (tid < step) {
#pragma unroll
                for (int i = 0; i < 16; ++i)
                    a[i] = fminf(a[i], mv[tid + step][15 - i]);
                bitonic16_asc(a);
#pragma unroll
                for (int i = 0; i < 16; ++i) mv[tid][i] = a[i];
            }
            __syncthreads();
        }
        if (tid == 0) {
            float p = pos[b * N_ + n0 + r];
            float s = 0.0f;
#pragma unroll
            for (int k = 0; k < 16; ++k) {
                float xv = p - a[k] + 1.0f;
                xv = fmaxf(xv, 0.0f);
                s += xv * xv;
            }
            atomicAdd(acc + 0, s);
        }
        __syncthreads();
    }
}

// ===========================================================================
extern "C" void kernel_launch(void* const* d_in, const int* in_sizes, int n_in,
                              void* d_out, int out_size, void* d_ws, size_t ws_size,
                              hipStream_t stream) {
    const float* kp1      = (const float*)d_in[0];
    const float* w_kp1    = (const float*)d_in[1];
    const float* kp1_desc = (const float*)d_in[2];
    const float* desc2    = (const float*)d_in[3];
    const float* homo     = (const float*)d_in[4];
    float* out = (float*)d_out;

    // ---- workspace layout (new path) ----
    char* p = (char*)d_ws;
    auto alloc = [&](size_t bytes) {
        char* r = p;
        p += (bytes + 255) & ~(size_t)255;
        return r;
    };
    float*          w_desc = (float*)alloc((size_t)B_ * N_ * C_ * 4);
    float*          pos    = (float*)alloc((size_t)B_ * N_ * 4);
    int*            cid4   = (int*)alloc((size_t)B_ * N_ * 4 * 4);
    int*            wid4   = (int*)alloc((size_t)B_ * N_ * 4 * 4);
    int*            wcc16  = (int*)alloc((size_t)B_ * N_ * 16 * 4);
    unsigned int*   marked = (unsigned int*)alloc((size_t)B_ * N_ * 16 * 4);
    float*          acc    = (float*)alloc(64);
    unsigned short* q_bf   = (unsigned short*)alloc((size_t)B_ * N_ * C_ * 2);
    unsigned short* d2t    = (unsigned short*)alloc((size_t)B_ * HW_ * C_ * 2);
    float*          rowmax = (float*)alloc((size_t)B_ * N_ * 128 * 4);
    float*          t32    = (float*)alloc((size_t)B_ * N_ * 4);
    int*            scnt   = (int*)alloc((size_t)B_ * N_ * 4);
    float2*         sbuf   = (float2*)alloc((size_t)B_ * N_ * SCAP_ * 8);
    size_t need = (size_t)(p - (char*)d_ws);

    if (ws_size >= need) {
        hqt_k0<<<1157, 256, 0, stream>>>(desc2, kp1_desc, kp1, w_kp1, homo,
                                         d2t, q_bf, cid4, wcc16, wid4, marked,
                                         scnt, acc);
        hqt_k2_sample<<<B_ * N_, 128, 0, stream>>>(w_kp1, desc2, kp1_desc,
                                                   w_desc, pos);
        hqt_k3a<<<256, 512, 0, stream>>>(q_bf, d2t, rowmax);
        hqt_k3b<<<256, 256, 0, stream>>>(rowmax, t32);
        hqt_k3c<<<256, 512, 0, stream>>>(q_bf, d2t, t32, scnt, sbuf);
        hqt_k3d<<<256, 256, 0, stream>>>(q_bf, d2t, marked, scnt, sbuf, pos, acc);
        hqt_k4_sos<<<B_ * N_, 64, 0, stream>>>(kp1_desc, w_desc, cid4, wcc16,
                                               wid4, acc);
        hqt_k5_final<<<1, 1, 0, stream>>>(acc, out);
    } else {
        // fallback: round-1 layout and path
        float* w_desc0 = (float*)d_ws;
        float* pos0    = w_desc0 + (size_t)B_ * N_ * C_;
        int*   cid40   = (int*)(pos0 + B_ * N_);
        int*   wid40   = cid40 + B_ * N_ * 4;
        int*   wcc160  = wid40 + B_ * N_ * 4;
        float* acc0    = (float*)(wcc160 + B_ * N_ * 16);
        hipMemsetAsync(acc0, 0, 2 * sizeof(float), stream);
        hqt_k1_cells<<<(B_ * N_ + 255) / 256, 256, 0, stream>>>(
            kp1, w_kp1, homo, cid40, wcc160, wid40);
        hqt_k2_sample<<<B_ * N_, 128, 0, stream>>>(w_kp1, desc2, kp1_desc,
                                                   w_desc0, pos0);
        hqt_k3_dsim<<<B_ * (N_ / R3), T3, 0, stream>>>(desc2, kp1_desc, wcc160,
                                                       pos0, acc0);
        hqt_k4_sos<<<B_ * N_, 64, 0, stream>>>(kp1_desc, w_desc0, cid40,
                                               wcc160, wid40, acc0);
        hqt_k5_final<<<1, 1, 0, stream>>>(acc0, out);
    }
}

// Round 3
// 200.106 us; speedup vs baseline: 1.3833x; 1.0315x over previous
//
#include <hip/hip_runtime.h>
#include <climits>

#define B_ 2
#define N_ 512
#define C_ 128
#define H_ 128
#define W_ 128
#define HW_ (H_ * W_)
#define NUM_NEG_ 16
#define SOS_NEG_ 8
#define SCAP_ 128   // survivor cap per row

typedef __attribute__((ext_vector_type(8))) short short8;
typedef __attribute__((ext_vector_type(4))) float f32x4;

__device__ inline unsigned int f2bf(float x) {
    unsigned int u = __float_as_uint(x);
    return (u + 0x7FFFu + ((u >> 16) & 1u)) >> 16;
}
__device__ inline float bf2f(unsigned int h) {
    return __uint_as_float(h << 16);
}

// ---------------------------------------------------------------------------
// 4 nearest grid-cell centers of point (y,x). Cell (yi,xi) center at
// (8*yi+4, 8*xi+4), id = yi*128+xi. 4-nearest always in clamped 4x4 window;
// tie-break (dist, then lower id) matches lax.top_k.
// ---------------------------------------------------------------------------
__device__ inline void nearest4(float y, float x, int out[4]) {
    y = fminf(fmaxf(y, -1e6f), 1e6f);
    x = fminf(fmaxf(x, -1e6f), 1e6f);
    int fy = (int)floorf(y * 0.125f - 0.5f);
    int fx = (int)floorf(x * 0.125f - 0.5f);
    int ylo = fy - 1; if (ylo < 0) ylo = 0; if (ylo > H_ - 4) ylo = H_ - 4;
    int xlo = fx - 1; if (xlo < 0) xlo = 0; if (xlo > W_ - 4) xlo = W_ - 4;
    float bd[4] = {1e30f, 1e30f, 1e30f, 1e30f};
    int   bi[4] = {INT_MAX, INT_MAX, INT_MAX, INT_MAX};
#pragma unroll
    for (int dyi = 0; dyi < 4; ++dyi) {
        int yi = ylo + dyi;
        float dy = y - (8.0f * yi + 4.0f);
        float dy2 = dy * dy;
#pragma unroll
        for (int dxi = 0; dxi < 4; ++dxi) {
            int xi = xlo + dxi;
            float dx = x - (8.0f * xi + 4.0f);
            float d = dy2 + dx * dx;
            int id = yi * W_ + xi;
#pragma unroll
            for (int k = 0; k < 4; ++k) {
                bool sm = (d < bd[k]) || (d == bd[k] && id < bi[k]);
                float od = bd[k]; int oi = bi[k];
                bd[k] = sm ? d : od;  bi[k] = sm ? id : oi;
                d = sm ? od : d;      id = sm ? oi : id;
            }
        }
    }
    out[0] = bi[0]; out[1] = bi[1]; out[2] = bi[2]; out[3] = bi[3];
}

__device__ inline void k1_body(int t, const float* kp1, const float* w_kp1,
                               const float* homo, int* cid4, int* wcc16,
                               int* wid4, unsigned int* marked) {
    int b = t / N_;
    float ky = kp1[2 * t], kx = kp1[2 * t + 1];
    int ids[4];
    nearest4(ky, kx, ids);
    const float* Hb = homo + 9 * b;
    float h00 = Hb[0], h01 = Hb[1], h02 = Hb[2];
    float h10 = Hb[3], h11 = Hb[4], h12 = Hb[5];
    float h20 = Hb[6], h21 = Hb[7], h22 = Hb[8];
    int w16[16];
#pragma unroll
    for (int i = 0; i < 4; ++i) {
        int id = ids[i];
        cid4[4 * t + i] = id;
        float cy = 8.0f * (id >> 7) + 4.0f;
        float cx = 8.0f * (id & 127) + 4.0f;
        float X = cx, Y = cy;
        float wz = h20 * X + h21 * Y + h22;
        float inv = 1.0f / (wz + 1e-8f);
        float wy = (h10 * X + h11 * Y + h12) * inv;
        float wx = (h00 * X + h01 * Y + h02) * inv;
        int wids[4];
        nearest4(wy, wx, wids);
#pragma unroll
        for (int j = 0; j < 4; ++j) {
            w16[4 * i + j] = wids[j];
            wcc16[16 * t + 4 * i + j] = wids[j];
        }
    }
    // dedup with multiplicity: slot i canonical iff first occurrence
#pragma unroll
    for (int i = 0; i < 16; ++i) {
        int cnt = 0; bool first = true;
#pragma unroll
        for (int j = 0; j < 16; ++j) {
            bool eq = (w16[j] == w16[i]);
            cnt += eq ? 1 : 0;
            if (j < i && eq) first = false;
        }
        marked[16 * t + i] = first ? ((unsigned int)w16[i] | ((unsigned int)cnt << 16))
                                   : 0xFFFFFFFFu;
    }
    float zy = w_kp1[2 * t], zx = w_kp1[2 * t + 1];
    int wi4[4];
    nearest4(zy, zx, wi4);
#pragma unroll
    for (int j = 0; j < 4; ++j) wid4[4 * t + j] = wi4[j];
}

// ---------------------------------------------------------------------------
// K0 fused: [0,1024) transpose+convert desc2 -> d2t_bf[b][j][c];
// [1024,1152) convert kp1_desc -> q_bf; 1152 zero scnt/acc; [1153,1157) k1.
// ---------------------------------------------------------------------------
__global__ __launch_bounds__(256) void hqt_k0(
    const float* __restrict__ desc2, const float* __restrict__ kp1_desc,
    const float* __restrict__ kp1, const float* __restrict__ w_kp1,
    const float* __restrict__ homo,
    unsigned short* __restrict__ d2t, unsigned short* __restrict__ q_bf,
    int* __restrict__ cid4, int* __restrict__ wcc16, int* __restrict__ wid4,
    unsigned int* __restrict__ marked, int* __restrict__ scnt,
    float* __restrict__ acc) {
    int blk = blockIdx.x;
    int tid = threadIdx.x;
    if (blk < 1024) {
        __shared__ float tile[32][129];
        int b = blk >> 9;
        int j0 = (blk & 511) * 32;
        int jj = tid & 31, cg = tid >> 5;
        const float* src = desc2 + (size_t)b * C_ * HW_;
#pragma unroll
        for (int cc = 0; cc < 16; ++cc) {
            int c = cg * 16 + cc;
            tile[jj][c] = src[(size_t)c * HW_ + j0 + jj];
        }
        __syncthreads();
        int row = tid >> 3, c8 = (tid & 7) * 16;
        unsigned int tmp[16];
#pragma unroll
        for (int k = 0; k < 16; ++k) tmp[k] = f2bf(tile[row][c8 + k]);
        uint4 o0, o1;
        o0.x = tmp[0] | (tmp[1] << 16);  o0.y = tmp[2] | (tmp[3] << 16);
        o0.z = tmp[4] | (tmp[5] << 16);  o0.w = tmp[6] | (tmp[7] << 16);
        o1.x = tmp[8] | (tmp[9] << 16);  o1.y = tmp[10] | (tmp[11] << 16);
        o1.z = tmp[12] | (tmp[13] << 16); o1.w = tmp[14] | (tmp[15] << 16);
        unsigned short* dst = d2t + ((size_t)(b << 14) + j0 + row) * C_ + c8;
        ((uint4*)dst)[0] = o0;
        ((uint4*)dst)[1] = o1;
    } else if (blk < 1152) {
        int idx = (blk - 1024) * 256 + tid;   // 4 elems each, 131072 total
        float4 v = *(const float4*)(kp1_desc + (size_t)idx * 4);
        uint2 u;
        u.x = f2bf(v.x) | (f2bf(v.y) << 16);
        u.y = f2bf(v.z) | (f2bf(v.w) << 16);
        *(uint2*)(q_bf + (size_t)idx * 4) = u;
    } else if (blk == 1152) {
        ((int4*)scnt)[tid] = make_int4(0, 0, 0, 0);
        if (tid == 0) { acc[0] = 0.0f; acc[1] = 0.0f; }
    } else {
        int t = (blk - 1153) * 256 + tid;
        if (t < B_ * N_)
            k1_body(t, kp1, w_kp1, homo, cid4, wcc16, wid4, marked);
    }
}

// ---------------------------------------------------------------------------
// K2: bilinear-sample desc2 at w_kp1, normalize -> w_bf (bf16) ; pos.
// ---------------------------------------------------------------------------
__global__ __launch_bounds__(128) void hqt_k2_sample(
    const float* __restrict__ w_kp1, const float* __restrict__ desc2,
    const float* __restrict__ kp1_desc, unsigned short* __restrict__ w_bf,
    float* __restrict__ pos) {
    int bn = blockIdx.x;
    int b = bn / N_;
    int c = threadIdx.x;
    float ky = w_kp1[2 * bn], kx = w_kp1[2 * bn + 1];
    float y = fminf(fmaxf(ky * 0.125f - 0.5f, 0.0f), (float)(H_ - 1));
    float x = fminf(fmaxf(kx * 0.125f - 0.5f, 0.0f), (float)(W_ - 1));
    int y0 = (int)floorf(y); if (y0 > H_ - 2) y0 = H_ - 2;
    int x0 = (int)floorf(x); if (x0 > W_ - 2) x0 = W_ - 2;
    float wy = y - (float)y0, wx = x - (float)x0;
    const float* dB = desc2 + ((size_t)b * C_ + c) * HW_;
    int i00 = y0 * W_ + x0;
    float v = dB[i00]          * (1.0f - wy) * (1.0f - wx)
            + dB[i00 + 1]      * (1.0f - wy) * wx
            + dB[i00 + W_]     * wy * (1.0f - wx)
            + dB[i00 + W_ + 1] * wy * wx;
    __shared__ float red[128];
    red[c] = v * v;
    __syncthreads();
    for (int s = 64; s > 0; s >>= 1) {
        if (c < s) red[c] += red[c + s];
        __syncthreads();
    }
    float nrm = sqrtf(red[0]);
    __syncthreads();
    float vn = v / (nrm + 1e-8f);
    w_bf[(size_t)bn * C_ + c] = (unsigned short)f2bf(vn);
    float qd = kp1_desc[(size_t)bn * C_ + c];
    red[c] = qd * vn;
    __syncthreads();
    for (int s = 64; s > 0; s >>= 1) {
        if (c < s) red[c] += red[c + s];
        __syncthreads();
    }
    if (c == 0) pos[bn] = 2.0f - 2.0f * red[0];
}

// f32 variant for the fallback path
__global__ __launch_bounds__(128) void hqt_k2_sample_f32(
    const float* __restrict__ w_kp1, const float* __restrict__ desc2,
    const float* __restrict__ kp1_desc, float* __restrict__ w_desc,
    float* __restrict__ pos) {
    int bn = blockIdx.x;
    int b = bn / N_;
    int c = threadIdx.x;
    float ky = w_kp1[2 * bn], kx = w_kp1[2 * bn + 1];
    float y = fminf(fmaxf(ky * 0.125f - 0.5f, 0.0f), (float)(H_ - 1));
    float x = fminf(fmaxf(kx * 0.125f - 0.5f, 0.0f), (float)(W_ - 1));
    int y0 = (int)floorf(y); if (y0 > H_ - 2) y0 = H_ - 2;
    int x0 = (int)floorf(x); if (x0 > W_ - 2) x0 = W_ - 2;
    float wy = y - (float)y0, wx = x - (float)x0;
    const float* dB = desc2 + ((size_t)b * C_ + c) * HW_;
    int i00 = y0 * W_ + x0;
    float v = dB[i00]          * (1.0f - wy) * (1.0f - wx)
            + dB[i00 + 1]      * (1.0f - wy) * wx
            + dB[i00 + W_]     * wy * (1.0f - wx)
            + dB[i00 + W_ + 1] * wy * wx;
    __shared__ float red[128];
    red[c] = v * v;
    __syncthreads();
    for (int s = 64; s > 0; s >>= 1) {
        if (c < s) red[c] += red[c + s];
        __syncthreads();
    }
    float nrm = sqrtf(red[0]);
    __syncthreads();
    float vn = v / (nrm + 1e-8f);
    w_desc[(size_t)bn * C_ + c] = vn;
    float qd = kp1_desc[(size_t)bn * C_ + c];
    red[c] = qd * vn;
    __syncthreads();
    for (int s = 64; s > 0; s >>= 1) {
        if (c < s) red[c] += red[c + s];
        __syncthreads();
    }
    if (c == 0) pos[bn] = 2.0f - 2.0f * red[0];
}

// ---------------------------------------------------------------------------
// K3a: MFMA pass 1. Block: 64 rows x 1024 cols, 8 waves (128 cols each).
// ---------------------------------------------------------------------------
__global__ __launch_bounds__(512) void hqt_k3a(
    const unsigned short* __restrict__ q_bf,
    const unsigned short* __restrict__ d2t,
    float* __restrict__ rowmax) {
    int blk = blockIdx.x;           // 256 = 2b x 8rg x 16cb
    int b = blk >> 7;
    int rg = (blk >> 4) & 7;
    int cb = blk & 15;
    int tid = threadIdx.x, w = tid >> 6, l = tid & 63;
    int l15 = l & 15, lg = l >> 4;
    int rowbase = rg * 64;
    int colbase = cb * 1024 + w * 128;
    const unsigned short* qb = q_bf + (size_t)b * N_ * C_;
    const unsigned short* db = d2t + (size_t)b * HW_ * C_;
    short8 a[4][4];
#pragma unroll
    for (int rt = 0; rt < 4; ++rt)
#pragma unroll
        for (int ks = 0; ks < 4; ++ks)
            a[rt][ks] = *(const short8*)(qb + (size_t)(rowbase + rt * 16 + l15) * C_ + ks * 32 + lg * 8);
    f32x4 mx[4];
#pragma unroll
    for (int rt = 0; rt < 4; ++rt) mx[rt] = f32x4{-1e30f, -1e30f, -1e30f, -1e30f};
#pragma unroll
    for (int t = 0; t < 8; ++t) {
        const unsigned short* dp = db + (size_t)(colbase + t * 16 + l15) * C_ + lg * 8;
        short8 b0 = *(const short8*)(dp);
        short8 b1 = *(const short8*)(dp + 32);
        short8 b2 = *(const short8*)(dp + 64);
        short8 b3 = *(const short8*)(dp + 96);
#pragma unroll
        for (int rt = 0; rt < 4; ++rt) {
            f32x4 acc4 = {0.0f, 0.0f, 0.0f, 0.0f};
            acc4 = __builtin_amdgcn_mfma_f32_16x16x32_bf16(a[rt][0], b0, acc4, 0, 0, 0);
            acc4 = __builtin_amdgcn_mfma_f32_16x16x32_bf16(a[rt][1], b1, acc4, 0, 0, 0);
            acc4 = __builtin_amdgcn_mfma_f32_16x16x32_bf16(a[rt][2], b2, acc4, 0, 0, 0);
            acc4 = __builtin_amdgcn_mfma_f32_16x16x32_bf16(a[rt][3], b3, acc4, 0, 0, 0);
#pragma unroll
            for (int r = 0; r < 4; ++r) mx[rt][r] = fmaxf(mx[rt][r], acc4[r]);
        }
    }
#pragma unroll
    for (int rt = 0; rt < 4; ++rt)
#pragma unroll
        for (int r = 0; r < 4; ++r) {
            float v = mx[rt][r];
            v = fmaxf(v, __shfl_xor(v, 1));
            v = fmaxf(v, __shfl_xor(v, 2));
            v = fmaxf(v, __shfl_xor(v, 4));
            v = fmaxf(v, __shfl_xor(v, 8));
            mx[rt][r] = v;
        }
    if (l15 == 0) {
        int chunk = cb * 8 + w;
#pragma unroll
        for (int rt = 0; rt < 4; ++rt)
#pragma unroll
            for (int r = 0; r < 4; ++r) {
                int rowg = b * N_ + rowbase + rt * 16 + lg * 4 + r;
                rowmax[(size_t)rowg * 128 + chunk] = mx[rt][r];
            }
    }
}

// ---------------------------------------------------------------------------
// K3b: per row, t = 32nd-largest of 128 window maxes.
// ---------------------------------------------------------------------------
__global__ __launch_bounds__(256) void hqt_k3b(
    const float* __restrict__ rowmax, float* __restrict__ t32) {
    int w = threadIdx.x >> 6, l = threadIdx.x & 63;
    int row = blockIdx.x * 4 + w;
    const float* rm = rowmax + (size_t)row * 128;
    float v = fmaxf(rm[l], rm[64 + l]);
    float t = -1e30f;
#pragma unroll 1
    for (int it = 0; it < 32; ++it) {
        float m = v;
        m = fmaxf(m, __shfl_xor(m, 1));
        m = fmaxf(m, __shfl_xor(m, 2));
        m = fmaxf(m, __shfl_xor(m, 4));
        m = fmaxf(m, __shfl_xor(m, 8));
        m = fmaxf(m, __shfl_xor(m, 16));
        m = fmaxf(m, __shfl_xor(m, 32));
        v = (v == m) ? -1e30f : v;
        t = m;
    }
    if (l == 0) t32[row] = t;
}

// ---------------------------------------------------------------------------
// K3c: MFMA pass 2: push (dot, col) with dot >= t[row] into survivor buffer.
// ---------------------------------------------------------------------------
__global__ __launch_bounds__(512) void hqt_k3c(
    const unsigned short* __restrict__ q_bf,
    const unsigned short* __restrict__ d2t,
    const float* __restrict__ t32,
    int* __restrict__ scnt, float2* __restrict__ sbuf) {
    int blk = blockIdx.x;
    int b = blk >> 7;
    int rg = (blk >> 4) & 7;
    int cb = blk & 15;
    int tid = threadIdx.x, w = tid >> 6, l = tid & 63;
    int l15 = l & 15, lg = l >> 4;
    int rowbase = rg * 64;
    int colbase = cb * 1024 + w * 128;
    const unsigned short* qb = q_bf + (size_t)b * N_ * C_;
    const unsigned short* db = d2t + (size_t)b * HW_ * C_;
    short8 a[4][4];
#pragma unroll
    for (int rt = 0; rt < 4; ++rt)
#pragma unroll
        for (int ks = 0; ks < 4; ++ks)
            a[rt][ks] = *(const short8*)(qb + (size_t)(rowbase + rt * 16 + l15) * C_ + ks * 32 + lg * 8);
    float tl[4][4];
#pragma unroll
    for (int rt = 0; rt < 4; ++rt)
#pragma unroll
        for (int r = 0; r < 4; ++r)
            tl[rt][r] = t32[b * N_ + rowbase + rt * 16 + lg * 4 + r];
#pragma unroll
    for (int t = 0; t < 8; ++t) {
        const unsigned short* dp = db + (size_t)(colbase + t * 16 + l15) * C_ + lg * 8;
        short8 b0 = *(const short8*)(dp);
        short8 b1 = *(const short8*)(dp + 32);
        short8 b2 = *(const short8*)(dp + 64);
        short8 b3 = *(const short8*)(dp + 96);
#pragma unroll
        for (int rt = 0; rt < 4; ++rt) {
            f32x4 acc4 = {0.0f, 0.0f, 0.0f, 0.0f};
            acc4 = __builtin_amdgcn_mfma_f32_16x16x32_bf16(a[rt][0], b0, acc4, 0, 0, 0);
            acc4 = __builtin_amdgcn_mfma_f32_16x16x32_bf16(a[rt][1], b1, acc4, 0, 0, 0);
            acc4 = __builtin_amdgcn_mfma_f32_16x16x32_bf16(a[rt][2], b2, acc4, 0, 0, 0);
            acc4 = __builtin_amdgcn_mfma_f32_16x16x32_bf16(a[rt][3], b3, acc4, 0, 0, 0);
#pragma unroll
            for (int r = 0; r < 4; ++r) {
                float d = acc4[r];
                if (d >= tl[rt][r]) {
                    int rowg = b * N_ + rowbase + rt * 16 + lg * 4 + r;
                    int idx = atomicAdd(scnt + rowg, 1);
                    if (idx < SCAP_) {
                        float2 e;
                        e.x = d;
                        e.y = __int_as_float(colbase + t * 16 + l15);
                        sbuf[(size_t)rowg * SCAP_ + idx] = e;
                    }
                }
            }
        }
    }
}

// ---------------------------------------------------------------------------
// K3d: one wave per row; exact penalized top-16 from survivors + marked.
// ---------------------------------------------------------------------------
__global__ __launch_bounds__(256) void hqt_k3d(
    const unsigned short* __restrict__ q_bf,
    const unsigned short* __restrict__ d2t,
    const unsigned int* __restrict__ marked,
    const int* __restrict__ scnt, const float2* __restrict__ sbuf,
    const float* __restrict__ pos, float* __restrict__ acc) {
    int w = threadIdx.x >> 6, l = threadIdx.x & 63;
    int row = blockIdx.x * 4 + w;
    int b = row >> 9;
    int sc = scnt[row]; if (sc > SCAP_) sc = SCAP_;
    float k0 = -1e30f, k1 = -1e30f, k2c = -1e30f;
    int c0 = -1, c1 = -1;
    if (l < sc) {
        float2 e = sbuf[(size_t)row * SCAP_ + l];
        k0 = e.x; c0 = __float_as_int(e.y);
    }
    if (64 + l < sc) {
        float2 e = sbuf[(size_t)row * SCAP_ + 64 + l];
        k1 = e.x; c1 = __float_as_int(e.y);
    }
#pragma unroll
    for (int i = 0; i < 16; ++i) {
        unsigned int mv = marked[row * 16 + i];
        int id = (int)(mv & 0xFFFFu);
        if (c0 == id) k0 = -1e30f;
        if (c1 == id) k1 = -1e30f;
    }
    {
        int mi = l >> 2, cq = l & 3;
        unsigned int mv = marked[row * 16 + mi];
        bool valid = (mv != 0xFFFFFFFFu);
        int col = valid ? (int)(mv & 0xFFFFu) : 0;
        int cnt = (int)(mv >> 16);
        const unsigned short* qp = q_bf + (size_t)row * C_ + cq * 32;
        const unsigned short* dp = d2t + ((size_t)b * HW_ + col) * C_ + cq * 32;
        float dot = 0.0f;
#pragma unroll
        for (int u = 0; u < 4; ++u) {
            short8 qv = *(const short8*)(qp + u * 8);
            short8 dv = *(const short8*)(dp + u * 8);
#pragma unroll
            for (int e = 0; e < 8; ++e)
                dot = fmaf(bf2f((unsigned short)qv[e]), bf2f((unsigned short)dv[e]), dot);
        }
        dot += __shfl_xor(dot, 1);
        dot += __shfl_xor(dot, 2);
        k2c = (valid && cq == 0) ? (dot - 2.5f * (float)cnt) : -1e30f;
    }
    float pos_r = pos[row];
    float sum = 0.0f;
#pragma unroll 1
    for (int it = 0; it < 16; ++it) {
        float v = fmaxf(k0, fmaxf(k1, k2c));
        float m = v;
        m = fmaxf(m, __shfl_xor(m, 1));
        m = fmaxf(m, __shfl_xor(m, 2));
        m = fmaxf(m, __shfl_xor(m, 4));
        m = fmaxf(m, __shfl_xor(m, 8));
        m = fmaxf(m, __shfl_xor(m, 16));
        m = fmaxf(m, __shfl_xor(m, 32));
        unsigned long long b0 = __ballot(k0 == m);
        if (b0) {
            if (l == __ffsll(b0) - 1) k0 = -1e30f;
        } else {
            unsigned long long b1 = __ballot(k1 == m);
            if (b1) {
                if (l == __ffsll(b1) - 1) k1 = -1e30f;
            } else {
                unsigned long long b2 = __ballot(k2c == m);
                if (l == __ffsll(b2) - 1) k2c = -1e30f;
            }
        }
        float h = pos_r + 2.0f * m - 1.0f;
        h = fmaxf(h, 0.0f);
        sum += h * h;
    }
    if (l == 0) atomicAdd(acc + 0, sum);
}

// ---------------------------------------------------------------------------
// K4m: MFMA k_sim/w_sim + lazy-penalty top-8 extraction + sos.
// 64 blocks (2b x 32 stripes of 16 rows), 256 threads (4 waves).
// ---------------------------------------------------------------------------
#define K4R_ 16
__global__ __launch_bounds__(256) void hqt_k4m(
    const unsigned short* __restrict__ q_bf,
    const unsigned short* __restrict__ w_bf,
    const int* __restrict__ cid4, const int* __restrict__ wcc16,
    const int* __restrict__ wid4, float* __restrict__ acc) {
    int blk = blockIdx.x;
    int b = blk >> 5;
    int r0 = (blk & 31) * K4R_;
    int tid = threadIdx.x, w = tid >> 6, l = tid & 63;
    int l15 = l & 15, lg = l >> 4;

    __shared__ float sim[K4R_][516];      // padded: (4*516)%32 == 16
    __shared__ int s_cid[N_][4];
    __shared__ int s_wid[N_][4];
    __shared__ int s_wcc[K4R_][16];
    __shared__ float s_sel[2][K4R_][8];

    {
        const int4* gc = (const int4*)(cid4 + b * N_ * 4);
        const int4* gw = (const int4*)(wid4 + b * N_ * 4);
        ((int4*)s_cid)[tid]       = gc[tid];
        ((int4*)s_cid)[tid + 256] = gc[tid + 256];
        ((int4*)s_wid)[tid]       = gw[tid];
        ((int4*)s_wid)[tid + 256] = gw[tid + 256];
        if (tid < K4R_ * 16)
            ((int*)s_wcc)[tid] = wcc16[(b * N_ + r0) * 16 + tid];
    }

#pragma unroll 1
    for (int mat = 0; mat < 2; ++mat) {
        const unsigned short* src = (mat ? w_bf : q_bf) + (size_t)b * N_ * C_;
        short8 a0 = *(const short8*)(src + (size_t)(r0 + l15) * C_ + lg * 8);
        short8 a1 = *(const short8*)(src + (size_t)(r0 + l15) * C_ + 32 + lg * 8);
        short8 a2 = *(const short8*)(src + (size_t)(r0 + l15) * C_ + 64 + lg * 8);
        short8 a3 = *(const short8*)(src + (size_t)(r0 + l15) * C_ + 96 + lg * 8);
        __syncthreads();   // prev selection / coop loads complete
#pragma unroll
        for (int t = 0; t < 8; ++t) {
            int col0 = (w * 8 + t) * 16;
            const unsigned short* dp = src + (size_t)(col0 + l15) * C_ + lg * 8;
            short8 b0 = *(const short8*)(dp);
            short8 b1 = *(const short8*)(dp + 32);
            short8 b2 = *(const short8*)(dp + 64);
            short8 b3 = *(const short8*)(dp + 96);
            f32x4 acc4 = {0.0f, 0.0f, 0.0f, 0.0f};
            acc4 = __builtin_amdgcn_mfma_f32_16x16x32_bf16(a0, b0, acc4, 0, 0, 0);
            acc4 = __builtin_amdgcn_mfma_f32_16x16x32_bf16(a1, b1, acc4, 0, 0, 0);
            acc4 = __builtin_amdgcn_mfma_f32_16x16x32_bf16(a2, b2, acc4, 0, 0, 0);
            acc4 = __builtin_amdgcn_mfma_f32_16x16x32_bf16(a3, b3, acc4, 0, 0, 0);
#pragma unroll
            for (int r = 0; r < 4; ++r)
                sim[lg * 4 + r][col0 + l15] = acc4[r];
        }
        __syncthreads();

        // selection: wave w owns rows w*4 .. w*4+3
#pragma unroll 1
        for (int q = 0; q < 4; ++q) {
            int lr = w * 4 + q;
            int grow = r0 + lr;       // within-batch row/keypoint index
            float key[8], clean[8];
#pragma unroll
            for (int i = 0; i < 8; ++i) {
                key[i] = sim[lr][i * 64 + l];
                clean[i] = key[i];
            }
            int adj = 0;
            int emitted = 0;
            int guard = 0;
            while (emitted < 8 && guard < 1100) {
                ++guard;
                float bv = key[0]; int bs = 0;
#pragma unroll
                for (int i = 1; i < 8; ++i)
                    if (key[i] > bv) { bv = key[i]; bs = i; }
                float v = bv; int c = bs * 64 + l;   // c = column index
#pragma unroll
                for (int off = 1; off < 64; off <<= 1) {
                    float ov = __shfl_xor(v, off);
                    int oc = __shfl_xor(c, off);
                    if (ov > v || (ov == v && oc < c)) { v = ov; c = oc; }
                }
                int owner = c & 63;
                int slot = c >> 6;
                int emit = 1;
                float cleanv = 0.0f;
                if (l == owner) {
                    if (!((adj >> slot) & 1)) {
                        int cnt = 0;
                        if (mat == 0) {
#pragma unroll
                            for (int i = 0; i < 4; ++i) {
                                int rc = s_cid[grow][i];
#pragma unroll
                                for (int j = 0; j < 4; ++j)
                                    cnt += (rc == s_cid[c][j]) ? 1 : 0;
                            }
                        } else {
#pragma unroll
                            for (int i = 0; i < 16; ++i) {
                                int rc = s_wcc[lr][i];
#pragma unroll
                                for (int j = 0; j < 4; ++j)
                                    cnt += (rc == s_wid[c][j]) ? 1 : 0;
                            }
                        }
                        if (cnt > 0) {
                            key[slot] -= 2.5f * (float)cnt;
                            adj |= 1 << slot;
                            emit = 0;
                        } else {
                            cleanv = clean[slot];
                            key[slot] = -1e30f;
                        }
                    } else {
                        cleanv = clean[slot];
                        key[slot] = -1e30f;
                    }
                }
                emit = __shfl(emit, owner);
                if (emit) {
                    cleanv = __shfl(cleanv, owner);
                    if (l == 0) s_sel[mat][lr][emitted] = cleanv;
                    ++emitted;
                }
            }
        }
    }
    // sos per row (wave-local: s_sel written by lane0 of this wave)
    if (l < 32) {
        int lr = w * 4 + (l >> 3);
        int i = l & 7;
        float t2 = 2.0f * (s_sel[1][lr][i] - s_sel[0][lr][i]);
        float sq = t2 * t2;
        sq += __shfl_xor(sq, 1);
        sq += __shfl_xor(sq, 2);
        sq += __shfl_xor(sq, 4);
        if (i == 0) atomicAdd(acc + 1, sqrtf(sq));
    }
}

__global__ void hqt_k5_final(const float* __restrict__ acc, float* __restrict__ out) {
    if (threadIdx.x == 0 && blockIdx.x == 0) {
        out[0] = acc[0] * (1.0f / (float)(B_ * N_ * NUM_NEG_))
               + acc[1] * (1.0f / (float)(B_ * N_));
    }
}

// ======================= fallback (round-1) kernels ========================
__global__ void hqt_k1_cells(const float* __restrict__ kp1,
                             const float* __restrict__ w_kp1,
                             const float* __restrict__ homo,
                             int* __restrict__ cid4,
                             int* __restrict__ wcc16,
                             int* __restrict__ wid4) {
    int t = blockIdx.x * blockDim.x + threadIdx.x;
    if (t >= B_ * N_) return;
    int b = t / N_;
    float ky = kp1[2 * t], kx = kp1[2 * t + 1];
    int ids[4];
    nearest4(ky, kx, ids);
    const float* Hb = homo + 9 * b;
    float h00 = Hb[0], h01 = Hb[1], h02 = Hb[2];
    float h10 = Hb[3], h11 = Hb[4], h12 = Hb[5];
    float h20 = Hb[6], h21 = Hb[7], h22 = Hb[8];
#pragma unroll
    for (int i = 0; i < 4; ++i) {
        int id = ids[i];
        cid4[4 * t + i] = id;
        float cy = 8.0f * (id >> 7) + 4.0f;
        float cx = 8.0f * (id & 127) + 4.0f;
        float X = cx, Y = cy;
        float wz = h20 * X + h21 * Y + h22;
        float inv = 1.0f / (wz + 1e-8f);
        float wy = (h10 * X + h11 * Y + h12) * inv;
        float wx = (h00 * X + h01 * Y + h02) * inv;
        int wids[4];
        nearest4(wy, wx, wids);
#pragma unroll
        for (int j = 0; j < 4; ++j) wcc16[16 * t + 4 * i + j] = wids[j];
    }
    float zy = w_kp1[2 * t], zx = w_kp1[2 * t + 1];
    int wi4[4];
    nearest4(zy, zx, wi4);
#pragma unroll
    for (int j = 0; j < 4; ++j) wid4[4 * t + j] = wi4[j];
}

__device__ inline void bitonic16_asc(float (&a)[16]) {
#pragma unroll
    for (int dd = 0; dd < 4; ++dd) {
        const int d = 8 >> dd;
#pragma unroll
        for (int i = 0; i < 16; ++i) {
            if ((i & d) == 0) {
                float lo = fminf(a[i], a[i + d]);
                float hi = fmaxf(a[i], a[i + d]);
                a[i] = lo; a[i + d] = hi;
            }
        }
    }
}

#define T3 512
#define R3 4
__global__ __launch_bounds__(T3) void hqt_k3_dsim(
    const float* __restrict__ desc2, const float* __restrict__ kp1_desc,
    const int* __restrict__ wcc16, const float* __restrict__ pos,
    float* __restrict__ acc) {
    const int nb = N_ / R3;
    int b = blockIdx.x / nb;
    int n0 = (blockIdx.x % nb) * R3;
    int tid = threadIdx.x;
    __shared__ float qT[C_][R3];
    __shared__ int ids_s[R3][16];
    {
        int r = tid & 3, c = tid >> 2;
        qT[c][r] = kp1_desc[(size_t)(b * N_ + n0 + r) * C_ + c];
    }
    if (tid < R3 * 16)
        ids_s[tid >> 4][tid & 15] = wcc16[(b * N_ + n0) * 16 + tid];
    __syncthreads();

    float top[R3][16];
#pragma unroll
    for (int r = 0; r < R3; ++r)
#pragma unroll
        for (int k = 0; k < 16; ++k) top[r][k] = 1e30f;

    const float* d2b = desc2 + (size_t)b * C_ * HW_;
#pragma unroll 1
    for (int g = 0; g < HW_ / (T3 * 4); ++g) {
        int j0 = (g * T3 + tid) * 4;
        float4 A0 = {0, 0, 0, 0}, A1 = {0, 0, 0, 0}, A2 = {0, 0, 0, 0}, A3 = {0, 0, 0, 0};
        for (int c = 0; c < C_; ++c) {
            float4 d = *reinterpret_cast<const float4*>(d2b + (size_t)c * HW_ + j0);
            float4 qv = *reinterpret_cast<const float4*>(&qT[c][0]);
            A0.x = fmaf(qv.x, d.x, A0.x); A0.y = fmaf(qv.x, d.y, A0.y);
            A0.z = fmaf(qv.x, d.z, A0.z); A0.w = fmaf(qv.x, d.w, A0.w);
            A1.x = fmaf(qv.y, d.x, A1.x); A1.y = fmaf(qv.y, d.y, A1.y);
            A1.z = fmaf(qv.y, d.z, A1.z); A1.w = fmaf(qv.y, d.w, A1.w);
            A2.x = fmaf(qv.z, d.x, A2.x); A2.y = fmaf(qv.z, d.y, A2.y);
            A2.z = fmaf(qv.z, d.z, A2.z); A2.w = fmaf(qv.z, d.w, A2.w);
            A3.x = fmaf(qv.w, d.x, A3.x); A3.y = fmaf(qv.w, d.y, A3.y);
            A3.z = fmaf(qv.w, d.z, A3.z); A3.w = fmaf(qv.w, d.w, A3.w);
        }
#pragma unroll
        for (int r = 0; r < R3; ++r) {
            float dots[4];
            dots[0] = (r == 0) ? A0.x : (r == 1) ? A1.x : (r == 2) ? A2.x : A3.x;
            dots[1] = (r == 0) ? A0.y : (r == 1) ? A1.y : (r == 2) ? A2.y : A3.y;
            dots[2] = (r == 0) ? A0.z : (r == 1) ? A1.z : (r == 2) ? A2.z : A3.z;
            dots[3] = (r == 0) ? A0.w : (r == 1) ? A1.w : (r == 2) ? A2.w : A3.w;
#pragma unroll
            for (int cc = 0; cc < 4; ++cc) {
                int j = j0 + cc;
                int cnt = 0;
#pragma unroll
                for (int i = 0; i < 16; ++i) cnt += (ids_s[r][i] == j) ? 1 : 0;
                float v = 2.0f - 2.0f * dots[cc] + 5.0f * (float)cnt;
                if (v < top[r][15]) {
#pragma unroll
                    for (int k = 0; k < 16; ++k) {
                        float o = top[r][k];
                        bool sm = v < o;
                        top[r][k] = sm ? v : o;
                        v = sm ? o : v;
                    }
                }
            }
        }
    }

    __shared__ float mv[T3][17];
#pragma unroll
    for (int r = 0; r < R3; ++r) {
        float a[16];
#pragma unroll
        for (int k = 0; k < 16; ++k) { a[k] = top[r][k]; mv[tid][k] = a[k]; }
        __syncthreads();
        for (int step = T3 / 2; step >= 1; step >>= 1) {
            if (tid < step) {
#pragma unroll
                for (int i = 0; i < 16; ++i)
                    a[i] = fminf(a[i], mv[tid + step][15 - i]);
                bitonic16_asc(a);
#pragma unroll
                for (int i = 0; i < 16; ++i) mv[tid][i] = a[i];
            }
            __syncthreads();
        }
        if (tid == 0) {
            float p = pos[b * N_ + n0 + r];
            float s = 0.0f;
#pragma unroll
            for (int k = 0; k < 16; ++k) {
                float xv = p - a[k] + 1.0f;
                xv = fmaxf(xv, 0.0f);
                s += xv * xv;
            }
            atomicAdd(acc + 0, s);
        }
        __syncthreads();
    }
}

__device__ inline void insert8_vi(float (&av)[8], int (&ai)[8], float v, int id) {
    bool le = (v < av[7]) || (v == av[7] && id < ai[7]);
    if (!le) return;
#pragma unroll
    for (int k = 0; k < 8; ++k) {
        float ov = av[k]; int oi = ai[k];
        bool sm = (v < ov) || (v == ov && id < oi);
        av[k] = sm ? v : ov;  ai[k] = sm ? id : oi;
        v = sm ? ov : v;      id = sm ? oi : id;
    }
}

__device__ inline void bitonic8_pairs(float (&av)[8], int (&ai)[8]) {
#pragma unroll
    for (int dd = 0; dd < 3; ++dd) {
        const int d = 4 >> dd;
#pragma unroll
        for (int i = 0; i < 8; ++i) {
            if ((i & d) == 0) {
                bool sw = (av[i + d] < av[i]) ||
                          (av[i + d] == av[i] && ai[i + d] < ai[i]);
                float tv = av[i]; int ti = ai[i];
                av[i]     = sw ? av[i + d] : av[i];
                ai[i]     = sw ? ai[i + d] : ai[i];
                av[i + d] = sw ? tv : av[i + d];
                ai[i + d] = sw ? ti : ai[i + d];
            }
        }
    }
}

__global__ __launch_bounds__(64) void hqt_k4_sos(
    const float* __restrict__ kp1_desc, const float* __restrict__ w_desc,
    const int* __restrict__ cid4, const int* __restrict__ wcc16,
    const int* __restrict__ wid4, float* __restrict__ acc) {
    int bn = blockIdx.x;
    int b = bn / N_;
    int lane = threadIdx.x;
    __shared__ float qk[C_], qw[C_];
    for (int c = lane; c < C_; c += 64) {
        qk[c] = kp1_desc[(size_t)bn * C_ + c];
        qw[c] = w_desc[(size_t)bn * C_ + c];
    }
    __syncthreads();
    int nk[4];
#pragma unroll
    for (int i = 0; i < 4; ++i) nk[i] = cid4[4 * bn + i];
    int nw[16];
#pragma unroll
    for (int i = 0; i < 16; ++i) nw[i] = wcc16[16 * bn + i];

    float kv[8], wv[8]; int ki[8], wi[8];
#pragma unroll
    for (int k = 0; k < 8; ++k) {
        kv[k] = 1e30f; wv[k] = 1e30f; ki[k] = INT_MAX; wi[k] = INT_MAX;
    }
    const float* kb = kp1_desc + (size_t)b * N_ * C_;
    const float* wb = w_desc + (size_t)b * N_ * C_;
    for (int tt = 0; tt < 8; ++tt) {
        int m = lane * 8 + tt;
        const float* rk = kb + (size_t)m * C_;
        const float* rw = wb + (size_t)m * C_;
        float dk = 0.0f, dw = 0.0f;
        for (int c = 0; c < C_; c += 4) {
            float4 xk = *(const float4*)(rk + c);
            float4 xw = *(const float4*)(rw + c);
            dk += qk[c] * xk.x + qk[c + 1] * xk.y + qk[c + 2] * xk.z + qk[c + 3] * xk.w;
            dw += qw[c] * xw.x + qw[c + 1] * xw.y + qw[c + 2] * xw.z + qw[c + 3] * xw.w;
        }
        int4 mc = *(const int4*)(cid4 + 4 * (b * N_ + m));
        int ck = 0;
#pragma unroll
        for (int i = 0; i < 4; ++i) {
            int u = nk[i];
            ck += (u == mc.x) + (u == mc.y) + (u == mc.z) + (u == mc.w);
        }
        int4 mw = *(const int4*)(wid4 + 4 * (b * N_ + m));
        int cw = 0;
#pragma unroll
        for (int i = 0; i < 16; ++i) {
            int u = nw[i];
            cw += (u == mw.x) + (u == mw.y) + (u == mw.z) + (u == mw.w);
        }
        float vk = 2.0f - 2.0f * dk + 5.0f * (float)ck;
        float vw2 = 2.0f - 2.0f * dw + 5.0f * (float)cw;
        insert8_vi(kv, ki, vk, m);
        insert8_vi(wv, wi, vw2, m);
    }

    __shared__ float mvs[64][9];
    __shared__ int mis[64][9];
    __shared__ int fk[8], fw[8];

#pragma unroll
    for (int i = 0; i < 8; ++i) { mvs[lane][i] = kv[i]; mis[lane][i] = ki[i]; }
    __syncthreads();
    for (int step = 32; step >= 1; step >>= 1) {
        if (lane < step) {
            float bv[8]; int bix[8];
#pragma unroll
            for (int i = 0; i < 8; ++i) {
                bv[i] = mvs[lane + step][7 - i];
                bix[i] = mis[lane + step][7 - i];
            }
#pragma unroll
            for (int i = 0; i < 8; ++i) {
                bool ta = (kv[i] < bv[i]) || (kv[i] == bv[i] && ki[i] < bix[i]);
                kv[i] = ta ? kv[i] : bv[i];
                ki[i] = ta ? ki[i] : bix[i];
            }
            bitonic8_pairs(kv, ki);
#pragma unroll
            for (int i = 0; i < 8; ++i) { mvs[lane][i] = kv[i]; mis[lane][i] = ki[i]; }
        }
        __syncthreads();
    }
    if (lane < 8) fk[lane] = mis[0][lane];
    __syncthreads();

#pragma unroll
    for (int i = 0; i < 8; ++i) { mvs[lane][i] = wv[i]; mis[lane][i] = wi[i]; }
    __syncthreads();
    for (int step = 32; step >= 1; step >>= 1) {
        if (lane < step) {
            float bv[8]; int bix[8];
#pragma unroll
            for (int i = 0; i < 8; ++i) {
                bv[i] = mvs[lane + step][7 - i];
                bix[i] = mis[lane + step][7 - i];
            }
#pragma unroll
            for (int i = 0; i < 8; ++i) {
                bool ta = (wv[i] < bv[i]) || (wv[i] == bv[i] && wi[i] < bix[i]);
                wv[i] = ta ? wv[i] : bv[i];
                wi[i] = ta ? wi[i] : bix[i];
            }
            bitonic8_pairs(wv, wi);
#pragma unroll
            for (int i = 0; i < 8; ++i) { mvs[lane][i] = wv[i]; mis[lane][i] = wi[i]; }
        }
        __syncthreads();
    }
    if (lane < 8) fw[lane] = mis[0][lane];
    __syncthreads();

    int s = lane >> 3, p = lane & 7;
    const float* rk = kb + (size_t)fk[s] * C_;
    const float* rw = wb + (size_t)fw[s] * C_;
    float dk = 0.0f, dw = 0.0f;
    for (int c = p; c < C_; c += 8) {
        dk += qk[c] * rk[c];
        dw += qw[c] * rw[c];
    }
    dk += __shfl_xor(dk, 1); dk += __shfl_xor(dk, 2); dk += __shfl_xor(dk, 4);
    dw += __shfl_xor(dw, 1); dw += __shfl_xor(dw, 2); dw += __shfl_xor(dw, 4);
    __shared__ float tsq[8];
    if (p == 0) {
        float t2 = 2.0f * (dw - dk);
        tsq[s] = t2 * t2;
    }
    __syncthreads();
    if (lane == 0) {
        float s8 = 0.0f;
#pragma unroll
        for (int i = 0; i < 8; ++i) s8 += tsq[i];
        atomicAdd(acc + 1, sqrtf(s8));
    }
}

// ===========================================================================
extern "C" void kernel_launch(void* const* d_in, const int* in_sizes, int n_in,
                              void* d_out, int out_size, void* d_ws, size_t ws_size,
                              hipStream_t stream) {
    const float* kp1      = (const float*)d_in[0];
    const float* w_kp1    = (const float*)d_in[1];
    const float* kp1_desc = (const float*)d_in[2];
    const float* desc2    = (const float*)d_in[3];
    const float* homo     = (const float*)d_in[4];
    float* out = (float*)d_out;

    // ---- workspace layout (new path) ----
    char* p = (char*)d_ws;
    auto alloc = [&](size_t bytes) {
        char* r = p;
        p += (bytes + 255) & ~(size_t)255;
        return r;
    };
    float*          pos    = (float*)alloc((size_t)B_ * N_ * 4);
    int*            cid4   = (int*)alloc((size_t)B_ * N_ * 4 * 4);
    int*            wid4   = (int*)alloc((size_t)B_ * N_ * 4 * 4);
    int*            wcc16  = (int*)alloc((size_t)B_ * N_ * 16 * 4);
    unsigned int*   marked = (unsigned int*)alloc((size_t)B_ * N_ * 16 * 4);
    float*          acc    = (float*)alloc(64);
    unsigned short* q_bf   = (unsigned short*)alloc((size_t)B_ * N_ * C_ * 2);
    unsigned short* w_bf   = (unsigned short*)alloc((size_t)B_ * N_ * C_ * 2);
    unsigned short* d2t    = (unsigned short*)alloc((size_t)B_ * HW_ * C_ * 2);
    float*          rowmax = (float*)alloc((size_t)B_ * N_ * 128 * 4);
    float*          t32    = (float*)alloc((size_t)B_ * N_ * 4);
    int*            scnt   = (int*)alloc((size_t)B_ * N_ * 4);
    float2*         sbuf   = (float2*)alloc((size_t)B_ * N_ * SCAP_ * 8);
    size_t need = (size_t)(p - (char*)d_ws);

    if (ws_size >= need) {
        hqt_k0<<<1157, 256, 0, stream>>>(desc2, kp1_desc, kp1, w_kp1, homo,
                                         d2t, q_bf, cid4, wcc16, wid4, marked,
                                         scnt, acc);
        hqt_k2_sample<<<B_ * N_, 128, 0, stream>>>(w_kp1, desc2, kp1_desc,
                                                   w_bf, pos);
        hqt_k3a<<<256, 512, 0, stream>>>(q_bf, d2t, rowmax);
        hqt_k3b<<<256, 256, 0, stream>>>(rowmax, t32);
        hqt_k3c<<<256, 512, 0, stream>>>(q_bf, d2t, t32, scnt, sbuf);
        hqt_k3d<<<256, 256, 0, stream>>>(q_bf, d2t, marked, scnt, sbuf, pos, acc);
        hqt_k4m<<<64, 256, 0, stream>>>(q_bf, w_bf, cid4, wcc16, wid4, acc);
        hqt_k5_final<<<1, 1, 0, stream>>>(acc, out);
    } else {
        // fallback: round-1 layout and path
        float* w_desc0 = (float*)d_ws;
        float* pos0    = w_desc0 + (size_t)B_ * N_ * C_;
        int*   cid40   = (int*)(pos0 + B_ * N_);
        int*   wid40   = cid40 + B_ * N_ * 4;
        int*   wcc160  = wid40 + B_ * N_ * 4;
        float* acc0    = (float*)(wcc160 + B_ * N_ * 16);
        hipMemsetAsync(acc0, 0, 2 * sizeof(float), stream);
        hqt_k1_cells<<<(B_ * N_ + 255) / 256, 256, 0, stream>>>(
            kp1, w_kp1, homo, cid40, wcc160, wid40);
        hqt_k2_sample_f32<<<B_ * N_, 128, 0, stream>>>(w_kp1, desc2, kp1_desc,
                                                       w_desc0, pos0);
        hqt_k3_dsim<<<B_ * (N_ / R3), T3, 0, stream>>>(desc2, kp1_desc, wcc160,
                                                       pos0, acc0);
        hqt_k4_sos<<<B_ * N_, 64, 0, stream>>>(kp1_desc, w_desc0, cid40,
                                               wcc160, wid40, acc0);
        hqt_k5_final<<<1, 1, 0, stream>>>(acc0, out);
    }
}

// Round 5
// 167.462 us; speedup vs baseline: 1.6529x; 1.1949x over previous
//
#include <hip/hip_runtime.h>
#include <climits>

#define B_ 2
#define N_ 512
#define C_ 128
#define H_ 128
#define W_ 128
#define HW_ (H_ * W_)
#define NUM_NEG_ 16
#define SOS_NEG_ 8
#define SCAP_ 128   // survivor cap per row

typedef __attribute__((ext_vector_type(8))) short short8;
typedef __attribute__((ext_vector_type(4))) float f32x4;

__device__ inline unsigned int f2bf(float x) {
    unsigned int u = __float_as_uint(x);
    return (u + 0x7FFFu + ((u >> 16) & 1u)) >> 16;
}
__device__ inline float bf2f(unsigned int h) {
    return __uint_as_float(h << 16);
}

// ---------------------------------------------------------------------------
// 4 nearest grid-cell centers of point (y,x). Cell (yi,xi) center at
// (8*yi+4, 8*xi+4), id = yi*128+xi. 4-nearest always in clamped 4x4 window;
// tie-break (dist, then lower id) matches lax.top_k.
// ---------------------------------------------------------------------------
__device__ inline void nearest4(float y, float x, int out[4]) {
    y = fminf(fmaxf(y, -1e6f), 1e6f);
    x = fminf(fmaxf(x, -1e6f), 1e6f);
    int fy = (int)floorf(y * 0.125f - 0.5f);
    int fx = (int)floorf(x * 0.125f - 0.5f);
    int ylo = fy - 1; if (ylo < 0) ylo = 0; if (ylo > H_ - 4) ylo = H_ - 4;
    int xlo = fx - 1; if (xlo < 0) xlo = 0; if (xlo > W_ - 4) xlo = W_ - 4;
    float bd[4] = {1e30f, 1e30f, 1e30f, 1e30f};
    int   bi[4] = {INT_MAX, INT_MAX, INT_MAX, INT_MAX};
#pragma unroll
    for (int dyi = 0; dyi < 4; ++dyi) {
        int yi = ylo + dyi;
        float dy = y - (8.0f * yi + 4.0f);
        float dy2 = dy * dy;
#pragma unroll
        for (int dxi = 0; dxi < 4; ++dxi) {
            int xi = xlo + dxi;
            float dx = x - (8.0f * xi + 4.0f);
            float d = dy2 + dx * dx;
            int id = yi * W_ + xi;
#pragma unroll
            for (int k = 0; k < 4; ++k) {
                bool sm = (d < bd[k]) || (d == bd[k] && id < bi[k]);
                float od = bd[k]; int oi = bi[k];
                bd[k] = sm ? d : od;  bi[k] = sm ? id : oi;
                d = sm ? od : d;      id = sm ? oi : id;
            }
        }
    }
    out[0] = bi[0]; out[1] = bi[1]; out[2] = bi[2]; out[3] = bi[3];
}

__device__ inline void k1_body(int t, const float* kp1, const float* w_kp1,
                               const float* homo, int* cid4, int* wcc16,
                               int* wid4, unsigned int* marked) {
    int b = t / N_;
    float ky = kp1[2 * t], kx = kp1[2 * t + 1];
    int ids[4];
    nearest4(ky, kx, ids);
    const float* Hb = homo + 9 * b;
    float h00 = Hb[0], h01 = Hb[1], h02 = Hb[2];
    float h10 = Hb[3], h11 = Hb[4], h12 = Hb[5];
    float h20 = Hb[6], h21 = Hb[7], h22 = Hb[8];
    int w16[16];
#pragma unroll
    for (int i = 0; i < 4; ++i) {
        int id = ids[i];
        cid4[4 * t + i] = id;
        float cy = 8.0f * (id >> 7) + 4.0f;
        float cx = 8.0f * (id & 127) + 4.0f;
        float X = cx, Y = cy;
        float wz = h20 * X + h21 * Y + h22;
        float inv = 1.0f / (wz + 1e-8f);
        float wy = (h10 * X + h11 * Y + h12) * inv;
        float wx = (h00 * X + h01 * Y + h02) * inv;
        int wids[4];
        nearest4(wy, wx, wids);
#pragma unroll
        for (int j = 0; j < 4; ++j) {
            w16[4 * i + j] = wids[j];
            wcc16[16 * t + 4 * i + j] = wids[j];
        }
    }
    // dedup with multiplicity: slot i canonical iff first occurrence
#pragma unroll
    for (int i = 0; i < 16; ++i) {
        int cnt = 0; bool first = true;
#pragma unroll
        for (int j = 0; j < 16; ++j) {
            bool eq = (w16[j] == w16[i]);
            cnt += eq ? 1 : 0;
            if (j < i && eq) first = false;
        }
        marked[16 * t + i] = first ? ((unsigned int)w16[i] | ((unsigned int)cnt << 16))
                                   : 0xFFFFFFFFu;
    }
    float zy = w_kp1[2 * t], zx = w_kp1[2 * t + 1];
    int wi4[4];
    nearest4(zy, zx, wi4);
#pragma unroll
    for (int j = 0; j < 4; ++j) wid4[4 * t + j] = wi4[j];
}

// ---------------------------------------------------------------------------
// K0 fused: [0,1024) transpose+convert desc2 -> d2t_bf[b][j][c];
// [1024,1152) convert kp1_desc -> q_bf; 1152 zero scnt/acc; [1153,1157) k1.
// ---------------------------------------------------------------------------
__global__ __launch_bounds__(256) void hqt_k0(
    const float* __restrict__ desc2, const float* __restrict__ kp1_desc,
    const float* __restrict__ kp1, const float* __restrict__ w_kp1,
    const float* __restrict__ homo,
    unsigned short* __restrict__ d2t, unsigned short* __restrict__ q_bf,
    int* __restrict__ cid4, int* __restrict__ wcc16, int* __restrict__ wid4,
    unsigned int* __restrict__ marked, int* __restrict__ scnt,
    float* __restrict__ acc) {
    int blk = blockIdx.x;
    int tid = threadIdx.x;
    if (blk < 1024) {
        __shared__ float tile[32][129];
        int b = blk >> 9;
        int j0 = (blk & 511) * 32;
        int jj = tid & 31, cg = tid >> 5;
        const float* src = desc2 + (size_t)b * C_ * HW_;
#pragma unroll
        for (int cc = 0; cc < 16; ++cc) {
            int c = cg * 16 + cc;
            tile[jj][c] = src[(size_t)c * HW_ + j0 + jj];
        }
        __syncthreads();
        int row = tid >> 3, c8 = (tid & 7) * 16;
        unsigned int tmp[16];
#pragma unroll
        for (int k = 0; k < 16; ++k) tmp[k] = f2bf(tile[row][c8 + k]);
        uint4 o0, o1;
        o0.x = tmp[0] | (tmp[1] << 16);  o0.y = tmp[2] | (tmp[3] << 16);
        o0.z = tmp[4] | (tmp[5] << 16);  o0.w = tmp[6] | (tmp[7] << 16);
        o1.x = tmp[8] | (tmp[9] << 16);  o1.y = tmp[10] | (tmp[11] << 16);
        o1.z = tmp[12] | (tmp[13] << 16); o1.w = tmp[14] | (tmp[15] << 16);
        unsigned short* dst = d2t + ((size_t)(b << 14) + j0 + row) * C_ + c8;
        ((uint4*)dst)[0] = o0;
        ((uint4*)dst)[1] = o1;
    } else if (blk < 1152) {
        int idx = (blk - 1024) * 256 + tid;   // 4 elems each, 131072 total
        float4 v = *(const float4*)(kp1_desc + (size_t)idx * 4);
        uint2 u;
        u.x = f2bf(v.x) | (f2bf(v.y) << 16);
        u.y = f2bf(v.z) | (f2bf(v.w) << 16);
        *(uint2*)(q_bf + (size_t)idx * 4) = u;
    } else if (blk == 1152) {
        ((int4*)scnt)[tid] = make_int4(0, 0, 0, 0);
        if (tid == 0) { acc[0] = 0.0f; acc[1] = 0.0f; }
    } else {
        int t = (blk - 1153) * 256 + tid;
        if (t < B_ * N_)
            k1_body(t, kp1, w_kp1, homo, cid4, wcc16, wid4, marked);
    }
}

// ---------------------------------------------------------------------------
// K2: bilinear-sample desc2 at w_kp1, normalize -> w_bf (bf16) ; pos.
// ---------------------------------------------------------------------------
__global__ __launch_bounds__(128) void hqt_k2_sample(
    const float* __restrict__ w_kp1, const float* __restrict__ desc2,
    const float* __restrict__ kp1_desc, unsigned short* __restrict__ w_bf,
    float* __restrict__ pos) {
    int bn = blockIdx.x;
    int b = bn / N_;
    int c = threadIdx.x;
    float ky = w_kp1[2 * bn], kx = w_kp1[2 * bn + 1];
    float y = fminf(fmaxf(ky * 0.125f - 0.5f, 0.0f), (float)(H_ - 1));
    float x = fminf(fmaxf(kx * 0.125f - 0.5f, 0.0f), (float)(W_ - 1));
    int y0 = (int)floorf(y); if (y0 > H_ - 2) y0 = H_ - 2;
    int x0 = (int)floorf(x); if (x0 > W_ - 2) x0 = W_ - 2;
    float wy = y - (float)y0, wx = x - (float)x0;
    const float* dB = desc2 + ((size_t)b * C_ + c) * HW_;
    int i00 = y0 * W_ + x0;
    float v = dB[i00]          * (1.0f - wy) * (1.0f - wx)
            + dB[i00 + 1]      * (1.0f - wy) * wx
            + dB[i00 + W_]     * wy * (1.0f - wx)
            + dB[i00 + W_ + 1] * wy * wx;
    __shared__ float red[128];
    red[c] = v * v;
    __syncthreads();
    for (int s = 64; s > 0; s >>= 1) {
        if (c < s) red[c] += red[c + s];
        __syncthreads();
    }
    float nrm = sqrtf(red[0]);
    __syncthreads();
    float vn = v / (nrm + 1e-8f);
    w_bf[(size_t)bn * C_ + c] = (unsigned short)f2bf(vn);
    float qd = kp1_desc[(size_t)bn * C_ + c];
    red[c] = qd * vn;
    __syncthreads();
    for (int s = 64; s > 0; s >>= 1) {
        if (c < s) red[c] += red[c + s];
        __syncthreads();
    }
    if (c == 0) pos[bn] = 2.0f - 2.0f * red[0];
}

// f32 variant for the fallback path
__global__ __launch_bounds__(128) void hqt_k2_sample_f32(
    const float* __restrict__ w_kp1, const float* __restrict__ desc2,
    const float* __restrict__ kp1_desc, float* __restrict__ w_desc,
    float* __restrict__ pos) {
    int bn = blockIdx.x;
    int b = bn / N_;
    int c = threadIdx.x;
    float ky = w_kp1[2 * bn], kx = w_kp1[2 * bn + 1];
    float y = fminf(fmaxf(ky * 0.125f - 0.5f, 0.0f), (float)(H_ - 1));
    float x = fminf(fmaxf(kx * 0.125f - 0.5f, 0.0f), (float)(W_ - 1));
    int y0 = (int)floorf(y); if (y0 > H_ - 2) y0 = H_ - 2;
    int x0 = (int)floorf(x); if (x0 > W_ - 2) x0 = W_ - 2;
    float wy = y - (float)y0, wx = x - (float)x0;
    const float* dB = desc2 + ((size_t)b * C_ + c) * HW_;
    int i00 = y0 * W_ + x0;
    float v = dB[i00]          * (1.0f - wy) * (1.0f - wx)
            + dB[i00 + 1]      * (1.0f - wy) * wx
            + dB[i00 + W_]     * wy * (1.0f - wx)
            + dB[i00 + W_ + 1] * wy * wx;
    __shared__ float red[128];
    red[c] = v * v;
    __syncthreads();
    for (int s = 64; s > 0; s >>= 1) {
        if (c < s) red[c] += red[c + s];
        __syncthreads();
    }
    float nrm = sqrtf(red[0]);
    __syncthreads();
    float vn = v / (nrm + 1e-8f);
    w_desc[(size_t)bn * C_ + c] = vn;
    float qd = kp1_desc[(size_t)bn * C_ + c];
    red[c] = qd * vn;
    __syncthreads();
    for (int s = 64; s > 0; s >>= 1) {
        if (c < s) red[c] += red[c + s];
        __syncthreads();
    }
    if (c == 0) pos[bn] = 2.0f - 2.0f * red[0];
}

// ---------------------------------------------------------------------------
// K3a: MFMA pass 1. Block: 64 rows x 1024 cols, 8 waves (128 cols each).
// ---------------------------------------------------------------------------
__global__ __launch_bounds__(512) void hqt_k3a(
    const unsigned short* __restrict__ q_bf,
    const unsigned short* __restrict__ d2t,
    float* __restrict__ rowmax) {
    int blk = blockIdx.x;           // 256 = 2b x 8rg x 16cb
    int b = blk >> 7;
    int rg = (blk >> 4) & 7;
    int cb = blk & 15;
    int tid = threadIdx.x, w = tid >> 6, l = tid & 63;
    int l15 = l & 15, lg = l >> 4;
    int rowbase = rg * 64;
    int colbase = cb * 1024 + w * 128;
    const unsigned short* qb = q_bf + (size_t)b * N_ * C_;
    const unsigned short* db = d2t + (size_t)b * HW_ * C_;
    short8 a[4][4];
#pragma unroll
    for (int rt = 0; rt < 4; ++rt)
#pragma unroll
        for (int ks = 0; ks < 4; ++ks)
            a[rt][ks] = *(const short8*)(qb + (size_t)(rowbase + rt * 16 + l15) * C_ + ks * 32 + lg * 8);
    f32x4 mx[4];
#pragma unroll
    for (int rt = 0; rt < 4; ++rt) mx[rt] = f32x4{-1e30f, -1e30f, -1e30f, -1e30f};
#pragma unroll
    for (int t = 0; t < 8; ++t) {
        const unsigned short* dp = db + (size_t)(colbase + t * 16 + l15) * C_ + lg * 8;
        short8 b0 = *(const short8*)(dp);
        short8 b1 = *(const short8*)(dp + 32);
        short8 b2 = *(const short8*)(dp + 64);
        short8 b3 = *(const short8*)(dp + 96);
#pragma unroll
        for (int rt = 0; rt < 4; ++rt) {
            f32x4 acc4 = {0.0f, 0.0f, 0.0f, 0.0f};
            acc4 = __builtin_amdgcn_mfma_f32_16x16x32_bf16(a[rt][0], b0, acc4, 0, 0, 0);
            acc4 = __builtin_amdgcn_mfma_f32_16x16x32_bf16(a[rt][1], b1, acc4, 0, 0, 0);
            acc4 = __builtin_amdgcn_mfma_f32_16x16x32_bf16(a[rt][2], b2, acc4, 0, 0, 0);
            acc4 = __builtin_amdgcn_mfma_f32_16x16x32_bf16(a[rt][3], b3, acc4, 0, 0, 0);
#pragma unroll
            for (int r = 0; r < 4; ++r) mx[rt][r] = fmaxf(mx[rt][r], acc4[r]);
        }
    }
#pragma unroll
    for (int rt = 0; rt < 4; ++rt)
#pragma unroll
        for (int r = 0; r < 4; ++r) {
            float v = mx[rt][r];
            v = fmaxf(v, __shfl_xor(v, 1));
            v = fmaxf(v, __shfl_xor(v, 2));
            v = fmaxf(v, __shfl_xor(v, 4));
            v = fmaxf(v, __shfl_xor(v, 8));
            mx[rt][r] = v;
        }
    if (l15 == 0) {
        int chunk = cb * 8 + w;
#pragma unroll
        for (int rt = 0; rt < 4; ++rt)
#pragma unroll
            for (int r = 0; r < 4; ++r) {
                int rowg = b * N_ + rowbase + rt * 16 + lg * 4 + r;
                rowmax[(size_t)rowg * 128 + chunk] = mx[rt][r];
            }
    }
}

// ---------------------------------------------------------------------------
// K3b: per row, t = 32nd-largest of 128 window maxes.
// ---------------------------------------------------------------------------
__global__ __launch_bounds__(256) void hqt_k3b(
    const float* __restrict__ rowmax, float* __restrict__ t32) {
    int w = threadIdx.x >> 6, l = threadIdx.x & 63;
    int row = blockIdx.x * 4 + w;
    const float* rm = rowmax + (size_t)row * 128;
    float v = fmaxf(rm[l], rm[64 + l]);
    float t = -1e30f;
#pragma unroll 1
    for (int it = 0; it < 32; ++it) {
        float m = v;
        m = fmaxf(m, __shfl_xor(m, 1));
        m = fmaxf(m, __shfl_xor(m, 2));
        m = fmaxf(m, __shfl_xor(m, 4));
        m = fmaxf(m, __shfl_xor(m, 8));
        m = fmaxf(m, __shfl_xor(m, 16));
        m = fmaxf(m, __shfl_xor(m, 32));
        v = (v == m) ? -1e30f : v;
        t = m;
    }
    if (l == 0) t32[row] = t;
}

// ---------------------------------------------------------------------------
// K3c: MFMA pass 2: push (dot, col) with dot >= t[row] into survivor buffer.
// ---------------------------------------------------------------------------
__global__ __launch_bounds__(512) void hqt_k3c(
    const unsigned short* __restrict__ q_bf,
    const unsigned short* __restrict__ d2t,
    const float* __restrict__ t32,
    int* __restrict__ scnt, float2* __restrict__ sbuf) {
    int blk = blockIdx.x;
    int b = blk >> 7;
    int rg = (blk >> 4) & 7;
    int cb = blk & 15;
    int tid = threadIdx.x, w = tid >> 6, l = tid & 63;
    int l15 = l & 15, lg = l >> 4;
    int rowbase = rg * 64;
    int colbase = cb * 1024 + w * 128;
    const unsigned short* qb = q_bf + (size_t)b * N_ * C_;
    const unsigned short* db = d2t + (size_t)b * HW_ * C_;
    short8 a[4][4];
#pragma unroll
    for (int rt = 0; rt < 4; ++rt)
#pragma unroll
        for (int ks = 0; ks < 4; ++ks)
            a[rt][ks] = *(const short8*)(qb + (size_t)(rowbase + rt * 16 + l15) * C_ + ks * 32 + lg * 8);
    float tl[4][4];
#pragma unroll
    for (int rt = 0; rt < 4; ++rt)
#pragma unroll
        for (int r = 0; r < 4; ++r)
            tl[rt][r] = t32[b * N_ + rowbase + rt * 16 + lg * 4 + r];
#pragma unroll
    for (int t = 0; t < 8; ++t) {
        const unsigned short* dp = db + (size_t)(colbase + t * 16 + l15) * C_ + lg * 8;
        short8 b0 = *(const short8*)(dp);
        short8 b1 = *(const short8*)(dp + 32);
        short8 b2 = *(const short8*)(dp + 64);
        short8 b3 = *(const short8*)(dp + 96);
#pragma unroll
        for (int rt = 0; rt < 4; ++rt) {
            f32x4 acc4 = {0.0f, 0.0f, 0.0f, 0.0f};
            acc4 = __builtin_amdgcn_mfma_f32_16x16x32_bf16(a[rt][0], b0, acc4, 0, 0, 0);
            acc4 = __builtin_amdgcn_mfma_f32_16x16x32_bf16(a[rt][1], b1, acc4, 0, 0, 0);
            acc4 = __builtin_amdgcn_mfma_f32_16x16x32_bf16(a[rt][2], b2, acc4, 0, 0, 0);
            acc4 = __builtin_amdgcn_mfma_f32_16x16x32_bf16(a[rt][3], b3, acc4, 0, 0, 0);
#pragma unroll
            for (int r = 0; r < 4; ++r) {
                float d = acc4[r];
                if (d >= tl[rt][r]) {
                    int rowg = b * N_ + rowbase + rt * 16 + lg * 4 + r;
                    int idx = atomicAdd(scnt + rowg, 1);
                    if (idx < SCAP_) {
                        float2 e;
                        e.x = d;
                        e.y = __int_as_float(colbase + t * 16 + l15);
                        sbuf[(size_t)rowg * SCAP_ + idx] = e;
                    }
                }
            }
        }
    }
}

// ---------------------------------------------------------------------------
// K3d: one wave per row; exact penalized top-16 from survivors + marked.
// ---------------------------------------------------------------------------
__global__ __launch_bounds__(256) void hqt_k3d(
    const unsigned short* __restrict__ q_bf,
    const unsigned short* __restrict__ d2t,
    const unsigned int* __restrict__ marked,
    const int* __restrict__ scnt, const float2* __restrict__ sbuf,
    const float* __restrict__ pos, float* __restrict__ acc) {
    int w = threadIdx.x >> 6, l = threadIdx.x & 63;
    int row = blockIdx.x * 4 + w;
    int b = row >> 9;
    int sc = scnt[row]; if (sc > SCAP_) sc = SCAP_;
    float k0 = -1e30f, k1 = -1e30f, k2c = -1e30f;
    int c0 = -1, c1 = -1;
    if (l < sc) {
        float2 e = sbuf[(size_t)row * SCAP_ + l];
        k0 = e.x; c0 = __float_as_int(e.y);
    }
    if (64 + l < sc) {
        float2 e = sbuf[(size_t)row * SCAP_ + 64 + l];
        k1 = e.x; c1 = __float_as_int(e.y);
    }
#pragma unroll
    for (int i = 0; i < 16; ++i) {
        unsigned int mv = marked[row * 16 + i];
        int id = (int)(mv & 0xFFFFu);
        if (c0 == id) k0 = -1e30f;
        if (c1 == id) k1 = -1e30f;
    }
    {
        int mi = l >> 2, cq = l & 3;
        unsigned int mv = marked[row * 16 + mi];
        bool valid = (mv != 0xFFFFFFFFu);
        int col = valid ? (int)(mv & 0xFFFFu) : 0;
        int cnt = (int)(mv >> 16);
        const unsigned short* qp = q_bf + (size_t)row * C_ + cq * 32;
        const unsigned short* dp = d2t + ((size_t)b * HW_ + col) * C_ + cq * 32;
        float dot = 0.0f;
#pragma unroll
        for (int u = 0; u < 4; ++u) {
            short8 qv = *(const short8*)(qp + u * 8);
            short8 dv = *(const short8*)(dp + u * 8);
#pragma unroll
            for (int e = 0; e < 8; ++e)
                dot = fmaf(bf2f((unsigned short)qv[e]), bf2f((unsigned short)dv[e]), dot);
        }
        dot += __shfl_xor(dot, 1);
        dot += __shfl_xor(dot, 2);
        k2c = (valid && cq == 0) ? (dot - 2.5f * (float)cnt) : -1e30f;
    }
    float pos_r = pos[row];
    float sum = 0.0f;
#pragma unroll 1
    for (int it = 0; it < 16; ++it) {
        float v = fmaxf(k0, fmaxf(k1, k2c));
        float m = v;
        m = fmaxf(m, __shfl_xor(m, 1));
        m = fmaxf(m, __shfl_xor(m, 2));
        m = fmaxf(m, __shfl_xor(m, 4));
        m = fmaxf(m, __shfl_xor(m, 8));
        m = fmaxf(m, __shfl_xor(m, 16));
        m = fmaxf(m, __shfl_xor(m, 32));
        unsigned long long b0 = __ballot(k0 == m);
        if (b0) {
            if (l == __ffsll(b0) - 1) k0 = -1e30f;
        } else {
            unsigned long long b1 = __ballot(k1 == m);
            if (b1) {
                if (l == __ffsll(b1) - 1) k1 = -1e30f;
            } else {
                unsigned long long b2 = __ballot(k2c == m);
                if (l == __ffsll(b2) - 1) k2c = -1e30f;
            }
        }
        float h = pos_r + 2.0f * m - 1.0f;
        h = fmaxf(h, 0.0f);
        sum += h * h;
    }
    if (l == 0) atomicAdd(acc + 0, sum);
}

// ---------------------------------------------------------------------------
// selection helpers (shared by k4b and fallback k4)
// ---------------------------------------------------------------------------
__device__ inline void insert8_vi(float (&av)[8], int (&ai)[8], float v, int id) {
    bool le = (v < av[7]) || (v == av[7] && id < ai[7]);
    if (!le) return;
#pragma unroll
    for (int k = 0; k < 8; ++k) {
        float ov = av[k]; int oi = ai[k];
        bool sm = (v < ov) || (v == ov && id < oi);
        av[k] = sm ? v : ov;  ai[k] = sm ? id : oi;
        v = sm ? ov : v;      id = sm ? oi : id;
    }
}

__device__ inline void bitonic8_pairs(float (&av)[8], int (&ai)[8]) {
#pragma unroll
    for (int dd = 0; dd < 3; ++dd) {
        const int d = 4 >> dd;
#pragma unroll
        for (int i = 0; i < 8; ++i) {
            if ((i & d) == 0) {
                bool sw = (av[i + d] < av[i]) ||
                          (av[i + d] == av[i] && ai[i + d] < ai[i]);
                float tv = av[i]; int ti = ai[i];
                av[i]     = sw ? av[i + d] : av[i];
                ai[i]     = sw ? ai[i + d] : ai[i];
                av[i + d] = sw ? tv : av[i + d];
                ai[i + d] = sw ? ti : ai[i + d];
            }
        }
    }
}

// wave-wide merge of per-lane sorted-8 (asc by (v,idx)); result in lane 0.
__device__ inline void wave_merge8(float (&av)[8], int (&ai)[8], int l) {
#pragma unroll
    for (int step = 32; step >= 1; step >>= 1) {
        float bv[8]; int bi2[8];
#pragma unroll
        for (int i = 0; i < 8; ++i) {
            bv[i]  = __shfl(av[7 - i], (l + step) & 63);
            bi2[i] = __shfl(ai[7 - i], (l + step) & 63);
        }
        bool upd = l < step;
#pragma unroll
        for (int i = 0; i < 8; ++i) {
            bool sm = (bv[i] < av[i]) || (bv[i] == av[i] && bi2[i] < ai[i]);
            if (upd && sm) { av[i] = bv[i]; ai[i] = bi2[i]; }
        }
        bitonic8_pairs(av, ai);
    }
}

// ---------------------------------------------------------------------------
// K4a: MFMA k_sim/w_sim with EAGER penalty -> psim key matrix.
// key = dot - 2.5*cnt  (dsim = 2 - 2*key, monotone decreasing in key).
// Grid: 128 = mat(2) x b(2) x rowgroup(32 of 16 rows); 256 thr (4 waves),
// wave w owns col quarter w*128..+127.
// ---------------------------------------------------------------------------
__global__ __launch_bounds__(256) void hqt_k4a(
    const unsigned short* __restrict__ q_bf,
    const unsigned short* __restrict__ w_bf,
    const int* __restrict__ cid4, const int* __restrict__ wid4,
    const int* __restrict__ wcc16, float* __restrict__ psim) {
    int blk = blockIdx.x;
    int mat = blk >> 6;
    int b = (blk >> 5) & 1;
    int r0 = (blk & 31) * 16;
    int tid = threadIdx.x, w = tid >> 6, l = tid & 63;
    int l15 = l & 15, lg = l >> 4;
    const unsigned short* src = (mat ? w_bf : q_bf) + (size_t)b * N_ * C_;

    __shared__ int s_colids[N_][4];      // cid4 (mat0) or wid4 (mat1), all 512
    __shared__ int s_rowcc[16][16];      // wcc16 of the 16 rows (mat1)
    {
        const int4* gsrc = (const int4*)((mat ? wid4 : cid4) + b * N_ * 4);
        ((int4*)s_colids)[tid]       = gsrc[tid];
        ((int4*)s_colids)[tid + 256] = gsrc[tid + 256];
        if (tid < 256) {
            // mat1 needs wcc16 rows; harmless load for mat0 too
            ((int*)s_rowcc)[tid] = wcc16[(b * N_ + r0) * 16 + tid];
        }
    }
    // A fragments for rows r0..r0+15
    short8 a0 = *(const short8*)(src + (size_t)(r0 + l15) * C_ + lg * 8);
    short8 a1 = *(const short8*)(src + (size_t)(r0 + l15) * C_ + 32 + lg * 8);
    short8 a2 = *(const short8*)(src + (size_t)(r0 + l15) * C_ + 64 + lg * 8);
    short8 a3 = *(const short8*)(src + (size_t)(r0 + l15) * C_ + 96 + lg * 8);
    __syncthreads();

    // row-side tables in registers (4 rows per lane: lg*4+r)
    int4 rowc[4];
    int rcc[4][16];
#pragma unroll
    for (int r = 0; r < 4; ++r) {
        rowc[r] = *(const int4*)(&s_colids[r0 + lg * 4 + r][0]);
        if (mat == 1) {
#pragma unroll
            for (int i = 0; i < 16; ++i) rcc[r][i] = s_rowcc[lg * 4 + r][i];
        }
    }

    float* prow = psim + ((size_t)(mat * B_ + b) * N_) * N_;
#pragma unroll
    for (int t = 0; t < 8; ++t) {
        int col0 = w * 128 + t * 16;
        const unsigned short* dp = src + (size_t)(col0 + l15) * C_ + lg * 8;
        short8 b0 = *(const short8*)(dp);
        short8 b1 = *(const short8*)(dp + 32);
        short8 b2 = *(const short8*)(dp + 64);
        short8 b3 = *(const short8*)(dp + 96);
        f32x4 acc4 = {0.0f, 0.0f, 0.0f, 0.0f};
        acc4 = __builtin_amdgcn_mfma_f32_16x16x32_bf16(a0, b0, acc4, 0, 0, 0);
        acc4 = __builtin_amdgcn_mfma_f32_16x16x32_bf16(a1, b1, acc4, 0, 0, 0);
        acc4 = __builtin_amdgcn_mfma_f32_16x16x32_bf16(a2, b2, acc4, 0, 0, 0);
        acc4 = __builtin_amdgcn_mfma_f32_16x16x32_bf16(a3, b3, acc4, 0, 0, 0);
        int mycol = col0 + l15;
        int4 cc = *(const int4*)(&s_colids[mycol][0]);
#pragma unroll
        for (int r = 0; r < 4; ++r) {
            int cnt = 0;
            if (mat == 0) {
#pragma unroll
                for (int j = 0; j < 4; ++j) {
                    int u = (j == 0) ? rowc[r].x : (j == 1) ? rowc[r].y
                          : (j == 2) ? rowc[r].z : rowc[r].w;
                    cnt += (u == cc.x) + (u == cc.y) + (u == cc.z) + (u == cc.w);
                }
            } else {
#pragma unroll
                for (int i = 0; i < 16; ++i) {
                    int u = rcc[r][i];
                    cnt += (u == cc.x) + (u == cc.y) + (u == cc.z) + (u == cc.w);
                }
            }
            float key = acc4[r] - 2.5f * (float)cnt;
            prow[(size_t)(r0 + lg * 4 + r) * N_ + mycol] = key;
        }
    }
}

// ---------------------------------------------------------------------------
// K4b: per (b,row) wave: top-8 of psimK and psimW rows (desc key, asc idx),
// recompute exact counts for the 8 selected, reconstruct clean dots, sos.
// Grid: 256 blocks x 256 thr (4 waves = 4 rows/block).
// ---------------------------------------------------------------------------
__global__ __launch_bounds__(256) void hqt_k4b(
    const float* __restrict__ psim,
    const int* __restrict__ cid4, const int* __restrict__ wid4,
    const int* __restrict__ wcc16, float* __restrict__ acc) {
    int w = threadIdx.x >> 6, l = threadIdx.x & 63;
    int rowg = blockIdx.x * 4 + w;          // 0..1023
    int b = rowg >> 9;
    int row = rowg & 511;

    __shared__ float s_kv[4][8], s_wv[4][8];
    __shared__ int   s_ki[4][8], s_wi[4][8];

    // ---- K selection ----
    float kv[8]; int ki[8];
#pragma unroll
    for (int i = 0; i < 8; ++i) { kv[i] = 1e30f; ki[i] = INT_MAX; }
    {
        const float* pk = psim + ((size_t)(0 * B_ + b) * N_ + row) * N_;
        float4 u0 = ((const float4*)pk)[l * 2];
        float4 u1 = ((const float4*)pk)[l * 2 + 1];
        insert8_vi(kv, ki, -u0.x, l * 8 + 0);
        insert8_vi(kv, ki, -u0.y, l * 8 + 1);
        insert8_vi(kv, ki, -u0.z, l * 8 + 2);
        insert8_vi(kv, ki, -u0.w, l * 8 + 3);
        insert8_vi(kv, ki, -u1.x, l * 8 + 4);
        insert8_vi(kv, ki, -u1.y, l * 8 + 5);
        insert8_vi(kv, ki, -u1.z, l * 8 + 6);
        insert8_vi(kv, ki, -u1.w, l * 8 + 7);
    }
    wave_merge8(kv, ki, l);
    if (l == 0) {
#pragma unroll
        for (int i = 0; i < 8; ++i) { s_kv[w][i] = -kv[i]; s_ki[w][i] = ki[i]; }
    }

    // ---- W selection ----
    float wv[8]; int wi[8];
#pragma unroll
    for (int i = 0; i < 8; ++i) { wv[i] = 1e30f; wi[i] = INT_MAX; }
    {
        const float* pw = psim + ((size_t)(1 * B_ + b) * N_ + row) * N_;
        float4 u0 = ((const float4*)pw)[l * 2];
        float4 u1 = ((const float4*)pw)[l * 2 + 1];
        insert8_vi(wv, wi, -u0.x, l * 8 + 0);
        insert8_vi(wv, wi, -u0.y, l * 8 + 1);
        insert8_vi(wv, wi, -u0.z, l * 8 + 2);
        insert8_vi(wv, wi, -u0.w, l * 8 + 3);
        insert8_vi(wv, wi, -u1.x, l * 8 + 4);
        insert8_vi(wv, wi, -u1.y, l * 8 + 5);
        insert8_vi(wv, wi, -u1.z, l * 8 + 6);
        insert8_vi(wv, wi, -u1.w, l * 8 + 7);
    }
    wave_merge8(wv, wi, l);
    if (l == 0) {
#pragma unroll
        for (int i = 0; i < 8; ++i) { s_wv[w][i] = -wv[i]; s_wi[w][i] = wi[i]; }
    }

    // ---- sos: 8 slot-lanes reconstruct clean dots ----
    if (l < 8) {
        int kidx = s_ki[w][l]; float kkey = s_kv[w][l];
        int widx = s_wi[w][l]; float wkey = s_wv[w][l];
        const int4* cb  = (const int4*)(cid4 + b * N_ * 4);
        const int4* wb4 = (const int4*)(wid4 + b * N_ * 4);
        int4 rc = cb[row];
        int4 mc = cb[kidx];
        int cntK = 0;
#pragma unroll
        for (int j = 0; j < 4; ++j) {
            int u = (j == 0) ? rc.x : (j == 1) ? rc.y : (j == 2) ? rc.z : rc.w;
            cntK += (u == mc.x) + (u == mc.y) + (u == mc.z) + (u == mc.w);
        }
        int4 mw = wb4[widx];
        int cntW = 0;
        const int4* rcc = (const int4*)(wcc16 + (b * N_ + row) * 16);
#pragma unroll
        for (int uq = 0; uq < 4; ++uq) {
            int4 rr = rcc[uq];
            cntW += (rr.x == mw.x) + (rr.x == mw.y) + (rr.x == mw.z) + (rr.x == mw.w);
            cntW += (rr.y == mw.x) + (rr.y == mw.y) + (rr.y == mw.z) + (rr.y == mw.w);
            cntW += (rr.z == mw.x) + (rr.z == mw.y) + (rr.z == mw.z) + (rr.z == mw.w);
            cntW += (rr.w == mw.x) + (rr.w == mw.y) + (rr.w == mw.z) + (rr.w == mw.w);
        }
        float dotK = kkey + 2.5f * (float)cntK;
        float dotW = wkey + 2.5f * (float)cntW;
        float t2 = 2.0f * (dotW - dotK);
        float sq = t2 * t2;
        sq += __shfl_xor(sq, 1);
        sq += __shfl_xor(sq, 2);
        sq += __shfl_xor(sq, 4);
        if (l == 0) atomicAdd(acc + 1, sqrtf(sq));
    }
}

__global__ void hqt_k5_final(const float* __restrict__ acc, float* __restrict__ out) {
    if (threadIdx.x == 0 && blockIdx.x == 0) {
        out[0] = acc[0] * (1.0f / (float)(B_ * N_ * NUM_NEG_))
               + acc[1] * (1.0f / (float)(B_ * N_));
    }
}

// ======================= fallback (round-1) kernels ========================
__global__ void hqt_k1_cells(const float* __restrict__ kp1,
                             const float* __restrict__ w_kp1,
                             const float* __restrict__ homo,
                             int* __restrict__ cid4,
                             int* __restrict__ wcc16,
                             int* __restrict__ wid4) {
    int t = blockIdx.x * blockDim.x + threadIdx.x;
    if (t >= B_ * N_) return;
    int b = t / N_;
    float ky = kp1[2 * t], kx = kp1[2 * t + 1];
    int ids[4];
    nearest4(ky, kx, ids);
    const float* Hb = homo + 9 * b;
    float h00 = Hb[0], h01 = Hb[1], h02 = Hb[2];
    float h10 = Hb[3], h11 = Hb[4], h12 = Hb[5];
    float h20 = Hb[6], h21 = Hb[7], h22 = Hb[8];
#pragma unroll
    for (int i = 0; i < 4; ++i) {
        int id = ids[i];
        cid4[4 * t + i] = id;
        float cy = 8.0f * (id >> 7) + 4.0f;
        float cx = 8.0f * (id & 127) + 4.0f;
        float X = cx, Y = cy;
        float wz = h20 * X + h21 * Y + h22;
        float inv = 1.0f / (wz + 1e-8f);
        float wy = (h10 * X + h11 * Y + h12) * inv;
        float wx = (h00 * X + h01 * Y + h02) * inv;
        int wids[4];
        nearest4(wy, wx, wids);
#pragma unroll
        for (int j = 0; j < 4; ++j) wcc16[16 * t + 4 * i + j] = wids[j];
    }
    float zy = w_kp1[2 * t], zx = w_kp1[2 * t + 1];
    int wi4[4];
    nearest4(zy, zx, wi4);
#pragma unroll
    for (int j = 0; j < 4; ++j) wid4[4 * t + j] = wi4[j];
}

__device__ inline void bitonic16_asc(float (&a)[16]) {
#pragma unroll
    for (int dd = 0; dd < 4; ++dd) {
        const int d = 8 >> dd;
#pragma unroll
        for (int i = 0; i < 16; ++i) {
            if ((i & d) == 0) {
                float lo = fminf(a[i], a[i + d]);
                float hi = fmaxf(a[i], a[i + d]);
                a[i] = lo; a[i + d] = hi;
            }
        }
    }
}

#define T3 512
#define R3 4
__global__ __launch_bounds__(T3) void hqt_k3_dsim(
    const float* __restrict__ desc2, const float* __restrict__ kp1_desc,
    const int* __restrict__ wcc16, const float* __restrict__ pos,
    float* __restrict__ acc) {
    const int nb = N_ / R3;
    int b = blockIdx.x / nb;
    int n0 = (blockIdx.x % nb) * R3;
    int tid = threadIdx.x;
    __shared__ float qT[C_][R3];
    __shared__ int ids_s[R3][16];
    {
        int r = tid & 3, c = tid >> 2;
        qT[c][r] = kp1_desc[(size_t)(b * N_ + n0 + r) * C_ + c];
    }
    if (tid < R3 * 16)
        ids_s[tid >> 4][tid & 15] = wcc16[(b * N_ + n0) * 16 + tid];
    __syncthreads();

    float top[R3][16];
#pragma unroll
    for (int r = 0; r < R3; ++r)
#pragma unroll
        for (int k = 0; k < 16; ++k) top[r][k] = 1e30f;

    const float* d2b = desc2 + (size_t)b * C_ * HW_;
#pragma unroll 1
    for (int g = 0; g < HW_ / (T3 * 4); ++g) {
        int j0 = (g * T3 + tid) * 4;
        float4 A0 = {0, 0, 0, 0}, A1 = {0, 0, 0, 0}, A2 = {0, 0, 0, 0}, A3 = {0, 0, 0, 0};
        for (int c = 0; c < C_; ++c) {
            float4 d = *reinterpret_cast<const float4*>(d2b + (size_t)c * HW_ + j0);
            float4 qv = *reinterpret_cast<const float4*>(&qT[c][0]);
            A0.x = fmaf(qv.x, d.x, A0.x); A0.y = fmaf(qv.x, d.y, A0.y);
            A0.z = fmaf(qv.x, d.z, A0.z); A0.w = fmaf(qv.x, d.w, A0.w);
            A1.x = fmaf(qv.y, d.x, A1.x); A1.y = fmaf(qv.y, d.y, A1.y);
            A1.z = fmaf(qv.y, d.z, A1.z); A1.w = fmaf(qv.y, d.w, A1.w);
            A2.x = fmaf(qv.z, d.x, A2.x); A2.y = fmaf(qv.z, d.y, A2.y);
            A2.z = fmaf(qv.z, d.z, A2.z); A2.w = fmaf(qv.z, d.w, A2.w);
            A3.x = fmaf(qv.w, d.x, A3.x); A3.y = fmaf(qv.w, d.y, A3.y);
            A3.z = fmaf(qv.w, d.z, A3.z); A3.w = fmaf(qv.w, d.w, A3.w);
        }
#pragma unroll
        for (int r = 0; r < R3; ++r) {
            float dots[4];
            dots[0] = (r == 0) ? A0.x : (r == 1) ? A1.x : (r == 2) ? A2.x : A3.x;
            dots[1] = (r == 0) ? A0.y : (r == 1) ? A1.y : (r == 2) ? A2.y : A3.y;
            dots[2] = (r == 0) ? A0.z : (r == 1) ? A1.z : (r == 2) ? A2.z : A3.z;
            dots[3] = (r == 0) ? A0.w : (r == 1) ? A1.w : (r == 2) ? A2.w : A3.w;
#pragma unroll
            for (int cc = 0; cc < 4; ++cc) {
                int j = j0 + cc;
                int cnt = 0;
#pragma unroll
                for (int i = 0; i < 16; ++i) cnt += (ids_s[r][i] == j) ? 1 : 0;
                float v = 2.0f - 2.0f * dots[cc] + 5.0f * (float)cnt;
                if (v < top[r][15]) {
#pragma unroll
                    for (int k = 0; k < 16; ++k) {
                        float o = top[r][k];
                        bool sm = v < o;
                        top[r][k] = sm ? v : o;
                        v = sm ? o : v;
                    }
                }
            }
        }
    }

    __shared__ float mv[T3][17];
#pragma unroll
    for (int r = 0; r < R3; ++r) {
        float a[16];
#pragma unroll
        for (int k = 0; k < 16; ++k) { a[k] = top[r][k]; mv[tid][k] = a[k]; }
        __syncthreads();
        for (int step = T3 / 2; step >= 1; step >>= 1) {
            if (tid < step) {
#pragma unroll
                for (int i = 0; i < 16; ++i)
                    a[i] = fminf(a[i], mv[tid + step][15 - i]);
                bitonic16_asc(a);
#pragma unroll
                for (int i = 0; i < 16; ++i) mv[tid][i] = a[i];
            }
            __syncthreads();
        }
        if (tid == 0) {
            float p = pos[b * N_ + n0 + r];
            float s = 0.0f;
#pragma unroll
            for (int k = 0; k < 16; ++k) {
                float xv = p - a[k] + 1.0f;
                xv = fmaxf(xv, 0.0f);
                s += xv * xv;
            }
            atomicAdd(acc + 0, s);
        }
        __syncthreads();
    }
}

__global__ __launch_bounds__(64) void hqt_k4_sos(
    const float* __restrict__ kp1_desc, const float* __restrict__ w_desc,
    const int* __restrict__ cid4, const int* __restrict__ wcc16,
    const int* __restrict__ wid4, float* __restrict__ acc) {
    int bn = blockIdx.x;
    int b = bn / N_;
    int lane = threadIdx.x;
    __shared__ float qk[C_], qw[C_];
    for (int c = lane; c < C_; c += 64) {
        qk[c] = kp1_desc[(size_t)bn * C_ + c];
        qw[c] = w_desc[(size_t)bn * C_ + c];
    }
    __syncthreads();
    int nk[4];
#pragma unroll
    for (int i = 0; i < 4; ++i) nk[i] = cid4[4 * bn + i];
    int nw[16];
#pragma unroll
    for (int i = 0; i < 16; ++i) nw[i] = wcc16[16 * bn + i];

    float kv[8], wv[8]; int ki[8], wi[8];
#pragma unroll
    for (int k = 0; k < 8; ++k) {
        kv[k] = 1e30f; wv[k] = 1e30f; ki[k] = INT_MAX; wi[k] = INT_MAX;
    }
    const float* kb = kp1_desc + (size_t)b * N_ * C_;
    const float* wb = w_desc + (size_t)b * N_ * C_;
    for (int tt = 0; tt < 8; ++tt) {
        int m = lane * 8 + tt;
        const float* rk = kb + (size_t)m * C_;
        const float* rw = wb + (size_t)m * C_;
        float dk = 0.0f, dw = 0.0f;
        for (int c = 0; c < C_; c += 4) {
            float4 xk = *(const float4*)(rk + c);
            float4 xw = *(const float4*)(rw + c);
            dk += qk[c] * xk.x + qk[c + 1] * xk.y + qk[c + 2] * xk.z + qk[c + 3] * xk.w;
            dw += qw[c] * xw.x + qw[c + 1] * xw.y + qw[c + 2] * xw.z + qw[c + 3] * xw.w;
        }
        int4 mc = *(const int4*)(cid4 + 4 * (b * N_ + m));
        int ck = 0;
#pragma unroll
        for (int i = 0; i < 4; ++i) {
            int u = nk[i];
            ck += (u == mc.x) + (u == mc.y) + (u == mc.z) + (u == mc.w);
        }
        int4 mw = *(const int4*)(wid4 + 4 * (b * N_ + m));
        int cw = 0;
#pragma unroll
        for (int i = 0; i < 16; ++i) {
            int u = nw[i];
            cw += (u == mw.x) + (u == mw.y) + (u == mw.z) + (u == mw.w);
        }
        float vk = 2.0f - 2.0f * dk + 5.0f * (float)ck;
        float vw2 = 2.0f - 2.0f * dw + 5.0f * (float)cw;
        insert8_vi(kv, ki, vk, m);
        insert8_vi(wv, wi, vw2, m);
    }

    __shared__ float mvs[64][9];
    __shared__ int mis[64][9];
    __shared__ int fk[8], fw[8];

#pragma unroll
    for (int i = 0; i < 8; ++i) { mvs[lane][i] = kv[i]; mis[lane][i] = ki[i]; }
    __syncthreads();
    for (int step = 32; step >= 1; step >>= 1) {
        if (lane < step) {
            float bv[8]; int bix[8];
#pragma unroll
            for (int i = 0; i < 8; ++i) {
                bv[i] = mvs[lane + step][7 - i];
                bix[i] = mis[lane + step][7 - i];
            }
#pragma unroll
            for (int i = 0; i < 8; ++i) {
                bool ta = (kv[i] < bv[i]) || (kv[i] == bv[i] && ki[i] < bix[i]);
                kv[i] = ta ? kv[i] : bv[i];
                ki[i] = ta ? ki[i] : bix[i];
            }
            bitonic8_pairs(kv, ki);
#pragma unroll
            for (int i = 0; i < 8; ++i) { mvs[lane][i] = kv[i]; mis[lane][i] = ki[i]; }
        }
        __syncthreads();
    }
    if (lane < 8) fk[lane] = mis[0][lane];
    __syncthreads();

#pragma unroll
    for (int i = 0; i < 8; ++i) { mvs[lane][i] = wv[i]; mis[lane][i] = wi[i]; }
    __syncthreads();
    for (int step = 32; step >= 1; step >>= 1) {
        if (lane < step) {
            float bv[8]; int bix[8];
#pragma unroll
            for (int i = 0; i < 8; ++i) {
                bv[i] = mvs[lane + step][7 - i];
                bix[i] = mis[lane + step][7 - i];
            }
#pragma unroll
            for (int i = 0; i < 8; ++i) {
                bool ta = (wv[i] < bv[i]) || (wv[i] == bv[i] && wi[i] < bix[i]);
                wv[i] = ta ? wv[i] : bv[i];
                wi[i] = ta ? wi[i] : bix[i];
            }
            bitonic8_pairs(wv, wi);
#pragma unroll
            for (int i = 0; i < 8; ++i) { mvs[lane][i] = wv[i]; mis[lane][i] = wi[i]; }
        }
        __syncthreads();
    }
    if (lane < 8) fw[lane] = mis[0][lane];
    __syncthreads();

    int s = lane >> 3, p = lane & 7;
    const float* rk = kb + (size_t)fk[s] * C_;
    const float* rw = wb + (size_t)fw[s] * C_;
    float dk = 0.0f, dw = 0.0f;
    for (int c = p; c < C_; c += 8) {
        dk += qk[c] * rk[c];
        dw += qw[c] * rw[c];
    }
    dk += __shfl_xor(dk, 1); dk += __shfl_xor(dk, 2); dk += __shfl_xor(dk, 4);
    dw += __shfl_xor(dw, 1); dw += __shfl_xor(dw, 2); dw += __shfl_xor(dw, 4);
    __shared__ float tsq[8];
    if (p == 0) {
        float t2 = 2.0f * (dw - dk);
        tsq[s] = t2 * t2;
    }
    __syncthreads();
    if (lane == 0) {
        float s8 = 0.0f;
#pragma unroll
        for (int i = 0; i < 8; ++i) s8 += tsq[i];
        atomicAdd(acc + 1, sqrtf(s8));
    }
}

// ===========================================================================
extern "C" void kernel_launch(void* const* d_in, const int* in_sizes, int n_in,
                              void* d_out, int out_size, void* d_ws, size_t ws_size,
                              hipStream_t stream) {
    const float* kp1      = (const float*)d_in[0];
    const float* w_kp1    = (const float*)d_in[1];
    const float* kp1_desc = (const float*)d_in[2];
    const float* desc2    = (const float*)d_in[3];
    const float* homo     = (const float*)d_in[4];
    float* out = (float*)d_out;

    // ---- workspace layout (new path) ----
    char* p = (char*)d_ws;
    auto alloc = [&](size_t bytes) {
        char* r = p;
        p += (bytes + 255) & ~(size_t)255;
        return r;
    };
    float*          pos    = (float*)alloc((size_t)B_ * N_ * 4);
    int*            cid4   = (int*)alloc((size_t)B_ * N_ * 4 * 4);
    int*            wid4   = (int*)alloc((size_t)B_ * N_ * 4 * 4);
    int*            wcc16  = (int*)alloc((size_t)B_ * N_ * 16 * 4);
    unsigned int*   marked = (unsigned int*)alloc((size_t)B_ * N_ * 16 * 4);
    float*          acc    = (float*)alloc(64);
    unsigned short* q_bf   = (unsigned short*)alloc((size_t)B_ * N_ * C_ * 2);
    unsigned short* w_bf   = (unsigned short*)alloc((size_t)B_ * N_ * C_ * 2);
    unsigned short* d2t    = (unsigned short*)alloc((size_t)B_ * HW_ * C_ * 2);
    float*          rowmax = (float*)alloc((size_t)B_ * N_ * 128 * 4);
    float*          t32    = (float*)alloc((size_t)B_ * N_ * 4);
    int*            scnt   = (int*)alloc((size_t)B_ * N_ * 4);
    float2*         sbuf   = (float2*)alloc((size_t)B_ * N_ * SCAP_ * 8);
    size_t need = (size_t)(p - (char*)d_ws);
    // psim overlays d2t (8 MB region, psim needs 4 MB; d2t is dead after k3d)
    float* psim = (float*)d2t;

    if (ws_size >= need) {
        hqt_k0<<<1157, 256, 0, stream>>>(desc2, kp1_desc, kp1, w_kp1, homo,
                                         d2t, q_bf, cid4, wcc16, wid4, marked,
                                         scnt, acc);
        hqt_k2_sample<<<B_ * N_, 128, 0, stream>>>(w_kp1, desc2, kp1_desc,
                                                   w_bf, pos);
        hqt_k3a<<<256, 512, 0, stream>>>(q_bf, d2t, rowmax);
        hqt_k3b<<<256, 256, 0, stream>>>(rowmax, t32);
        hqt_k3c<<<256, 512, 0, stream>>>(q_bf, d2t, t32, scnt, sbuf);
        hqt_k3d<<<256, 256, 0, stream>>>(q_bf, d2t, marked, scnt, sbuf, pos, acc);
        hqt_k4a<<<128, 256, 0, stream>>>(q_bf, w_bf, cid4, wid4, wcc16, psim);
        hqt_k4b<<<256, 256, 0, stream>>>(psim, cid4, wid4, wcc16, acc);
        hqt_k5_final<<<1, 1, 0, stream>>>(acc, out);
    } else {
        // fallback: round-1 layout and path
        float* w_desc0 = (float*)d_ws;
        float* pos0    = w_desc0 + (size_t)B_ * N_ * C_;
        int*   cid40   = (int*)(pos0 + B_ * N_);
        int*   wid40   = cid40 + B_ * N_ * 4;
        int*   wcc160  = wid40 + B_ * N_ * 4;
        float* acc0    = (float*)(wcc160 + B_ * N_ * 16);
        hipMemsetAsync(acc0, 0, 2 * sizeof(float), stream);
        hqt_k1_cells<<<(B_ * N_ + 255) / 256, 256, 0, stream>>>(
            kp1, w_kp1, homo, cid40, wcc160, wid40);
        hqt_k2_sample_f32<<<B_ * N_, 128, 0, stream>>>(w_kp1, desc2, kp1_desc,
                                                       w_desc0, pos0);
        hqt_k3_dsim<<<B_ * (N_ / R3), T3, 0, stream>>>(desc2, kp1_desc, wcc160,
                                                       pos0, acc0);
        hqt_k4_sos<<<B_ * N_, 64, 0, stream>>>(kp1_desc, w_desc0, cid40,
                                               wcc160, wid40, acc0);
        hqt_k5_final<<<1, 1, 0, stream>>>(acc0, out);
    }
}

// Round 6
// 135.023 us; speedup vs baseline: 2.0500x; 1.2402x over previous
//
#include <hip/hip_runtime.h>
#include <climits>

#define B_ 2
#define N_ 512
#define C_ 128
#define H_ 128
#define W_ 128
#define HW_ (H_ * W_)
#define NUM_NEG_ 16
#define SOS_NEG_ 8
#define SCAP_ 128   // survivor cap per row

typedef __attribute__((ext_vector_type(8))) short short8;
typedef __attribute__((ext_vector_type(4))) float f32x4;

__device__ inline unsigned int f2bf(float x) {
    unsigned int u = __float_as_uint(x);
    return (u + 0x7FFFu + ((u >> 16) & 1u)) >> 16;
}
__device__ inline float bf2f(unsigned int h) {
    return __uint_as_float(h << 16);
}

// ---------------------------------------------------------------------------
// 4 nearest grid-cell centers of point (y,x); tie-break matches lax.top_k.
// ---------------------------------------------------------------------------
__device__ inline void nearest4(float y, float x, int out[4]) {
    y = fminf(fmaxf(y, -1e6f), 1e6f);
    x = fminf(fmaxf(x, -1e6f), 1e6f);
    int fy = (int)floorf(y * 0.125f - 0.5f);
    int fx = (int)floorf(x * 0.125f - 0.5f);
    int ylo = fy - 1; if (ylo < 0) ylo = 0; if (ylo > H_ - 4) ylo = H_ - 4;
    int xlo = fx - 1; if (xlo < 0) xlo = 0; if (xlo > W_ - 4) xlo = W_ - 4;
    float bd[4] = {1e30f, 1e30f, 1e30f, 1e30f};
    int   bi[4] = {INT_MAX, INT_MAX, INT_MAX, INT_MAX};
#pragma unroll
    for (int dyi = 0; dyi < 4; ++dyi) {
        int yi = ylo + dyi;
        float dy = y - (8.0f * yi + 4.0f);
        float dy2 = dy * dy;
#pragma unroll
        for (int dxi = 0; dxi < 4; ++dxi) {
            int xi = xlo + dxi;
            float dx = x - (8.0f * xi + 4.0f);
            float d = dy2 + dx * dx;
            int id = yi * W_ + xi;
#pragma unroll
            for (int k = 0; k < 4; ++k) {
                bool sm = (d < bd[k]) || (d == bd[k] && id < bi[k]);
                float od = bd[k]; int oi = bi[k];
                bd[k] = sm ? d : od;  bi[k] = sm ? id : oi;
                d = sm ? od : d;      id = sm ? oi : id;
            }
        }
    }
    out[0] = bi[0]; out[1] = bi[1]; out[2] = bi[2]; out[3] = bi[3];
}

__device__ inline void k1_body(int t, const float* kp1, const float* w_kp1,
                               const float* homo, int* cid4, int* wcc16,
                               int* wid4, unsigned int* marked) {
    int b = t / N_;
    float ky = kp1[2 * t], kx = kp1[2 * t + 1];
    int ids[4];
    nearest4(ky, kx, ids);
    const float* Hb = homo + 9 * b;
    float h00 = Hb[0], h01 = Hb[1], h02 = Hb[2];
    float h10 = Hb[3], h11 = Hb[4], h12 = Hb[5];
    float h20 = Hb[6], h21 = Hb[7], h22 = Hb[8];
    int w16[16];
#pragma unroll
    for (int i = 0; i < 4; ++i) {
        int id = ids[i];
        cid4[4 * t + i] = id;
        float cy = 8.0f * (id >> 7) + 4.0f;
        float cx = 8.0f * (id & 127) + 4.0f;
        float X = cx, Y = cy;
        float wz = h20 * X + h21 * Y + h22;
        float inv = 1.0f / (wz + 1e-8f);
        float wy = (h10 * X + h11 * Y + h12) * inv;
        float wx = (h00 * X + h01 * Y + h02) * inv;
        int wids[4];
        nearest4(wy, wx, wids);
#pragma unroll
        for (int j = 0; j < 4; ++j) {
            w16[4 * i + j] = wids[j];
            wcc16[16 * t + 4 * i + j] = wids[j];
        }
    }
#pragma unroll
    for (int i = 0; i < 16; ++i) {
        int cnt = 0; bool first = true;
#pragma unroll
        for (int j = 0; j < 16; ++j) {
            bool eq = (w16[j] == w16[i]);
            cnt += eq ? 1 : 0;
            if (j < i && eq) first = false;
        }
        marked[16 * t + i] = first ? ((unsigned int)w16[i] | ((unsigned int)cnt << 16))
                                   : 0xFFFFFFFFu;
    }
    float zy = w_kp1[2 * t], zx = w_kp1[2 * t + 1];
    int wi4[4];
    nearest4(zy, zx, wi4);
#pragma unroll
    for (int j = 0; j < 4; ++j) wid4[4 * t + j] = wi4[j];
}

// ---------------------------------------------------------------------------
// KA fused: [0,1024) d2t transpose; [1024,1152) q_bf; 1152 zero scnt/acc/ticket;
// [1153,1157) k1; [1157,1413) k2 (wave-per-keypoint, shfl-only).
// ---------------------------------------------------------------------------
__global__ __launch_bounds__(256) void hqt_ka(
    const float* __restrict__ desc2, const float* __restrict__ kp1_desc,
    const float* __restrict__ kp1, const float* __restrict__ w_kp1,
    const float* __restrict__ homo,
    unsigned short* __restrict__ d2t, unsigned short* __restrict__ q_bf,
    unsigned short* __restrict__ w_bf, float* __restrict__ pos,
    int* __restrict__ cid4, int* __restrict__ wcc16, int* __restrict__ wid4,
    unsigned int* __restrict__ marked, int* __restrict__ scnt,
    float* __restrict__ acc) {
    int blk = blockIdx.x;
    int tid = threadIdx.x;
    if (blk < 1024) {
        __shared__ float tile[32][129];
        int b = blk >> 9;
        int j0 = (blk & 511) * 32;
        int jj = tid & 31, cg = tid >> 5;
        const float* src = desc2 + (size_t)b * C_ * HW_;
#pragma unroll
        for (int cc = 0; cc < 16; ++cc) {
            int c = cg * 16 + cc;
            tile[jj][c] = src[(size_t)c * HW_ + j0 + jj];
        }
        __syncthreads();
        int row = tid >> 3, c8 = (tid & 7) * 16;
        unsigned int tmp[16];
#pragma unroll
        for (int k = 0; k < 16; ++k) tmp[k] = f2bf(tile[row][c8 + k]);
        uint4 o0, o1;
        o0.x = tmp[0] | (tmp[1] << 16);  o0.y = tmp[2] | (tmp[3] << 16);
        o0.z = tmp[4] | (tmp[5] << 16);  o0.w = tmp[6] | (tmp[7] << 16);
        o1.x = tmp[8] | (tmp[9] << 16);  o1.y = tmp[10] | (tmp[11] << 16);
        o1.z = tmp[12] | (tmp[13] << 16); o1.w = tmp[14] | (tmp[15] << 16);
        unsigned short* dst = d2t + ((size_t)(b << 14) + j0 + row) * C_ + c8;
        ((uint4*)dst)[0] = o0;
        ((uint4*)dst)[1] = o1;
    } else if (blk < 1152) {
        int idx = (blk - 1024) * 256 + tid;
        float4 v = *(const float4*)(kp1_desc + (size_t)idx * 4);
        uint2 u;
        u.x = f2bf(v.x) | (f2bf(v.y) << 16);
        u.y = f2bf(v.z) | (f2bf(v.w) << 16);
        *(uint2*)(q_bf + (size_t)idx * 4) = u;
    } else if (blk == 1152) {
        ((int4*)scnt)[tid] = make_int4(0, 0, 0, 0);
        if (tid == 0) { acc[0] = 0.0f; acc[1] = 0.0f; acc[2] = 0.0f; acc[3] = 0.0f; }
    } else if (blk < 1157) {
        int t = (blk - 1153) * 256 + tid;
        if (t < B_ * N_)
            k1_body(t, kp1, w_kp1, homo, cid4, wcc16, wid4, marked);
    } else {
        // k2: wave-per-keypoint bilinear sample + normalize + pos
        int w = tid >> 6, l = tid & 63;
        int bn = (blk - 1157) * 4 + w;
        int b = bn / N_;
        float ky = w_kp1[2 * bn], kx = w_kp1[2 * bn + 1];
        float y = fminf(fmaxf(ky * 0.125f - 0.5f, 0.0f), (float)(H_ - 1));
        float x = fminf(fmaxf(kx * 0.125f - 0.5f, 0.0f), (float)(W_ - 1));
        int y0 = (int)floorf(y); if (y0 > H_ - 2) y0 = H_ - 2;
        int x0 = (int)floorf(x); if (x0 > W_ - 2) x0 = W_ - 2;
        float wy = y - (float)y0, wx = x - (float)x0;
        int i00 = y0 * W_ + x0;
        float w00 = (1.0f - wy) * (1.0f - wx), w01 = (1.0f - wy) * wx;
        float w10 = wy * (1.0f - wx),          w11 = wy * wx;
        const float* dB0 = desc2 + ((size_t)b * C_ + l) * HW_;
        const float* dB1 = desc2 + ((size_t)b * C_ + l + 64) * HW_;
        float v0 = dB0[i00] * w00 + dB0[i00 + 1] * w01
                 + dB0[i00 + W_] * w10 + dB0[i00 + W_ + 1] * w11;
        float v1 = dB1[i00] * w00 + dB1[i00 + 1] * w01
                 + dB1[i00 + W_] * w10 + dB1[i00 + W_ + 1] * w11;
        float s = v0 * v0 + v1 * v1;
        s += __shfl_xor(s, 1);  s += __shfl_xor(s, 2);  s += __shfl_xor(s, 4);
        s += __shfl_xor(s, 8);  s += __shfl_xor(s, 16); s += __shfl_xor(s, 32);
        float inv = 1.0f / (sqrtf(s) + 1e-8f);
        float vn0 = v0 * inv, vn1 = v1 * inv;
        w_bf[(size_t)bn * C_ + l]      = (unsigned short)f2bf(vn0);
        w_bf[(size_t)bn * C_ + 64 + l] = (unsigned short)f2bf(vn1);
        float qd0 = kp1_desc[(size_t)bn * C_ + l];
        float qd1 = kp1_desc[(size_t)bn * C_ + 64 + l];
        float d = qd0 * vn0 + qd1 * vn1;
        d += __shfl_xor(d, 1);  d += __shfl_xor(d, 2);  d += __shfl_xor(d, 4);
        d += __shfl_xor(d, 8);  d += __shfl_xor(d, 16); d += __shfl_xor(d, 32);
        if (l == 0) pos[bn] = 2.0f - 2.0f * d;
    }
}

// ---------------------------------------------------------------------------
// KB fused: [0,256) k3a rowmax pass; [256,384) k4a psim pass (512 thr).
// ---------------------------------------------------------------------------
__global__ __launch_bounds__(512) void hqt_kb(
    const unsigned short* __restrict__ q_bf,
    const unsigned short* __restrict__ w_bf,
    const unsigned short* __restrict__ d2t,
    const int* __restrict__ cid4, const int* __restrict__ wid4,
    const int* __restrict__ wcc16,
    float* __restrict__ rowmax, float* __restrict__ psim) {
    int blk = blockIdx.x;
    int tid = threadIdx.x, w = tid >> 6, l = tid & 63;
    int l15 = l & 15, lg = l >> 4;
    if (blk < 256) {
        // ---- k3a: rowmax over 128-col windows ----
        int b = blk >> 7;
        int rg = (blk >> 4) & 7;
        int cb = blk & 15;
        int rowbase = rg * 64;
        int colbase = cb * 1024 + w * 128;
        const unsigned short* qb = q_bf + (size_t)b * N_ * C_;
        const unsigned short* db = d2t + (size_t)b * HW_ * C_;
        short8 a[4][4];
#pragma unroll
        for (int rt = 0; rt < 4; ++rt)
#pragma unroll
            for (int ks = 0; ks < 4; ++ks)
                a[rt][ks] = *(const short8*)(qb + (size_t)(rowbase + rt * 16 + l15) * C_ + ks * 32 + lg * 8);
        f32x4 mx[4];
#pragma unroll
        for (int rt = 0; rt < 4; ++rt) mx[rt] = f32x4{-1e30f, -1e30f, -1e30f, -1e30f};
#pragma unroll
        for (int t = 0; t < 8; ++t) {
            const unsigned short* dp = db + (size_t)(colbase + t * 16 + l15) * C_ + lg * 8;
            short8 b0 = *(const short8*)(dp);
            short8 b1 = *(const short8*)(dp + 32);
            short8 b2 = *(const short8*)(dp + 64);
            short8 b3 = *(const short8*)(dp + 96);
#pragma unroll
            for (int rt = 0; rt < 4; ++rt) {
                f32x4 acc4 = {0.0f, 0.0f, 0.0f, 0.0f};
                acc4 = __builtin_amdgcn_mfma_f32_16x16x32_bf16(a[rt][0], b0, acc4, 0, 0, 0);
                acc4 = __builtin_amdgcn_mfma_f32_16x16x32_bf16(a[rt][1], b1, acc4, 0, 0, 0);
                acc4 = __builtin_amdgcn_mfma_f32_16x16x32_bf16(a[rt][2], b2, acc4, 0, 0, 0);
                acc4 = __builtin_amdgcn_mfma_f32_16x16x32_bf16(a[rt][3], b3, acc4, 0, 0, 0);
#pragma unroll
                for (int r = 0; r < 4; ++r) mx[rt][r] = fmaxf(mx[rt][r], acc4[r]);
            }
        }
#pragma unroll
        for (int rt = 0; rt < 4; ++rt)
#pragma unroll
            for (int r = 0; r < 4; ++r) {
                float v = mx[rt][r];
                v = fmaxf(v, __shfl_xor(v, 1));
                v = fmaxf(v, __shfl_xor(v, 2));
                v = fmaxf(v, __shfl_xor(v, 4));
                v = fmaxf(v, __shfl_xor(v, 8));
                mx[rt][r] = v;
            }
        if (l15 == 0) {
            int chunk = cb * 8 + w;
#pragma unroll
            for (int rt = 0; rt < 4; ++rt)
#pragma unroll
                for (int r = 0; r < 4; ++r) {
                    int rowg = b * N_ + rowbase + rt * 16 + lg * 4 + r;
                    rowmax[(size_t)rowg * 128 + chunk] = mx[rt][r];
                }
        }
    } else {
        // ---- k4a: eager-penalty sim key matrices (8 waves x 64 cols) ----
        int blk2 = blk - 256;
        int mat = blk2 >> 6;
        int b = (blk2 >> 5) & 1;
        int r0 = (blk2 & 31) * 16;
        const unsigned short* src = (mat ? w_bf : q_bf) + (size_t)b * N_ * C_;

        __shared__ int s_colids[N_][4];
        __shared__ int s_rowcc[16][16];
        {
            const int4* gsrc = (const int4*)((mat ? wid4 : cid4) + b * N_ * 4);
            ((int4*)s_colids)[tid] = gsrc[tid];
            if (tid < 256)
                ((int*)s_rowcc)[tid] = wcc16[(b * N_ + r0) * 16 + tid];
        }
        short8 a0 = *(const short8*)(src + (size_t)(r0 + l15) * C_ + lg * 8);
        short8 a1 = *(const short8*)(src + (size_t)(r0 + l15) * C_ + 32 + lg * 8);
        short8 a2 = *(const short8*)(src + (size_t)(r0 + l15) * C_ + 64 + lg * 8);
        short8 a3 = *(const short8*)(src + (size_t)(r0 + l15) * C_ + 96 + lg * 8);
        __syncthreads();

        int4 rowc[4];
        int rcc[4][16];
#pragma unroll
        for (int r = 0; r < 4; ++r) {
            rowc[r] = *(const int4*)(&s_colids[r0 + lg * 4 + r][0]);
            if (mat == 1) {
#pragma unroll
                for (int i = 0; i < 16; ++i) rcc[r][i] = s_rowcc[lg * 4 + r][i];
            }
        }

        float* prow = psim + ((size_t)(mat * B_ + b) * N_) * N_;
#pragma unroll
        for (int t = 0; t < 4; ++t) {
            int col0 = w * 64 + t * 16;
            const unsigned short* dp = src + (size_t)(col0 + l15) * C_ + lg * 8;
            short8 b0 = *(const short8*)(dp);
            short8 b1 = *(const short8*)(dp + 32);
            short8 b2 = *(const short8*)(dp + 64);
            short8 b3 = *(const short8*)(dp + 96);
            f32x4 acc4 = {0.0f, 0.0f, 0.0f, 0.0f};
            acc4 = __builtin_amdgcn_mfma_f32_16x16x32_bf16(a0, b0, acc4, 0, 0, 0);
            acc4 = __builtin_amdgcn_mfma_f32_16x16x32_bf16(a1, b1, acc4, 0, 0, 0);
            acc4 = __builtin_amdgcn_mfma_f32_16x16x32_bf16(a2, b2, acc4, 0, 0, 0);
            acc4 = __builtin_amdgcn_mfma_f32_16x16x32_bf16(a3, b3, acc4, 0, 0, 0);
            int mycol = col0 + l15;
            int4 cc = *(const int4*)(&s_colids[mycol][0]);
#pragma unroll
            for (int r = 0; r < 4; ++r) {
                int cnt = 0;
                if (mat == 0) {
#pragma unroll
                    for (int j = 0; j < 4; ++j) {
                        int u = (j == 0) ? rowc[r].x : (j == 1) ? rowc[r].y
                              : (j == 2) ? rowc[r].z : rowc[r].w;
                        cnt += (u == cc.x) + (u == cc.y) + (u == cc.z) + (u == cc.w);
                    }
                } else {
#pragma unroll
                    for (int i = 0; i < 16; ++i) {
                        int u = rcc[r][i];
                        cnt += (u == cc.x) + (u == cc.y) + (u == cc.z) + (u == cc.w);
                    }
                }
                float key = acc4[r] - 2.5f * (float)cnt;
                prow[(size_t)(r0 + lg * 4 + r) * N_ + mycol] = key;
            }
        }
    }
}

// ---------------------------------------------------------------------------
// K3b: per row, t = 32nd-largest of 128 window maxes.
// ---------------------------------------------------------------------------
__global__ __launch_bounds__(256) void hqt_k3b(
    const float* __restrict__ rowmax, float* __restrict__ t32) {
    int w = threadIdx.x >> 6, l = threadIdx.x & 63;
    int row = blockIdx.x * 4 + w;
    const float* rm = rowmax + (size_t)row * 128;
    float v = fmaxf(rm[l], rm[64 + l]);
    float t = -1e30f;
#pragma unroll 1
    for (int it = 0; it < 32; ++it) {
        float m = v;
        m = fmaxf(m, __shfl_xor(m, 1));
        m = fmaxf(m, __shfl_xor(m, 2));
        m = fmaxf(m, __shfl_xor(m, 4));
        m = fmaxf(m, __shfl_xor(m, 8));
        m = fmaxf(m, __shfl_xor(m, 16));
        m = fmaxf(m, __shfl_xor(m, 32));
        v = (v == m) ? -1e30f : v;
        t = m;
    }
    if (l == 0) t32[row] = t;
}

// ---------------------------------------------------------------------------
// KC (= k3c): MFMA pass 2: push (dot, col) with dot >= t[row] into sbuf.
// ---------------------------------------------------------------------------
__global__ __launch_bounds__(512) void hqt_kc(
    const unsigned short* __restrict__ q_bf,
    const unsigned short* __restrict__ d2t,
    const float* __restrict__ t32,
    int* __restrict__ scnt, float2* __restrict__ sbuf) {
    int blk = blockIdx.x;
    int b = blk >> 7;
    int rg = (blk >> 4) & 7;
    int cb = blk & 15;
    int tid = threadIdx.x, w = tid >> 6, l = tid & 63;
    int l15 = l & 15, lg = l >> 4;
    int rowbase = rg * 64;
    int colbase = cb * 1024 + w * 128;
    const unsigned short* qb = q_bf + (size_t)b * N_ * C_;
    const unsigned short* db = d2t + (size_t)b * HW_ * C_;
    short8 a[4][4];
#pragma unroll
    for (int rt = 0; rt < 4; ++rt)
#pragma unroll
        for (int ks = 0; ks < 4; ++ks)
            a[rt][ks] = *(const short8*)(qb + (size_t)(rowbase + rt * 16 + l15) * C_ + ks * 32 + lg * 8);
    float tl[4][4];
#pragma unroll
    for (int rt = 0; rt < 4; ++rt)
#pragma unroll
        for (int r = 0; r < 4; ++r)
            tl[rt][r] = t32[b * N_ + rowbase + rt * 16 + lg * 4 + r];
#pragma unroll
    for (int t = 0; t < 8; ++t) {
        const unsigned short* dp = db + (size_t)(colbase + t * 16 + l15) * C_ + lg * 8;
        short8 b0 = *(const short8*)(dp);
        short8 b1 = *(const short8*)(dp + 32);
        short8 b2 = *(const short8*)(dp + 64);
        short8 b3 = *(const short8*)(dp + 96);
#pragma unroll
        for (int rt = 0; rt < 4; ++rt) {
            f32x4 acc4 = {0.0f, 0.0f, 0.0f, 0.0f};
            acc4 = __builtin_amdgcn_mfma_f32_16x16x32_bf16(a[rt][0], b0, acc4, 0, 0, 0);
            acc4 = __builtin_amdgcn_mfma_f32_16x16x32_bf16(a[rt][1], b1, acc4, 0, 0, 0);
            acc4 = __builtin_amdgcn_mfma_f32_16x16x32_bf16(a[rt][2], b2, acc4, 0, 0, 0);
            acc4 = __builtin_amdgcn_mfma_f32_16x16x32_bf16(a[rt][3], b3, acc4, 0, 0, 0);
#pragma unroll
            for (int r = 0; r < 4; ++r) {
                float d = acc4[r];
                if (d >= tl[rt][r]) {
                    int rowg = b * N_ + rowbase + rt * 16 + lg * 4 + r;
                    int idx = atomicAdd(scnt + rowg, 1);
                    if (idx < SCAP_) {
                        float2 e;
                        e.x = d;
                        e.y = __int_as_float(colbase + t * 16 + l15);
                        sbuf[(size_t)rowg * SCAP_ + idx] = e;
                    }
                }
            }
        }
    }
}

// ---------------------------------------------------------------------------
// selection helpers
// ---------------------------------------------------------------------------
__device__ inline void insert8_vi(float (&av)[8], int (&ai)[8], float v, int id) {
    bool le = (v < av[7]) || (v == av[7] && id < ai[7]);
    if (!le) return;
#pragma unroll
    for (int k = 0; k < 8; ++k) {
        float ov = av[k]; int oi = ai[k];
        bool sm = (v < ov) || (v == ov && id < oi);
        av[k] = sm ? v : ov;  ai[k] = sm ? id : oi;
        v = sm ? ov : v;      id = sm ? oi : id;
    }
}

__device__ inline void bitonic8_pairs(float (&av)[8], int (&ai)[8]) {
#pragma unroll
    for (int dd = 0; dd < 3; ++dd) {
        const int d = 4 >> dd;
#pragma unroll
        for (int i = 0; i < 8; ++i) {
            if ((i & d) == 0) {
                bool sw = (av[i + d] < av[i]) ||
                          (av[i + d] == av[i] && ai[i + d] < ai[i]);
                float tv = av[i]; int ti = ai[i];
                av[i]     = sw ? av[i + d] : av[i];
                ai[i]     = sw ? ai[i + d] : ai[i];
                av[i + d] = sw ? tv : av[i + d];
                ai[i + d] = sw ? ti : ai[i + d];
            }
        }
    }
}

__device__ inline void wave_merge8(float (&av)[8], int (&ai)[8], int l) {
#pragma unroll
    for (int step = 32; step >= 1; step >>= 1) {
        float bv[8]; int bi2[8];
#pragma unroll
        for (int i = 0; i < 8; ++i) {
            bv[i]  = __shfl(av[7 - i], (l + step) & 63);
            bi2[i] = __shfl(ai[7 - i], (l + step) & 63);
        }
        bool upd = l < step;
#pragma unroll
        for (int i = 0; i < 8; ++i) {
            bool sm = (bv[i] < av[i]) || (bv[i] == av[i] && bi2[i] < ai[i]);
            if (upd && sm) { av[i] = bv[i]; ai[i] = bi2[i]; }
        }
        bitonic8_pairs(av, ai);
    }
}

// ---------------------------------------------------------------------------
// KD fused: [0,256) k3d (fos); [256,512) k4b (sos); atomic-ticket finalize.
// ---------------------------------------------------------------------------
__global__ __launch_bounds__(256) void hqt_kd(
    const unsigned short* __restrict__ q_bf,
    const unsigned short* __restrict__ d2t,
    const unsigned int* __restrict__ marked,
    const int* __restrict__ scnt, const float2* __restrict__ sbuf,
    const float* __restrict__ pos, const float* __restrict__ psim,
    const int* __restrict__ cid4, const int* __restrict__ wid4,
    const int* __restrict__ wcc16, float* __restrict__ acc,
    float* __restrict__ out) {
    int blk = blockIdx.x;
    int w = threadIdx.x >> 6, l = threadIdx.x & 63;
    if (blk < 256) {
        // ---- k3d: exact penalized top-16 -> fos partial ----
        int row = blk * 4 + w;
        int b = row >> 9;
        int sc = scnt[row]; if (sc > SCAP_) sc = SCAP_;
        float k0 = -1e30f, k1 = -1e30f, k2c = -1e30f;
        int c0 = -1, c1 = -1;
        if (l < sc) {
            float2 e = sbuf[(size_t)row * SCAP_ + l];
            k0 = e.x; c0 = __float_as_int(e.y);
        }
        if (64 + l < sc) {
            float2 e = sbuf[(size_t)row * SCAP_ + 64 + l];
            k1 = e.x; c1 = __float_as_int(e.y);
        }
#pragma unroll
        for (int i = 0; i < 16; ++i) {
            unsigned int mv = marked[row * 16 + i];
            int id = (int)(mv & 0xFFFFu);
            if (c0 == id) k0 = -1e30f;
            if (c1 == id) k1 = -1e30f;
        }
        {
            int mi = l >> 2, cq = l & 3;
            unsigned int mv = marked[row * 16 + mi];
            bool valid = (mv != 0xFFFFFFFFu);
            int col = valid ? (int)(mv & 0xFFFFu) : 0;
            int cnt = (int)(mv >> 16);
            const unsigned short* qp = q_bf + (size_t)row * C_ + cq * 32;
            const unsigned short* dp = d2t + ((size_t)b * HW_ + col) * C_ + cq * 32;
            float dot = 0.0f;
#pragma unroll
            for (int u = 0; u < 4; ++u) {
                short8 qv = *(const short8*)(qp + u * 8);
                short8 dv = *(const short8*)(dp + u * 8);
#pragma unroll
                for (int e = 0; e < 8; ++e)
                    dot = fmaf(bf2f((unsigned short)qv[e]), bf2f((unsigned short)dv[e]), dot);
            }
            dot += __shfl_xor(dot, 1);
            dot += __shfl_xor(dot, 2);
            k2c = (valid && cq == 0) ? (dot - 2.5f * (float)cnt) : -1e30f;
        }
        float pos_r = pos[row];
        float sum = 0.0f;
#pragma unroll 1
        for (int it = 0; it < 16; ++it) {
            float v = fmaxf(k0, fmaxf(k1, k2c));
            float m = v;
            m = fmaxf(m, __shfl_xor(m, 1));
            m = fmaxf(m, __shfl_xor(m, 2));
            m = fmaxf(m, __shfl_xor(m, 4));
            m = fmaxf(m, __shfl_xor(m, 8));
            m = fmaxf(m, __shfl_xor(m, 16));
            m = fmaxf(m, __shfl_xor(m, 32));
            unsigned long long b0 = __ballot(k0 == m);
            if (b0) {
                if (l == __ffsll(b0) - 1) k0 = -1e30f;
            } else {
                unsigned long long b1 = __ballot(k1 == m);
                if (b1) {
                    if (l == __ffsll(b1) - 1) k1 = -1e30f;
                } else {
                    unsigned long long b2 = __ballot(k2c == m);
                    if (l == __ffsll(b2) - 1) k2c = -1e30f;
                }
            }
            float h = pos_r + 2.0f * m - 1.0f;
            h = fmaxf(h, 0.0f);
            sum += h * h;
        }
        if (l == 0) atomicAdd(acc + 0, sum);
    } else {
        // ---- k4b: top-8 of psim rows + sos ----
        int rowg = (blk - 256) * 4 + w;
        int b = rowg >> 9;
        int row = rowg & 511;

        __shared__ float s_kv[4][8], s_wv[4][8];
        __shared__ int   s_ki[4][8], s_wi[4][8];

        float kv[8]; int ki[8];
#pragma unroll
        for (int i = 0; i < 8; ++i) { kv[i] = 1e30f; ki[i] = INT_MAX; }
        {
            const float* pk = psim + ((size_t)(0 * B_ + b) * N_ + row) * N_;
            float4 u0 = ((const float4*)pk)[l * 2];
            float4 u1 = ((const float4*)pk)[l * 2 + 1];
            insert8_vi(kv, ki, -u0.x, l * 8 + 0);
            insert8_vi(kv, ki, -u0.y, l * 8 + 1);
            insert8_vi(kv, ki, -u0.z, l * 8 + 2);
            insert8_vi(kv, ki, -u0.w, l * 8 + 3);
            insert8_vi(kv, ki, -u1.x, l * 8 + 4);
            insert8_vi(kv, ki, -u1.y, l * 8 + 5);
            insert8_vi(kv, ki, -u1.z, l * 8 + 6);
            insert8_vi(kv, ki, -u1.w, l * 8 + 7);
        }
        wave_merge8(kv, ki, l);
        if (l == 0) {
#pragma unroll
            for (int i = 0; i < 8; ++i) { s_kv[w][i] = -kv[i]; s_ki[w][i] = ki[i]; }
        }

        float wv[8]; int wi[8];
#pragma unroll
        for (int i = 0; i < 8; ++i) { wv[i] = 1e30f; wi[i] = INT_MAX; }
        {
            const float* pw = psim + ((size_t)(1 * B_ + b) * N_ + row) * N_;
            float4 u0 = ((const float4*)pw)[l * 2];
            float4 u1 = ((const float4*)pw)[l * 2 + 1];
            insert8_vi(wv, wi, -u0.x, l * 8 + 0);
            insert8_vi(wv, wi, -u0.y, l * 8 + 1);
            insert8_vi(wv, wi, -u0.z, l * 8 + 2);
            insert8_vi(wv, wi, -u0.w, l * 8 + 3);
            insert8_vi(wv, wi, -u1.x, l * 8 + 4);
            insert8_vi(wv, wi, -u1.y, l * 8 + 5);
            insert8_vi(wv, wi, -u1.z, l * 8 + 6);
            insert8_vi(wv, wi, -u1.w, l * 8 + 7);
        }
        wave_merge8(wv, wi, l);
        if (l == 0) {
#pragma unroll
            for (int i = 0; i < 8; ++i) { s_wv[w][i] = -wv[i]; s_wi[w][i] = wi[i]; }
        }

        if (l < 8) {
            int kidx = s_ki[w][l]; float kkey = s_kv[w][l];
            int widx = s_wi[w][l]; float wkey = s_wv[w][l];
            const int4* cb  = (const int4*)(cid4 + b * N_ * 4);
            const int4* wb4 = (const int4*)(wid4 + b * N_ * 4);
            int4 rc = cb[row];
            int4 mc = cb[kidx];
            int cntK = 0;
#pragma unroll
            for (int j = 0; j < 4; ++j) {
                int u = (j == 0) ? rc.x : (j == 1) ? rc.y : (j == 2) ? rc.z : rc.w;
                cntK += (u == mc.x) + (u == mc.y) + (u == mc.z) + (u == mc.w);
            }
            int4 mw = wb4[widx];
            int cntW = 0;
            const int4* rcc = (const int4*)(wcc16 + (b * N_ + row) * 16);
#pragma unroll
            for (int uq = 0; uq < 4; ++uq) {
                int4 rr = rcc[uq];
                cntW += (rr.x == mw.x) + (rr.x == mw.y) + (rr.x == mw.z) + (rr.x == mw.w);
                cntW += (rr.y == mw.x) + (rr.y == mw.y) + (rr.y == mw.z) + (rr.y == mw.w);
                cntW += (rr.z == mw.x) + (rr.z == mw.y) + (rr.z == mw.z) + (rr.z == mw.w);
                cntW += (rr.w == mw.x) + (rr.w == mw.y) + (rr.w == mw.z) + (rr.w == mw.w);
            }
            float dotK = kkey + 2.5f * (float)cntK;
            float dotW = wkey + 2.5f * (float)cntW;
            float t2 = 2.0f * (dotW - dotK);
            float sq = t2 * t2;
            sq += __shfl_xor(sq, 1);
            sq += __shfl_xor(sq, 2);
            sq += __shfl_xor(sq, 4);
            if (l == 0) atomicAdd(acc + 1, sqrtf(sq));
        }
    }
    // ---- ticket finalize (all 512 blocks) ----
    __syncthreads();
    if (threadIdx.x == 0) {
        __threadfence();
        unsigned int t = atomicAdd((unsigned int*)(acc + 2), 1u);
        if (t == 511u) {
            float a0 = atomicAdd(acc + 0, 0.0f);
            float a1 = atomicAdd(acc + 1, 0.0f);
            out[0] = a0 * (1.0f / (float)(B_ * N_ * NUM_NEG_))
                   + a1 * (1.0f / (float)(B_ * N_));
        }
    }
}

// ======================= fallback (round-1) kernels ========================
__global__ void hqt_k1_cells(const float* __restrict__ kp1,
                             const float* __restrict__ w_kp1,
                             const float* __restrict__ homo,
                             int* __restrict__ cid4,
                             int* __restrict__ wcc16,
                             int* __restrict__ wid4) {
    int t = blockIdx.x * blockDim.x + threadIdx.x;
    if (t >= B_ * N_) return;
    int b = t / N_;
    float ky = kp1[2 * t], kx = kp1[2 * t + 1];
    int ids[4];
    nearest4(ky, kx, ids);
    const float* Hb = homo + 9 * b;
    float h00 = Hb[0], h01 = Hb[1], h02 = Hb[2];
    float h10 = Hb[3], h11 = Hb[4], h12 = Hb[5];
    float h20 = Hb[6], h21 = Hb[7], h22 = Hb[8];
#pragma unroll
    for (int i = 0; i < 4; ++i) {
        int id = ids[i];
        cid4[4 * t + i] = id;
        float cy = 8.0f * (id >> 7) + 4.0f;
        float cx = 8.0f * (id & 127) + 4.0f;
        float X = cx, Y = cy;
        float wz = h20 * X + h21 * Y + h22;
        float inv = 1.0f / (wz + 1e-8f);
        float wy = (h10 * X + h11 * Y + h12) * inv;
        float wx = (h00 * X + h01 * Y + h02) * inv;
        int wids[4];
        nearest4(wy, wx, wids);
#pragma unroll
        for (int j = 0; j < 4; ++j) wcc16[16 * t + 4 * i + j] = wids[j];
    }
    float zy = w_kp1[2 * t], zx = w_kp1[2 * t + 1];
    int wi4[4];
    nearest4(zy, zx, wi4);
#pragma unroll
    for (int j = 0; j < 4; ++j) wid4[4 * t + j] = wi4[j];
}

__global__ __launch_bounds__(128) void hqt_k2_sample_f32(
    const float* __restrict__ w_kp1, const float* __restrict__ desc2,
    const float* __restrict__ kp1_desc, float* __restrict__ w_desc,
    float* __restrict__ pos) {
    int bn = blockIdx.x;
    int b = bn / N_;
    int c = threadIdx.x;
    float ky = w_kp1[2 * bn], kx = w_kp1[2 * bn + 1];
    float y = fminf(fmaxf(ky * 0.125f - 0.5f, 0.0f), (float)(H_ - 1));
    float x = fminf(fmaxf(kx * 0.125f - 0.5f, 0.0f), (float)(W_ - 1));
    int y0 = (int)floorf(y); if (y0 > H_ - 2) y0 = H_ - 2;
    int x0 = (int)floorf(x); if (x0 > W_ - 2) x0 = W_ - 2;
    float wy = y - (float)y0, wx = x - (float)x0;
    const float* dB = desc2 + ((size_t)b * C_ + c) * HW_;
    int i00 = y0 * W_ + x0;
    float v = dB[i00]          * (1.0f - wy) * (1.0f - wx)
            + dB[i00 + 1]      * (1.0f - wy) * wx
            + dB[i00 + W_]     * wy * (1.0f - wx)
            + dB[i00 + W_ + 1] * wy * wx;
    __shared__ float red[128];
    red[c] = v * v;
    __syncthreads();
    for (int s = 64; s > 0; s >>= 1) {
        if (c < s) red[c] += red[c + s];
        __syncthreads();
    }
    float nrm = sqrtf(red[0]);
    __syncthreads();
    float vn = v / (nrm + 1e-8f);
    w_desc[(size_t)bn * C_ + c] = vn;
    float qd = kp1_desc[(size_t)bn * C_ + c];
    red[c] = qd * vn;
    __syncthreads();
    for (int s = 64; s > 0; s >>= 1) {
        if (c < s) red[c] += red[c + s];
        __syncthreads();
    }
    if (c == 0) pos[bn] = 2.0f - 2.0f * red[0];
}

__device__ inline void bitonic16_asc(float (&a)[16]) {
#pragma unroll
    for (int dd = 0; dd < 4; ++dd) {
        const int d = 8 >> dd;
#pragma unroll
        for (int i = 0; i < 16; ++i) {
            if ((i & d) == 0) {
                float lo = fminf(a[i], a[i + d]);
                float hi = fmaxf(a[i], a[i + d]);
                a[i] = lo; a[i + d] = hi;
            }
        }
    }
}

#define T3 512
#define R3 4
__global__ __launch_bounds__(T3) void hqt_k3_dsim(
    const float* __restrict__ desc2, const float* __restrict__ kp1_desc,
    const int* __restrict__ wcc16, const float* __restrict__ pos,
    float* __restrict__ acc) {
    const int nb = N_ / R3;
    int b = blockIdx.x / nb;
    int n0 = (blockIdx.x % nb) * R3;
    int tid = threadIdx.x;
    __shared__ float qT[C_][R3];
    __shared__ int ids_s[R3][16];
    {
        int r = tid & 3, c = tid >> 2;
        qT[c][r] = kp1_desc[(size_t)(b * N_ + n0 + r) * C_ + c];
    }
    if (tid < R3 * 16)
        ids_s[tid >> 4][tid & 15] = wcc16[(b * N_ + n0) * 16 + tid];
    __syncthreads();

    float top[R3][16];
#pragma unroll
    for (int r = 0; r < R3; ++r)
#pragma unroll
        for (int k = 0; k < 16; ++k) top[r][k] = 1e30f;

    const float* d2b = desc2 + (size_t)b * C_ * HW_;
#pragma unroll 1
    for (int g = 0; g < HW_ / (T3 * 4); ++g) {
        int j0 = (g * T3 + tid) * 4;
        float4 A0 = {0, 0, 0, 0}, A1 = {0, 0, 0, 0}, A2 = {0, 0, 0, 0}, A3 = {0, 0, 0, 0};
        for (int c = 0; c < C_; ++c) {
            float4 d = *reinterpret_cast<const float4*>(d2b + (size_t)c * HW_ + j0);
            float4 qv = *reinterpret_cast<const float4*>(&qT[c][0]);
            A0.x = fmaf(qv.x, d.x, A0.x); A0.y = fmaf(qv.x, d.y, A0.y);
            A0.z = fmaf(qv.x, d.z, A0.z); A0.w = fmaf(qv.x, d.w, A0.w);
            A1.x = fmaf(qv.y, d.x, A1.x); A1.y = fmaf(qv.y, d.y, A1.y);
            A1.z = fmaf(qv.y, d.z, A1.z); A1.w = fmaf(qv.y, d.w, A1.w);
            A2.x = fmaf(qv.z, d.x, A2.x); A2.y = fmaf(qv.z, d.y, A2.y);
            A2.z = fmaf(qv.z, d.z, A2.z); A2.w = fmaf(qv.z, d.w, A2.w);
            A3.x = fmaf(qv.w, d.x, A3.x); A3.y = fmaf(qv.w, d.y, A3.y);
            A3.z = fmaf(qv.w, d.z, A3.z); A3.w = fmaf(qv.w, d.w, A3.w);
        }
#pragma unroll
        for (int r = 0; r < R3; ++r) {
            float dots[4];
            dots[0] = (r == 0) ? A0.x : (r == 1) ? A1.x : (r == 2) ? A2.x : A3.x;
            dots[1] = (r == 0) ? A0.y : (r == 1) ? A1.y : (r == 2) ? A2.y : A3.y;
            dots[2] = (r == 0) ? A0.z : (r == 1) ? A1.z : (r == 2) ? A2.z : A3.z;
            dots[3] = (r == 0) ? A0.w : (r == 1) ? A1.w : (r == 2) ? A2.w : A3.w;
#pragma unroll
            for (int cc = 0; cc < 4; ++cc) {
                int j = j0 + cc;
                int cnt = 0;
#pragma unroll
                for (int i = 0; i < 16; ++i) cnt += (ids_s[r][i] == j) ? 1 : 0;
                float v = 2.0f - 2.0f * dots[cc] + 5.0f * (float)cnt;
                if (v < top[r][15]) {
#pragma unroll
                    for (int k = 0; k < 16; ++k) {
                        float o = top[r][k];
                        bool sm = v < o;
                        top[r][k] = sm ? v : o;
                        v = sm ? o : v;
                    }
                }
            }
        }
    }

    __shared__ float mv[T3][17];
#pragma unroll
    for (int r = 0; r < R3; ++r) {
        float a[16];
#pragma unroll
        for (int k = 0; k < 16; ++k) { a[k] = top[r][k]; mv[tid][k] = a[k]; }
        __syncthreads();
        for (int step = T3 / 2; step >= 1; step >>= 1) {
            if (tid < step) {
#pragma unroll
                for (int i = 0; i < 16; ++i)
                    a[i] = fminf(a[i], mv[tid + step][15 - i]);
                bitonic16_asc(a);
#pragma unroll
                for (int i = 0; i < 16; ++i) mv[tid][i] = a[i];
            }
            __syncthreads();
        }
        if (tid == 0) {
            float p = pos[b * N_ + n0 + r];
            float s = 0.0f;
#pragma unroll
            for (int k = 0; k < 16; ++k) {
                float xv = p - a[k] + 1.0f;
                xv = fmaxf(xv, 0.0f);
                s += xv * xv;
            }
            atomicAdd(acc + 0, s);
        }
        __syncthreads();
    }
}

__global__ __launch_bounds__(64) void hqt_k4_sos(
    const float* __restrict__ kp1_desc, const float* __restrict__ w_desc,
    const int* __restrict__ cid4, const int* __restrict__ wcc16,
    const int* __restrict__ wid4, float* __restrict__ acc) {
    int bn = blockIdx.x;
    int b = bn / N_;
    int lane = threadIdx.x;
    __shared__ float qk[C_], qw[C_];
    for (int c = lane; c < C_; c += 64) {
        qk[c] = kp1_desc[(size_t)bn * C_ + c];
        qw[c] = w_desc[(size_t)bn * C_ + c];
    }
    __syncthreads();
    int nk[4];
#pragma unroll
    for (int i = 0; i < 4; ++i) nk[i] = cid4[4 * bn + i];
    int nw[16];
#pragma unroll
    for (int i = 0; i < 16; ++i) nw[i] = wcc16[16 * bn + i];

    float kv[8], wv[8]; int ki[8], wi[8];
#pragma unroll
    for (int k = 0; k < 8; ++k) {
        kv[k] = 1e30f; wv[k] = 1e30f; ki[k] = INT_MAX; wi[k] = INT_MAX;
    }
    const float* kb = kp1_desc + (size_t)b * N_ * C_;
    const float* wb = w_desc + (size_t)b * N_ * C_;
    for (int tt = 0; tt < 8; ++tt) {
        int m = lane * 8 + tt;
        const float* rk = kb + (size_t)m * C_;
        const float* rw = wb + (size_t)m * C_;
        float dk = 0.0f, dw = 0.0f;
        for (int c = 0; c < C_; c += 4) {
            float4 xk = *(const float4*)(rk + c);
            float4 xw = *(const float4*)(rw + c);
            dk += qk[c] * xk.x + qk[c + 1] * xk.y + qk[c + 2] * xk.z + qk[c + 3] * xk.w;
            dw += qw[c] * xw.x + qw[c + 1] * xw.y + qw[c + 2] * xw.z + qw[c + 3] * xw.w;
        }
        int4 mc = *(const int4*)(cid4 + 4 * (b * N_ + m));
        int ck = 0;
#pragma unroll
        for (int i = 0; i < 4; ++i) {
            int u = nk[i];
            ck += (u == mc.x) + (u == mc.y) + (u == mc.z) + (u == mc.w);
        }
        int4 mw = *(const int4*)(wid4 + 4 * (b * N_ + m));
        int cw = 0;
#pragma unroll
        for (int i = 0; i < 16; ++i) {
            int u = nw[i];
            cw += (u == mw.x) + (u == mw.y) + (u == mw.z) + (u == mw.w);
        }
        float vk = 2.0f - 2.0f * dk + 5.0f * (float)ck;
        float vw2 = 2.0f - 2.0f * dw + 5.0f * (float)cw;
        insert8_vi(kv, ki, vk, m);
        insert8_vi(wv, wi, vw2, m);
    }

    __shared__ float mvs[64][9];
    __shared__ int mis[64][9];
    __shared__ int fk[8], fw[8];

#pragma unroll
    for (int i = 0; i < 8; ++i) { mvs[lane][i] = kv[i]; mis[lane][i] = ki[i]; }
    __syncthreads();
    for (int step = 32; step >= 1; step >>= 1) {
        if (lane < step) {
            float bv[8]; int bix[8];
#pragma unroll
            for (int i = 0; i < 8; ++i) {
                bv[i] = mvs[lane + step][7 - i];
                bix[i] = mis[lane + step][7 - i];
            }
#pragma unroll
            for (int i = 0; i < 8; ++i) {
                bool ta = (kv[i] < bv[i]) || (kv[i] == bv[i] && ki[i] < bix[i]);
                kv[i] = ta ? kv[i] : bv[i];
                ki[i] = ta ? ki[i] : bix[i];
            }
            bitonic8_pairs(kv, ki);
#pragma unroll
            for (int i = 0; i < 8; ++i) { mvs[lane][i] = kv[i]; mis[lane][i] = ki[i]; }
        }
        __syncthreads();
    }
    if (lane < 8) fk[lane] = mis[0][lane];
    __syncthreads();

#pragma unroll
    for (int i = 0; i < 8; ++i) { mvs[lane][i] = wv[i]; mis[lane][i] = wi[i]; }
    __syncthreads();
    for (int step = 32; step >= 1; step >>= 1) {
        if (lane < step) {
            float bv[8]; int bix[8];
#pragma unroll
            for (int i = 0; i < 8; ++i) {
                bv[i] = mvs[lane + step][7 - i];
                bix[i] = mis[lane + step][7 - i];
            }
#pragma unroll
            for (int i = 0; i < 8; ++i) {
                bool ta = (wv[i] < bv[i]) || (wv[i] == bv[i] && wi[i] < bix[i]);
                wv[i] = ta ? wv[i] : bv[i];
                wi[i] = ta ? wi[i] : bix[i];
            }
            bitonic8_pairs(wv, wi);
#pragma unroll
            for (int i = 0; i < 8; ++i) { mvs[lane][i] = wv[i]; mis[lane][i] = wi[i]; }
        }
        __syncthreads();
    }
    if (lane < 8) fw[lane] = mis[0][lane];
    __syncthreads();

    int s = lane >> 3, p = lane & 7;
    const float* rk = kb + (size_t)fk[s] * C_;
    const float* rw = wb + (size_t)fw[s] * C_;
    float dk = 0.0f, dw = 0.0f;
    for (int c = p; c < C_; c += 8) {
        dk += qk[c] * rk[c];
        dw += qw[c] * rw[c];
    }
    dk += __shfl_xor(dk, 1); dk += __shfl_xor(dk, 2); dk += __shfl_xor(dk, 4);
    dw += __shfl_xor(dw, 1); dw += __shfl_xor(dw, 2); dw += __shfl_xor(dw, 4);
    __shared__ float tsq[8];
    if (p == 0) {
        float t2 = 2.0f * (dw - dk);
        tsq[s] = t2 * t2;
    }
    __syncthreads();
    if (lane == 0) {
        float s8 = 0.0f;
#pragma unroll
        for (int i = 0; i < 8; ++i) s8 += tsq[i];
        atomicAdd(acc + 1, sqrtf(s8));
    }
}

__global__ void hqt_k5_final(const float* __restrict__ acc, float* __restrict__ out) {
    if (threadIdx.x == 0 && blockIdx.x == 0) {
        out[0] = acc[0] * (1.0f / (float)(B_ * N_ * NUM_NEG_))
               + acc[1] * (1.0f / (float)(B_ * N_));
    }
}

// ===========================================================================
extern "C" void kernel_launch(void* const* d_in, const int* in_sizes, int n_in,
                              void* d_out, int out_size, void* d_ws, size_t ws_size,
                              hipStream_t stream) {
    const float* kp1      = (const float*)d_in[0];
    const float* w_kp1    = (const float*)d_in[1];
    const float* kp1_desc = (const float*)d_in[2];
    const float* desc2    = (const float*)d_in[3];
    const float* homo     = (const float*)d_in[4];
    float* out = (float*)d_out;

    char* p = (char*)d_ws;
    auto alloc = [&](size_t bytes) {
        char* r = p;
        p += (bytes + 255) & ~(size_t)255;
        return r;
    };
    float*          pos    = (float*)alloc((size_t)B_ * N_ * 4);
    int*            cid4   = (int*)alloc((size_t)B_ * N_ * 4 * 4);
    int*            wid4   = (int*)alloc((size_t)B_ * N_ * 4 * 4);
    int*            wcc16  = (int*)alloc((size_t)B_ * N_ * 16 * 4);
    unsigned int*   marked = (unsigned int*)alloc((size_t)B_ * N_ * 16 * 4);
    float*          acc    = (float*)alloc(64);
    unsigned short* q_bf   = (unsigned short*)alloc((size_t)B_ * N_ * C_ * 2);
    unsigned short* w_bf   = (unsigned short*)alloc((size_t)B_ * N_ * C_ * 2);
    unsigned short* d2t    = (unsigned short*)alloc((size_t)B_ * HW_ * C_ * 2);
    float*          psim   = (float*)alloc((size_t)2 * B_ * N_ * N_ * 4);
    float*          rowmax = (float*)alloc((size_t)B_ * N_ * 128 * 4);
    float*          t32    = (float*)alloc((size_t)B_ * N_ * 4);
    int*            scnt   = (int*)alloc((size_t)B_ * N_ * 4);
    float2*         sbuf   = (float2*)alloc((size_t)B_ * N_ * SCAP_ * 8);
    size_t need = (size_t)(p - (char*)d_ws);

    if (ws_size >= need) {
        hqt_ka<<<1413, 256, 0, stream>>>(desc2, kp1_desc, kp1, w_kp1, homo,
                                         d2t, q_bf, w_bf, pos, cid4, wcc16,
                                         wid4, marked, scnt, acc);
        hqt_kb<<<384, 512, 0, stream>>>(q_bf, w_bf, d2t, cid4, wid4, wcc16,
                                        rowmax, psim);
        hqt_k3b<<<256, 256, 0, stream>>>(rowmax, t32);
        hqt_kc<<<256, 512, 0, stream>>>(q_bf, d2t, t32, scnt, sbuf);
        hqt_kd<<<512, 256, 0, stream>>>(q_bf, d2t, marked, scnt, sbuf, pos,
                                        psim, cid4, wid4, wcc16, acc, out);
    } else {
        // fallback: round-1 layout and path
        float* w_desc0 = (float*)d_ws;
        float* pos0    = w_desc0 + (size_t)B_ * N_ * C_;
        int*   cid40   = (int*)(pos0 + B_ * N_);
        int*   wid40   = cid40 + B_ * N_ * 4;
        int*   wcc160  = wid40 + B_ * N_ * 4;
        float* acc0    = (float*)(wcc160 + B_ * N_ * 16);
        hipMemsetAsync(acc0, 0, 2 * sizeof(float), stream);
        hqt_k1_cells<<<(B_ * N_ + 255) / 256, 256, 0, stream>>>(
            kp1, w_kp1, homo, cid40, wcc160, wid40);
        hqt_k2_sample_f32<<<B_ * N_, 128, 0, stream>>>(w_kp1, desc2, kp1_desc,
                                                       w_desc0, pos0);
        hqt_k3_dsim<<<B_ * (N_ / R3), T3, 0, stream>>>(desc2, kp1_desc, wcc160,
                                                       pos0, acc0);
        hqt_k4_sos<<<B_ * N_, 64, 0, stream>>>(kp1_desc, w_desc0, cid40,
                                               wcc160, wid40, acc0);
        hqt_k5_final<<<1, 1, 0, stream>>>(acc0, out);
    }
}